// Round 5
// baseline (6765.676 us; speedup 1.0000x reference)
//
#include <hip/hip_runtime.h>
#include <hip/hip_bf16.h>
#include <cstdint>
#include <cstddef>

typedef __hip_bfloat16 bf16;
typedef float  f32x4   __attribute__((ext_vector_type(4)));
typedef float  float4v __attribute__((ext_vector_type(4)));
typedef short  short8  __attribute__((ext_vector_type(8)));
typedef short  short4v __attribute__((ext_vector_type(4)));
typedef __bf16 bf16x8  __attribute__((ext_vector_type(8)));

__device__ __forceinline__ void mfma16(f32x4& d, short8 a, short8 b) {
  d = __builtin_amdgcn_mfma_f32_16x16x32_bf16(
      __builtin_bit_cast(bf16x8, a), __builtin_bit_cast(bf16x8, b), d, 0, 0, 0);
}
__device__ __forceinline__ unsigned short f2b_bits(float x) {
  __hip_bfloat16 h = __float2bfloat16(x);
  return __builtin_bit_cast(unsigned short, h);
}
__device__ __forceinline__ float gelu_exact(float x) {
  return 0.5f * x * (1.0f + erff(x * 0.7071067811865475f));
}
__device__ __forceinline__ void gload_lds16(const bf16* g, char* l) {
  __builtin_amdgcn_global_load_lds((const __attribute__((address_space(1))) void*)g,
                                   (__attribute__((address_space(3))) void*)l, 16, 0, 0);
}

// ---------- f32 -> bf16 convert, 4 elems/thread ----------
__global__ __launch_bounds__(256) void k_cvt(const float* __restrict__ src,
                                             bf16* __restrict__ dst, int n4) {
  int i = blockIdx.x * 256 + threadIdx.x;
  if (i >= n4) return;
  float4v v = *(const float4v*)(src + (size_t)i * 4);
  short4v s;
  s[0] = (short)f2b_bits(v[0]); s[1] = (short)f2b_bits(v[1]);
  s[2] = (short)f2b_bits(v[2]); s[3] = (short)f2b_bits(v[3]);
  *(short4v*)((short*)dst + (size_t)i * 4) = s;
}

// ---------- transpose (+optional per-k scale): f32 (K,N) -> bf16 (N,K) ----------
__global__ void k_tfold(const float* __restrict__ src, const float* __restrict__ scale,
                        bf16* __restrict__ dst, int K, int N,
                        long long src_bs, long long scale_bs, long long dst_bs) {
  src += (size_t)blockIdx.z * src_bs;
  dst += (size_t)blockIdx.z * dst_bs;
  const float* sc = scale ? scale + (size_t)blockIdx.z * scale_bs : nullptr;
  __shared__ float tile[32][33];
  int n0 = blockIdx.x * 32, k0 = blockIdx.y * 32;
  int tx = threadIdx.x, ty = threadIdx.y;
#pragma unroll
  for (int j = 0; j < 4; ++j) {
    int k = k0 + ty + j * 8;
    float s = sc ? sc[k] : 1.0f;
    tile[ty + j * 8][tx] = src[(size_t)k * N + n0 + tx] * s;
  }
  __syncthreads();
#pragma unroll
  for (int j = 0; j < 4; ++j) {
    int n = n0 + ty + j * 8;
    dst[(size_t)n * K + k0 + tx] = __float2bfloat16(tile[tx][ty + j * 8]);
  }
}

// ---------- dual transpose-fold: read W once, write two scaled transposes ----------
__global__ void k_tfold2(const float* __restrict__ src,
                         const float* __restrict__ s1, const float* __restrict__ s2,
                         bf16* __restrict__ d1, bf16* __restrict__ d2, int K, int N,
                         long long src_bs, long long s_bs,
                         long long d1_bs, long long d2_bs) {
  src += (size_t)blockIdx.z * src_bs;
  d1  += (size_t)blockIdx.z * d1_bs;
  d2  += (size_t)blockIdx.z * d2_bs;
  s1  += (size_t)blockIdx.z * s_bs;
  s2  += (size_t)blockIdx.z * s_bs;
  __shared__ float tile[32][33];
  __shared__ float sc1[32], sc2[32];
  int n0 = blockIdx.x * 32, k0 = blockIdx.y * 32;
  int tx = threadIdx.x, ty = threadIdx.y;
  if (ty == 0) { sc1[tx] = s1[k0 + tx]; sc2[tx] = s2[k0 + tx]; }
#pragma unroll
  for (int j = 0; j < 4; ++j) {
    int k = k0 + ty + j * 8;
    tile[ty + j * 8][tx] = src[(size_t)k * N + n0 + tx];
  }
  __syncthreads();
#pragma unroll
  for (int j = 0; j < 4; ++j) {
    int n = n0 + ty + j * 8;
    float v = tile[tx][ty + j * 8];
    d1[(size_t)n * K + k0 + tx] = __float2bfloat16(v * sc1[tx]);
    d2[(size_t)n * K + k0 + tx] = __float2bfloat16(v * sc2[tx]);
  }
}

// ---------- bias fold: out[n] = sum_k lnb[k]*W[k][n], k-parallel ----------
__global__ __launch_bounds__(256) void k_bfold(const float* __restrict__ W,
                                               const float* __restrict__ lnb,
                                               float* __restrict__ out, int K, int N,
                                               long long w_bs, long long b_bs, long long o_bs) {
  W   += (size_t)blockIdx.y * w_bs;
  lnb += (size_t)blockIdx.y * b_bs;
  out += (size_t)blockIdx.y * o_bs;
  const int l = threadIdx.x & 63, kg = threadIdx.x >> 6;
  const int n = blockIdx.x * 64 + l;
  float a = 0.0f;
  for (int k = kg; k < K; k += 4) a = fmaf(lnb[k], W[(size_t)k * N + n], a);
  __shared__ float red[4][64];
  red[kg][l] = a;
  __syncthreads();
  if (kg == 0) out[n] = (red[0][l] + red[1][l]) + (red[2][l] + red[3][l]);
}

// ---------- dual bias fold: read W once, two bias vectors, two outputs ----------
__global__ __launch_bounds__(256) void k_bfold2(const float* __restrict__ W,
                                                const float* __restrict__ b1,
                                                const float* __restrict__ b2,
                                                float* __restrict__ o1,
                                                float* __restrict__ o2, int K, int N,
                                                long long w_bs, long long b_bs,
                                                long long o1_bs, long long o2_bs) {
  W  += (size_t)blockIdx.y * w_bs;
  b1 += (size_t)blockIdx.y * b_bs;
  b2 += (size_t)blockIdx.y * b_bs;
  o1 += (size_t)blockIdx.y * o1_bs;
  o2 += (size_t)blockIdx.y * o2_bs;
  const int l = threadIdx.x & 63, kg = threadIdx.x >> 6;
  const int n = blockIdx.x * 64 + l;
  float a1 = 0.0f, a2 = 0.0f;
  for (int k = kg; k < K; k += 4) {
    float wv = W[(size_t)k * N + n];
    a1 = fmaf(b1[k], wv, a1);
    a2 = fmaf(b2[k], wv, a2);
  }
  __shared__ float r1[4][64], r2[4][64];
  r1[kg][l] = a1; r2[kg][l] = a2;
  __syncthreads();
  if (kg == 0) {
    o1[n] = (r1[0][l] + r1[1][l]) + (r1[2][l] + r1[3][l]);
    o2[n] = (r2[0][l] + r2[1][l]) + (r2[2][l] + r2[3][l]);
  }
}

// ---------- row standardize (768-wide), f32 -> bf16 ----------
__global__ __launch_bounds__(256) void k_std(const float* __restrict__ src,
                                             bf16* __restrict__ dst) {
  int row = blockIdx.x;
  const float* x = src + (size_t)row * 768;
  int t = threadIdx.x;
  float a0 = x[t], a1 = x[t + 256], a2 = x[t + 512];
  float s = a0 + a1 + a2;
  float q = a0 * a0 + a1 * a1 + a2 * a2;
#pragma unroll
  for (int off = 1; off < 64; off <<= 1) { s += __shfl_xor(s, off); q += __shfl_xor(q, off); }
  __shared__ float ss[4], qs[4];
  if ((t & 63) == 0) { ss[t >> 6] = s; qs[t >> 6] = q; }
  __syncthreads();
  s = ss[0] + ss[1] + ss[2] + ss[3];
  q = qs[0] + qs[1] + qs[2] + qs[3];
  float mean = s * (1.0f / 768.0f);
  float var  = q * (1.0f / 768.0f) - mean * mean;
  float inv  = rsqrtf(var + 1e-5f);
  bf16* d = dst + (size_t)row * 768;
  d[t]       = __float2bfloat16((a0 - mean) * inv);
  d[t + 256] = __float2bfloat16((a1 - mean) * inv);
  d[t + 512] = __float2bfloat16((a2 - mean) * inv);
}

// ---------- final layernorm (768-wide) with w,b: f32 -> f32 ----------
__global__ __launch_bounds__(256) void k_lnout(const float* __restrict__ src,
                                               const float* __restrict__ w,
                                               const float* __restrict__ b,
                                               float* __restrict__ dst) {
  int row = blockIdx.x;
  const float* x = src + (size_t)row * 768;
  int t = threadIdx.x;
  float a0 = x[t], a1 = x[t + 256], a2 = x[t + 512];
  float s = a0 + a1 + a2;
  float q = a0 * a0 + a1 * a1 + a2 * a2;
#pragma unroll
  for (int off = 1; off < 64; off <<= 1) { s += __shfl_xor(s, off); q += __shfl_xor(q, off); }
  __shared__ float ss[4], qs[4];
  if ((t & 63) == 0) { ss[t >> 6] = s; qs[t >> 6] = q; }
  __syncthreads();
  s = ss[0] + ss[1] + ss[2] + ss[3];
  q = qs[0] + qs[1] + qs[2] + qs[3];
  float mean = s * (1.0f / 768.0f);
  float var  = q * (1.0f / 768.0f) - mean * mean;
  float inv  = rsqrtf(var + 1e-5f);
  float* d = dst + (size_t)row * 768;
  d[t]       = (a0 - mean) * inv * w[t]       + b[t];
  d[t + 256] = (a1 - mean) * inv * w[t + 256] + b[t + 256];
  d[t + 512] = (a2 - mean) * inv * w[t + 512] + b[t + 512];
}

// ---------- MFMA GEMM: C(M,N) = A(M,K)bf16 @ Bt(N,K)bf16 [+bias][gelu][+res f32] ----------
// 1-D grid (N fastest) + bijective XCD swizzle. Double-buffered LDS via
// global_load_lds(16B): stage(kt+1) issued BEFORE compute(kt); one
// __syncthreads per K-step (drains vmcnt+lgkm) -> loads overlap MFMA.
template <int BM, int BN, bool OBF16, bool GELU>
__global__ __launch_bounds__(256) void k_gemm(const bf16* __restrict__ A,
                                              const bf16* __restrict__ Bt,
                                              void* __restrict__ Cv,
                                              const float* __restrict__ bias,
                                              const float* __restrict__ res,
                                              int M, int N, int K, int nxt, int nwg) {
  constexpr int MF = BM / 32, NF = BN / 32;
  constexpr int AJ = BM / 32, BJ = BN / 32;
  __shared__ __align__(16) char As[2][BM * 128];
  __shared__ __align__(16) char Bs[2][BN * 128];

  const int lin = blockIdx.x;
  const int qq = nwg >> 3, r8 = nwg & 7;
  const int xcd = lin & 7, idx = lin >> 3;
  const int swz = (xcd < r8) ? (xcd * (qq + 1) + idx)
                             : (r8 * (qq + 1) + (xcd - r8) * qq + idx);
  const int bm = (swz / nxt) * BM, bn = (swz % nxt) * BN;

  const int t = threadIdx.x, lane = t & 63, w = t >> 6;
  const int wr = w >> 1, wc = w & 1;
  const int l15 = lane & 15, lg = lane >> 4;
  const int lr = lane >> 3, lc = lane & 7;
  const int csw = lc ^ lr;               // pre-swizzled source col-block (rule 21)

  const bf16* asrc[AJ]; int aoff[AJ];
#pragma unroll
  for (int j = 0; j < AJ; ++j) {
    int rl = w * (BM / 4) + j * 8 + lr;
    int gr = bm + rl; if (gr > M - 1) gr = M - 1;
    asrc[j] = A + (size_t)gr * K + csw * 8;
    aoff[j] = (w * (BM / 4) + j * 8) * 128;
  }
  const bf16* bsrc[BJ]; int boff[BJ];
#pragma unroll
  for (int j = 0; j < BJ; ++j) {
    int rl = w * (BN / 4) + j * 8 + lr;
    int gc = bn + rl; if (gc > N - 1) gc = N - 1;
    bsrc[j] = Bt + (size_t)gc * K + csw * 8;
    boff[j] = (w * (BN / 4) + j * 8) * 128;
  }

  auto stage = [&](int kt, int buf) {
    const size_t ko = (size_t)kt * 64;
#pragma unroll
    for (int j = 0; j < AJ; ++j) gload_lds16(asrc[j] + ko, As[buf] + aoff[j]);
#pragma unroll
    for (int j = 0; j < BJ; ++j) gload_lds16(bsrc[j] + ko, Bs[buf] + boff[j]);
  };

  f32x4 acc[MF][NF] = {};
  const int nk = K / 64;
  stage(0, 0);
  __syncthreads();                        // drain vmcnt -> buf0 ready

  for (int kt = 0; kt < nk; ++kt) {
    const int cur = kt & 1;
    if (kt + 1 < nk) stage(kt + 1, cur ^ 1);   // issue early, overlaps MFMA below
#pragma unroll
    for (int ks = 0; ks < 2; ++ks) {
      short8 af[MF], bfr[NF];
#pragma unroll
      for (int m = 0; m < MF; ++m) {
        int r = wr * (BM / 2) + m * 16 + l15;
        af[m] = *(const short8*)(As[cur] + r * 128 + ((ks * 64 + lg * 16) ^ ((r & 7) << 4)));
      }
#pragma unroll
      for (int n = 0; n < NF; ++n) {
        int r = wc * (BN / 2) + n * 16 + l15;
        bfr[n] = *(const short8*)(Bs[cur] + r * 128 + ((ks * 64 + lg * 16) ^ ((r & 7) << 4)));
      }
#pragma unroll
      for (int m = 0; m < MF; ++m)
#pragma unroll
        for (int n = 0; n < NF; ++n) mfma16(acc[m][n], af[m], bfr[n]);
    }
    __syncthreads();                      // drains stage(kt+1); protects cur buf
  }

#pragma unroll
  for (int m = 0; m < MF; ++m) {
    int gr0 = bm + wr * (BM / 2) + m * 16 + lg * 4;
#pragma unroll
    for (int n = 0; n < NF; ++n) {
      int gc = bn + wc * (BN / 2) + n * 16 + l15;
      float bvs = bias ? bias[gc] : 0.0f;
#pragma unroll
      for (int r = 0; r < 4; ++r) {
        int gr = gr0 + r;
        if (gr < M) {
          float v = acc[m][n][r] + bvs;
          if (GELU) v = gelu_exact(v);
          if (res) v += res[(size_t)gr * N + gc];
          if (OBF16) ((bf16*)Cv)[(size_t)gr * N + gc] = __float2bfloat16(v);
          else       ((float*)Cv)[(size_t)gr * N + gc] = v;
        }
      }
    }
  }
}

// ---------- fused attention: one block per (local b, h); 4 waves, 16 q-rows each ----------
__global__ __launch_bounds__(256) void k_attn(const bf16* __restrict__ qkvl,
                                              const bf16* __restrict__ kvx,
                                              bf16* __restrict__ outp, int n1, int b0) {
  const int bh = blockIdx.x;
  const int bl = bh >> 4, h = bh & 15;
  const int b = b0 + bl;
  __shared__ __align__(16) char Qs[64 * 128];
  __shared__ __align__(16) char Ks[64 * 128];
  __shared__ __align__(16) char Vt[64 * 128];
  __shared__ __align__(16) char Ps[4][16 * 128];
  const int t = threadIdx.x, lane = t & 63, w = t >> 6;
  const int l15 = lane & 15, lg = lane >> 4;

#pragma unroll
  for (int it = 0; it < 2; ++it) {
    int slot = it * 256 + t; int r = slot >> 3, c = slot & 7;
    short8 v = *(const short8*)(qkvl + (size_t)(b * 64 + r) * 3072 + h * 64 + c * 8);
    *(short8*)(Qs + r * 128 + ((c * 16) ^ ((r & 7) << 4))) = v;
  }
  const int n_kv = n1 + 64;
  const int nch = (n_kv + 63) >> 6;
  float m_run[4], l_run[4];
  f32x4 o[4] = {};
#pragma unroll
  for (int r = 0; r < 4; ++r) { m_run[r] = -1e30f; l_run[r] = 0.0f; }

  short8 kreg[2], vreg[2];
  auto loadKV = [&](int ch) {
#pragma unroll
    for (int it = 0; it < 2; ++it) {
      int slot = it * 256 + t; int rr = slot >> 3, c = slot & 7;
      int j = ch * 64 + rr;
      short8 kv = {}; short8 vv = {};
      if (j < n_kv) {
        const bf16* kb;
        if (j < n1) kb = kvx + (size_t)(bl * n1 + j) * 2048 + h * 64;
        else        kb = qkvl + (size_t)(b * 64 + (j - n1)) * 3072 + 1024 + h * 64;
        kv = *(const short8*)(kb + c * 8);
        vv = *(const short8*)(kb + 1024 + c * 8);
      }
      kreg[it] = kv; vreg[it] = vv;
    }
  };
  loadKV(0);

  for (int ch = 0; ch < nch; ++ch) {
    __syncthreads();
#pragma unroll
    for (int it = 0; it < 2; ++it) {
      int slot = it * 256 + t; int rr = slot >> 3, c = slot & 7;
      *(short8*)(Ks + rr * 128 + ((c * 16) ^ ((rr & 7) << 4))) = kreg[it];
#pragma unroll
      for (int j2 = 0; j2 < 8; ++j2) {
        int dh = c * 8 + j2;
        *(short*)(Vt + dh * 128 + ((rr * 2) ^ ((dh & 7) << 4))) = vreg[it][j2];
      }
    }
    __syncthreads();
    if (ch + 1 < nch) loadKV(ch + 1);

    f32x4 s[4] = {};
#pragma unroll
    for (int ks = 0; ks < 2; ++ks) {
      int qr = w * 16 + l15;
      short8 qf = *(const short8*)(Qs + qr * 128 + ((ks * 64 + lg * 16) ^ ((qr & 7) << 4)));
#pragma unroll
      for (int n = 0; n < 4; ++n) {
        int kr = n * 16 + l15;
        short8 kf = *(const short8*)(Ks + kr * 128 + ((ks * 64 + lg * 16) ^ ((kr & 7) << 4)));
        mfma16(s[n], qf, kf);
      }
    }
    float p[4][4];
#pragma unroll
    for (int r = 0; r < 4; ++r) {
      float mx = m_run[r];
#pragma unroll
      for (int n = 0; n < 4; ++n) {
        float v = s[n][r] * 0.125f;
        int kvi = ch * 64 + n * 16 + l15;
        if (kvi >= n_kv) v = -1e30f;
        s[n][r] = v;
        mx = fmaxf(mx, v);
      }
#pragma unroll
      for (int off = 1; off < 16; off <<= 1) mx = fmaxf(mx, __shfl_xor(mx, off));
      float scl = __expf(m_run[r] - mx);
      m_run[r] = mx;
      float rs = 0.0f;
#pragma unroll
      for (int n = 0; n < 4; ++n) { float pv = __expf(s[n][r] - mx); p[n][r] = pv; rs += pv; }
#pragma unroll
      for (int off = 1; off < 16; off <<= 1) rs += __shfl_xor(rs, off);
      l_run[r] = l_run[r] * scl + rs;
#pragma unroll
      for (int nn = 0; nn < 4; ++nn) o[nn][r] *= scl;
    }
#pragma unroll
    for (int n = 0; n < 4; ++n)
#pragma unroll
      for (int r = 0; r < 4; ++r) {
        int q = lg * 4 + r; int kv = n * 16 + l15;
        *(unsigned short*)(Ps[w] + q * 128 + ((kv * 2) ^ ((q & 7) << 4))) = f2b_bits(p[n][r]);
      }
#pragma unroll
    for (int ks = 0; ks < 2; ++ks) {
      short8 pf = *(const short8*)(Ps[w] + l15 * 128 + ((ks * 64 + lg * 16) ^ ((l15 & 7) << 4)));
#pragma unroll
      for (int nn = 0; nn < 4; ++nn) {
        int dh = nn * 16 + l15;
        short8 vf = *(const short8*)(Vt + dh * 128 + ((ks * 64 + lg * 16) ^ ((dh & 7) << 4)));
        mfma16(o[nn], pf, vf);
      }
    }
  }
#pragma unroll
  for (int nn = 0; nn < 4; ++nn)
#pragma unroll
    for (int r = 0; r < 4; ++r) {
      int qr = w * 16 + lg * 4 + r;
      int dh = nn * 16 + l15;
      float v = o[nn][r] / l_run[r];
      outp[(size_t)(b * 64 + qr) * 1024 + h * 64 + dh] = __float2bfloat16(v);
    }
}

// =========================== host ===========================
extern "C" void kernel_launch(void* const* d_in, const int* in_sizes, int n_in,
                              void* d_out, int out_size, void* d_ws, size_t ws_size,
                              hipStream_t stream) {
  (void)in_sizes; (void)n_in; (void)out_size;
  const float* id_emb = (const float*)d_in[0];
  const float* f_in[4]  = {(const float*)d_in[4],  (const float*)d_in[3],
                           (const float*)d_in[2],  (const float*)d_in[1]};
  const float* pw_in[4] = {(const float*)d_in[11], (const float*)d_in[9],
                           (const float*)d_in[7],  (const float*)d_in[5]};
  const float* pb_in[4] = {(const float*)d_in[12], (const float*)d_in[10],
                           (const float*)d_in[8],  (const float*)d_in[6]};
  const float* ln1w = (const float*)d_in[13];
  const float* ln1b = (const float*)d_in[14];
  const float* ln2w = (const float*)d_in[15];
  const float* ln2b = (const float*)d_in[16];
  const float* wq   = (const float*)d_in[17];
  const float* wkv  = (const float*)d_in[18];
  const float* wo   = (const float*)d_in[19];
  const float* fflnw = (const float*)d_in[20];
  const float* fflnb = (const float*)d_in[21];
  const float* ffw1  = (const float*)d_in[22];
  const float* ffw2  = (const float*)d_in[23];
  const float* projw = (const float*)d_in[24];
  const float* projb = (const float*)d_in[25];
  const float* normw = (const float*)d_in[26];
  const float* normb = (const float*)d_in[27];

  static const int N1S[4]  = {49, 196, 784, 3136};
  static const int FRDS[4] = {512, 256, 128, 64};

  // ---- adaptive workspace plan (ws_size is fixed per run -> deterministic) ----
  bf16 *zfeat[4], *fbf[4], *pT[4], *projT;
  float *qkvl_bias, *kvx_bias, *ff_bias, *lat, *headtmp;
  bf16 *qkvl_act, *attnout, *zlat, *latbf, *ffh;
  bf16 *wqkvlT = nullptr, *wkvxT = nullptr, *woT = nullptr, *w1T = nullptr, *w2T = nullptr;
  bf16 *wbuf = nullptr;
  char *big;

  auto assign = [&](bool fullw, int bc) -> size_t {
    size_t off = 0; char* base = (char*)d_ws;
    auto A = [&](size_t b) -> char* {
      char* p = base + off; off = (off + b + 255) & ~(size_t)255; return p;
    };
    for (int i = 0; i < 4; ++i) zfeat[i] = (bf16*)A((size_t)16 * N1S[i] * 768 * 2);
    for (int i = 0; i < 4; ++i) fbf[i]   = (bf16*)A((size_t)16 * N1S[i] * FRDS[i] * 2);
    for (int i = 0; i < 4; ++i) pT[i]    = (bf16*)A((size_t)768 * FRDS[i] * 2);
    projT     = (bf16*)A(768ull * 768 * 2);
    qkvl_bias = (float*)A(24ull * 3072 * 4);
    kvx_bias  = (float*)A(24ull * 2048 * 4);
    ff_bias   = (float*)A(6ull * 3072 * 4);
    qkvl_act  = (bf16*)A(1024ull * 3072 * 2);
    attnout   = (bf16*)A(1024ull * 1024 * 2);
    lat       = (float*)A(1024ull * 768 * 4);
    zlat      = (bf16*)A(1024ull * 768 * 2);
    if (fullw) {
      wqkvlT = (bf16*)A(24ull * 3072 * 768 * 2);
      wkvxT  = (bf16*)A(24ull * 2048 * 768 * 2);
      woT    = (bf16*)A(24ull * 768 * 1024 * 2);
      w1T    = (bf16*)A(6ull * 3072 * 768 * 2);
      w2T    = (bf16*)A(6ull * 768 * 3072 * 2);
      wbuf = nullptr;
    } else {
      wbuf = (bf16*)A(((3072ull + 2048) * 768 + 768ull * 1024) * 2);
      wqkvlT = wkvxT = woT = w1T = w2T = nullptr;
    }
    big = A((size_t)bc * 3136 * 2048 * 2);
    ffh = qkvl_act; headtmp = (float*)qkvl_act; latbf = zlat;
    return off;
  };

  static const bool FULLS[10] = {true,true,true,false,false,true,true,false,false,false};
  static const int  BCS[10]   = {16,  8,   4,   16,   8,    2,   1,   4,    2,    1};
  bool fullw = false; int bc = 1; bool ok = false;
  for (int c = 0; c < 10; ++c) {
    if (assign(FULLS[c], BCS[c]) <= ws_size) { fullw = FULLS[c]; bc = BCS[c]; ok = true; break; }
  }
  if (!ok) return;

  float* featf32 = (float*)big;
  bf16*  kvxbuf  = (bf16*)big;

  auto gemm = [&](int tile, const bf16* A, const bf16* Bt, void* C,
                  const float* bias, const float* res, int M, int N, int K,
                  bool obf, bool gl) {
    if (tile == 128) {
      int nxt = N / 128, nwg = nxt * ((M + 127) / 128);
      if (obf && gl) k_gemm<128,128,true ,true ><<<nwg,256,0,stream>>>(A,Bt,C,bias,res,M,N,K,nxt,nwg);
      else if (obf)  k_gemm<128,128,true ,false><<<nwg,256,0,stream>>>(A,Bt,C,bias,res,M,N,K,nxt,nwg);
      else           k_gemm<128,128,false,false><<<nwg,256,0,stream>>>(A,Bt,C,bias,res,M,N,K,nxt,nwg);
    } else if (tile == 64) {
      int nxt = N / 64, nwg = nxt * ((M + 63) / 64);
      if (obf && gl)  k_gemm<64,64,true ,true ><<<nwg,256,0,stream>>>(A,Bt,C,bias,res,M,N,K,nxt,nwg);
      else if (obf)   k_gemm<64,64,true ,false><<<nwg,256,0,stream>>>(A,Bt,C,bias,res,M,N,K,nxt,nwg);
      else            k_gemm<64,64,false,false><<<nwg,256,0,stream>>>(A,Bt,C,bias,res,M,N,K,nxt,nwg);
    } else {
      int nxt = N / 64, nwg = nxt * ((M + 31) / 32);
      if (obf && gl)  k_gemm<32,64,true ,true ><<<nwg,256,0,stream>>>(A,Bt,C,bias,res,M,N,K,nxt,nwg);
      else if (obf)   k_gemm<32,64,true ,false><<<nwg,256,0,stream>>>(A,Bt,C,bias,res,M,N,K,nxt,nwg);
      else            k_gemm<32,64,false,false><<<nwg,256,0,stream>>>(A,Bt,C,bias,res,M,N,K,nxt,nwg);
    }
  };
  auto pick = [&](int M, int N) -> int {
    return M >= 2048 ? 128 : (N >= 1536 ? 64 : 32);
  };

  dim3 tb(32, 8);

  // ---- bias folds (k-parallel GEMV; wkv read ONCE for both LN biases) ----
  k_bfold <<<dim3(16, 24), 256, 0, stream>>>(wq,  ln2b, qkvl_bias, 768, 1024, 768LL*1024, 768, 3072);
  k_bfold2<<<dim3(32, 24), 256, 0, stream>>>(wkv, ln2b, ln1b, qkvl_bias + 1024, kvx_bias,
                                             768, 2048, 768LL*2048, 768, 3072, 2048);
  k_bfold <<<dim3(48, 6),  256, 0, stream>>>(ffw1, fflnb, ff_bias, 768, 3072, 768LL*3072, 768, 3072);

  // ---- small folded weights (always) ----
  for (int i = 0; i < 4; ++i)
    k_tfold<<<dim3(24, FRDS[i] / 32, 1), tb, 0, stream>>>(pw_in[i], nullptr, pT[i], FRDS[i], 768, 0, 0, 0);
  k_tfold<<<dim3(24, 24, 1), tb, 0, stream>>>(projw, nullptr, projT, 768, 768, 0, 0, 0);

  // ---- full-mode weight folds (batched over layers; wkv read ONCE) ----
  if (fullw) {
    k_tfold <<<dim3(32, 24, 24), tb, 0, stream>>>(wq,  ln2w, wqkvlT, 768, 1024, 768LL*1024, 768, 3072LL*768);
    k_tfold2<<<dim3(64, 24, 24), tb, 0, stream>>>(wkv, ln2w, ln1w, wqkvlT + 1024LL*768, wkvxT,
                                                  768, 2048, 768LL*2048, 768, 3072LL*768, 2048LL*768);
    k_tfold <<<dim3(24, 32, 24), tb, 0, stream>>>(wo,  nullptr, woT, 1024, 768, 1024LL*768, 0, 768LL*1024);
    k_tfold <<<dim3(96, 24, 6),  tb, 0, stream>>>(ffw1, fflnw, w1T, 768, 3072, 768LL*3072, 768, 3072LL*768);
    k_tfold <<<dim3(24, 96, 6),  tb, 0, stream>>>(ffw2, nullptr, w2T, 3072, 768, 3072LL*768, 0, 768LL*3072);
  }

  auto attnW = [&](int di, const bf16*& qkvlT_p, const bf16*& kvxT_p, const bf16*& woT_p) {
    if (fullw) {
      qkvlT_p = wqkvlT + (size_t)di * 3072 * 768;
      kvxT_p  = wkvxT  + (size_t)di * 2048 * 768;
      woT_p   = woT    + (size_t)di * 768 * 1024;
    } else {
      bf16* dq   = wbuf;
      bf16* dkvx = wbuf + 3072ull * 768;
      bf16* dwo  = dkvx + 2048ull * 768;
      k_tfold <<<dim3(32, 24, 1), tb, 0, stream>>>(wq  + (size_t)di*768*1024, ln2w + 768ull*di, dq, 768, 1024, 0, 0, 0);
      k_tfold2<<<dim3(64, 24, 1), tb, 0, stream>>>(wkv + (size_t)di*768*2048, ln2w + 768ull*di, ln1w + 768ull*di,
                                                   dq + 1024ull*768, dkvx, 768, 2048, 0, 0, 0, 0);
      k_tfold <<<dim3(24, 32, 1), tb, 0, stream>>>(wo  + (size_t)di*1024*768, nullptr, dwo, 1024, 768, 0, 0, 0);
      qkvlT_p = dq; kvxT_p = dkvx; woT_p = dwo;
    }
  };
  auto ffW = [&](int d, const bf16*& w1p, const bf16*& w2p) {
    if (fullw) {
      w1p = w1T + (size_t)d * 3072 * 768;
      w2p = w2T + (size_t)d * 768 * 3072;
    } else {
      bf16* d1 = wbuf;
      bf16* d2 = wbuf + 3072ull * 768;
      k_tfold<<<dim3(96, 24, 1), tb, 0, stream>>>(ffw1 + (size_t)d*768*3072, fflnw + 768ull*d, d1,  768, 3072, 0, 0, 0);
      k_tfold<<<dim3(24, 96, 1), tb, 0, stream>>>(ffw2 + (size_t)d*3072*768, nullptr,          d2, 3072,  768, 0, 0, 0);
      w1p = d1; w2p = d2;
    }
  };

  // ---- feature projection + standardize ----
  for (int i = 0; i < 4; ++i) {
    int n1 = N1S[i], frd = FRDS[i];
    size_t cnt = (size_t)16 * n1 * frd;
    k_cvt<<<(int)(cnt / 1024), 256, 0, stream>>>(f_in[i], fbf[i], (int)(cnt / 4));
    for (int b0 = 0; b0 < 16; b0 += bc) {
      int rows = bc * n1;
      gemm(pick(rows, 768), fbf[i] + (size_t)b0 * n1 * frd, pT[i], featf32,
           pb_in[i], nullptr, rows, 768, frd, false, false);
      k_std<<<rows, 256, 0, stream>>>(featf32, zfeat[i] + (size_t)b0 * n1 * 768);
    }
  }

  hipMemcpyAsync(lat, id_emb, 1024ull * 768 * 4, hipMemcpyDeviceToDevice, stream);

  // ---- depth loop ----
  for (int d = 0; d < 6; ++d) {
    for (int i = 0; i < 4; ++i) {
      int di = d * 4 + i, n1 = N1S[i];
      const bf16 *qkvlT_p, *kvxT_p, *woT_p;
      attnW(di, qkvlT_p, kvxT_p, woT_p);
      k_std<<<1024, 256, 0, stream>>>(lat, zlat);
      gemm(64, zlat, qkvlT_p, qkvl_act, qkvl_bias + 3072ull * di, nullptr,
           1024, 3072, 768, true, false);
      for (int b0 = 0; b0 < 16; b0 += bc) {
        int rows = bc * n1;
        gemm(pick(rows, 2048), zfeat[i] + (size_t)b0 * n1 * 768, kvxT_p, kvxbuf,
             kvx_bias + 2048ull * di, nullptr, rows, 2048, 768, true, false);
        k_attn<<<bc * 16, 256, 0, stream>>>(qkvl_act, kvxbuf, attnout, n1, b0);
      }
      gemm(32, attnout, woT_p, lat, nullptr, lat, 1024, 768, 1024, false, false);
    }
    const bf16 *w1p, *w2p;
    ffW(d, w1p, w2p);
    k_std<<<1024, 256, 0, stream>>>(lat, zlat);
    gemm(64, zlat, w1p, ffh, ff_bias + 3072ull * d, nullptr, 1024, 3072, 768, true, true);
    gemm(32, ffh, w2p, lat, nullptr, lat, 1024, 768, 3072, false, false);
  }

  // ---- head ----
  k_cvt<<<768, 256, 0, stream>>>(lat, latbf, 196608);
  gemm(32, latbf, projT, headtmp, projb, nullptr, 1024, 768, 768, false, false);
  k_lnout<<<1024, 256, 0, stream>>>(headtmp, normw, normb, (float*)d_out);
}

// Round 6
// 6094.438 us; speedup vs baseline: 1.1101x; 1.1101x over previous
//
#include <hip/hip_runtime.h>
#include <hip/hip_bf16.h>
#include <cstdint>
#include <cstddef>

typedef __hip_bfloat16 bf16;
typedef float  f32x4   __attribute__((ext_vector_type(4)));
typedef float  float4v __attribute__((ext_vector_type(4)));
typedef short  short8  __attribute__((ext_vector_type(8)));
typedef short  short4v __attribute__((ext_vector_type(4)));
typedef __bf16 bf16x8  __attribute__((ext_vector_type(8)));

__device__ __forceinline__ void mfma16(f32x4& d, short8 a, short8 b) {
  d = __builtin_amdgcn_mfma_f32_16x16x32_bf16(
      __builtin_bit_cast(bf16x8, a), __builtin_bit_cast(bf16x8, b), d, 0, 0, 0);
}
__device__ __forceinline__ unsigned short f2b_bits(float x) {
  __hip_bfloat16 h = __float2bfloat16(x);
  return __builtin_bit_cast(unsigned short, h);
}
__device__ __forceinline__ float gelu_exact(float x) {
  return 0.5f * x * (1.0f + erff(x * 0.7071067811865475f));
}

// ---------- f32 -> bf16 convert, 4 elems/thread ----------
__global__ __launch_bounds__(256) void k_cvt(const float* __restrict__ src,
                                             bf16* __restrict__ dst, int n4) {
  int i = blockIdx.x * 256 + threadIdx.x;
  if (i >= n4) return;
  float4v v = *(const float4v*)(src + (size_t)i * 4);
  short4v s;
  s[0] = (short)f2b_bits(v[0]); s[1] = (short)f2b_bits(v[1]);
  s[2] = (short)f2b_bits(v[2]); s[3] = (short)f2b_bits(v[3]);
  *(short4v*)((short*)dst + (size_t)i * 4) = s;
}

// ---------- transpose (+optional per-k scale): f32 (K,N) -> bf16 (N,K) ----------
__global__ void k_tfold(const float* __restrict__ src, const float* __restrict__ scale,
                        bf16* __restrict__ dst, int K, int N,
                        long long src_bs, long long scale_bs, long long dst_bs) {
  src += (size_t)blockIdx.z * src_bs;
  dst += (size_t)blockIdx.z * dst_bs;
  const float* sc = scale ? scale + (size_t)blockIdx.z * scale_bs : nullptr;
  __shared__ float tile[32][33];
  int n0 = blockIdx.x * 32, k0 = blockIdx.y * 32;
  int tx = threadIdx.x, ty = threadIdx.y;
#pragma unroll
  for (int j = 0; j < 4; ++j) {
    int k = k0 + ty + j * 8;
    float s = sc ? sc[k] : 1.0f;
    tile[ty + j * 8][tx] = src[(size_t)k * N + n0 + tx] * s;
  }
  __syncthreads();
#pragma unroll
  for (int j = 0; j < 4; ++j) {
    int n = n0 + ty + j * 8;
    dst[(size_t)n * K + k0 + tx] = __float2bfloat16(tile[tx][ty + j * 8]);
  }
}

// ---------- dual transpose-fold: read W once, write two scaled transposes ----------
__global__ void k_tfold2(const float* __restrict__ src,
                         const float* __restrict__ s1, const float* __restrict__ s2,
                         bf16* __restrict__ d1, bf16* __restrict__ d2, int K, int N,
                         long long src_bs, long long s_bs,
                         long long d1_bs, long long d2_bs) {
  src += (size_t)blockIdx.z * src_bs;
  d1  += (size_t)blockIdx.z * d1_bs;
  d2  += (size_t)blockIdx.z * d2_bs;
  s1  += (size_t)blockIdx.z * s_bs;
  s2  += (size_t)blockIdx.z * s_bs;
  __shared__ float tile[32][33];
  __shared__ float sc1[32], sc2[32];
  int n0 = blockIdx.x * 32, k0 = blockIdx.y * 32;
  int tx = threadIdx.x, ty = threadIdx.y;
  if (ty == 0) { sc1[tx] = s1[k0 + tx]; sc2[tx] = s2[k0 + tx]; }
#pragma unroll
  for (int j = 0; j < 4; ++j) {
    int k = k0 + ty + j * 8;
    tile[ty + j * 8][tx] = src[(size_t)k * N + n0 + tx];
  }
  __syncthreads();
#pragma unroll
  for (int j = 0; j < 4; ++j) {
    int n = n0 + ty + j * 8;
    float v = tile[tx][ty + j * 8];
    d1[(size_t)n * K + k0 + tx] = __float2bfloat16(v * sc1[tx]);
    d2[(size_t)n * K + k0 + tx] = __float2bfloat16(v * sc2[tx]);
  }
}

// ---------- bias fold: out[n] = sum_k lnb[k]*W[k][n], k-parallel ----------
__global__ __launch_bounds__(256) void k_bfold(const float* __restrict__ W,
                                               const float* __restrict__ lnb,
                                               float* __restrict__ out, int K, int N,
                                               long long w_bs, long long b_bs, long long o_bs) {
  W   += (size_t)blockIdx.y * w_bs;
  lnb += (size_t)blockIdx.y * b_bs;
  out += (size_t)blockIdx.y * o_bs;
  const int l = threadIdx.x & 63, kg = threadIdx.x >> 6;
  const int n = blockIdx.x * 64 + l;
  float a = 0.0f;
  for (int k = kg; k < K; k += 4) a = fmaf(lnb[k], W[(size_t)k * N + n], a);
  __shared__ float red[4][64];
  red[kg][l] = a;
  __syncthreads();
  if (kg == 0) out[n] = (red[0][l] + red[1][l]) + (red[2][l] + red[3][l]);
}

// ---------- dual bias fold ----------
__global__ __launch_bounds__(256) void k_bfold2(const float* __restrict__ W,
                                                const float* __restrict__ b1,
                                                const float* __restrict__ b2,
                                                float* __restrict__ o1,
                                                float* __restrict__ o2, int K, int N,
                                                long long w_bs, long long b_bs,
                                                long long o1_bs, long long o2_bs) {
  W  += (size_t)blockIdx.y * w_bs;
  b1 += (size_t)blockIdx.y * b_bs;
  b2 += (size_t)blockIdx.y * b_bs;
  o1 += (size_t)blockIdx.y * o1_bs;
  o2 += (size_t)blockIdx.y * o2_bs;
  const int l = threadIdx.x & 63, kg = threadIdx.x >> 6;
  const int n = blockIdx.x * 64 + l;
  float a1 = 0.0f, a2 = 0.0f;
  for (int k = kg; k < K; k += 4) {
    float wv = W[(size_t)k * N + n];
    a1 = fmaf(b1[k], wv, a1);
    a2 = fmaf(b2[k], wv, a2);
  }
  __shared__ float r1[4][64], r2[4][64];
  r1[kg][l] = a1; r2[kg][l] = a2;
  __syncthreads();
  if (kg == 0) {
    o1[n] = (r1[0][l] + r1[1][l]) + (r1[2][l] + r1[3][l]);
    o2[n] = (r2[0][l] + r2[1][l]) + (r2[2][l] + r2[3][l]);
  }
}

// ---------- row standardize (768-wide), f32 -> bf16 ----------
__global__ __launch_bounds__(256) void k_std(const float* __restrict__ src,
                                             bf16* __restrict__ dst) {
  int row = blockIdx.x;
  const float* x = src + (size_t)row * 768;
  int t = threadIdx.x;
  float a0 = x[t], a1 = x[t + 256], a2 = x[t + 512];
  float s = a0 + a1 + a2;
  float q = a0 * a0 + a1 * a1 + a2 * a2;
#pragma unroll
  for (int off = 1; off < 64; off <<= 1) { s += __shfl_xor(s, off); q += __shfl_xor(q, off); }
  __shared__ float ss[4], qs[4];
  if ((t & 63) == 0) { ss[t >> 6] = s; qs[t >> 6] = q; }
  __syncthreads();
  s = ss[0] + ss[1] + ss[2] + ss[3];
  q = qs[0] + qs[1] + qs[2] + qs[3];
  float mean = s * (1.0f / 768.0f);
  float var  = q * (1.0f / 768.0f) - mean * mean;
  float inv  = rsqrtf(var + 1e-5f);
  bf16* d = dst + (size_t)row * 768;
  d[t]       = __float2bfloat16((a0 - mean) * inv);
  d[t + 256] = __float2bfloat16((a1 - mean) * inv);
  d[t + 512] = __float2bfloat16((a2 - mean) * inv);
}

// ---------- final layernorm (768-wide) with w,b: f32 -> f32 ----------
__global__ __launch_bounds__(256) void k_lnout(const float* __restrict__ src,
                                               const float* __restrict__ w,
                                               const float* __restrict__ b,
                                               float* __restrict__ dst) {
  int row = blockIdx.x;
  const float* x = src + (size_t)row * 768;
  int t = threadIdx.x;
  float a0 = x[t], a1 = x[t + 256], a2 = x[t + 512];
  float s = a0 + a1 + a2;
  float q = a0 * a0 + a1 * a1 + a2 * a2;
#pragma unroll
  for (int off = 1; off < 64; off <<= 1) { s += __shfl_xor(s, off); q += __shfl_xor(q, off); }
  __shared__ float ss[4], qs[4];
  if ((t & 63) == 0) { ss[t >> 6] = s; qs[t >> 6] = q; }
  __syncthreads();
  s = ss[0] + ss[1] + ss[2] + ss[3];
  q = qs[0] + qs[1] + qs[2] + qs[3];
  float mean = s * (1.0f / 768.0f);
  float var  = q * (1.0f / 768.0f) - mean * mean;
  float inv  = rsqrtf(var + 1e-5f);
  float* d = dst + (size_t)row * 768;
  d[t]       = (a0 - mean) * inv * w[t]       + b[t];
  d[t + 256] = (a1 - mean) * inv * w[t + 256] + b[t + 256];
  d[t + 512] = (a2 - mean) * inv * w[t + 512] + b[t + 512];
}

// ---------- MFMA GEMM: C(M,N) = A(M,K)bf16 @ Bt(N,K)bf16 [+bias][gelu][+res f32] ----------
// R3 reg-staged pipeline (32KB-class LDS, loads in VGPR flight across MFMA phase)
// + R4 1-D N-fastest grid with bijective XCD swizzle.
template <int BM, int BN, bool OBF16, bool GELU>
__global__ __launch_bounds__(256) void k_gemm(const bf16* __restrict__ A,
                                              const bf16* __restrict__ Bt,
                                              void* __restrict__ Cv,
                                              const float* __restrict__ bias,
                                              const float* __restrict__ res,
                                              int M, int N, int K, int nxt, int nwg) {
  constexpr int AI = BM / 32, BI = BN / 32;
  constexpr int MF = BM / 32, NF = BN / 32;
  __shared__ __align__(16) char As[BM * 128];
  __shared__ __align__(16) char Bs[BN * 128];

  const int lin = blockIdx.x;
  const int qq = nwg >> 3, r8 = nwg & 7;
  const int xcd = lin & 7, idx = lin >> 3;
  const int swz = (xcd < r8) ? (xcd * (qq + 1) + idx)
                             : (r8 * (qq + 1) + (xcd - r8) * qq + idx);
  const int bm = (swz / nxt) * BM, bn = (swz % nxt) * BN;

  const int t = threadIdx.x, lane = t & 63, w = t >> 6;
  const int wr = w >> 1, wc = w & 1;
  const int l15 = lane & 15, lg = lane >> 4;
  const int srow = t >> 3, scol = t & 7;

  const bf16* aptr[AI]; int aoff[AI];
#pragma unroll
  for (int i = 0; i < AI; ++i) {
    int r = i * 32 + srow;
    int gr = bm + r; if (gr > M - 1) gr = M - 1;
    aptr[i] = A + (size_t)gr * K + scol * 8;
    aoff[i] = r * 128 + ((scol * 16) ^ ((r & 7) << 4));
  }
  const bf16* bptr[BI]; int boff[BI];
#pragma unroll
  for (int i = 0; i < BI; ++i) {
    int r = i * 32 + srow;
    int gc = bn + r; if (gc > N - 1) gc = N - 1;
    bptr[i] = Bt + (size_t)gc * K + scol * 8;
    boff[i] = r * 128 + ((scol * 16) ^ ((r & 7) << 4));
  }

  f32x4 acc[MF][NF] = {};
  short8 av[AI], bv[BI];
#pragma unroll
  for (int i = 0; i < AI; ++i) av[i] = *(const short8*)(aptr[i]);
#pragma unroll
  for (int i = 0; i < BI; ++i) bv[i] = *(const short8*)(bptr[i]);

  const int nk = K / 64;
  for (int kt = 0; kt < nk; ++kt) {
    __syncthreads();
#pragma unroll
    for (int i = 0; i < AI; ++i) *(short8*)(As + aoff[i]) = av[i];
#pragma unroll
    for (int i = 0; i < BI; ++i) *(short8*)(Bs + boff[i]) = bv[i];
    __syncthreads();
    if (kt + 1 < nk) {
#pragma unroll
      for (int i = 0; i < AI; ++i) av[i] = *(const short8*)(aptr[i] + (size_t)(kt + 1) * 64);
#pragma unroll
      for (int i = 0; i < BI; ++i) bv[i] = *(const short8*)(bptr[i] + (size_t)(kt + 1) * 64);
    }
#pragma unroll
    for (int ks = 0; ks < 2; ++ks) {
      short8 af[MF], bfr[NF];
#pragma unroll
      for (int m = 0; m < MF; ++m) {
        int r = wr * (BM / 2) + m * 16 + l15;
        af[m] = *(const short8*)(As + r * 128 + ((ks * 64 + lg * 16) ^ ((r & 7) << 4)));
      }
#pragma unroll
      for (int n = 0; n < NF; ++n) {
        int r = wc * (BN / 2) + n * 16 + l15;
        bfr[n] = *(const short8*)(Bs + r * 128 + ((ks * 64 + lg * 16) ^ ((r & 7) << 4)));
      }
#pragma unroll
      for (int m = 0; m < MF; ++m)
#pragma unroll
        for (int n = 0; n < NF; ++n) mfma16(acc[m][n], af[m], bfr[n]);
    }
  }

#pragma unroll
  for (int m = 0; m < MF; ++m) {
    int gr0 = bm + wr * (BM / 2) + m * 16 + lg * 4;
#pragma unroll
    for (int n = 0; n < NF; ++n) {
      int gc = bn + wc * (BN / 2) + n * 16 + l15;
      float bvs = bias ? bias[gc] : 0.0f;
#pragma unroll
      for (int r = 0; r < 4; ++r) {
        int gr = gr0 + r;
        if (gr < M) {
          float v = acc[m][n][r] + bvs;
          if (GELU) v = gelu_exact(v);
          if (res) v += res[(size_t)gr * N + gc];
          if (OBF16) ((bf16*)Cv)[(size_t)gr * N + gc] = __float2bfloat16(v);
          else       ((float*)Cv)[(size_t)gr * N + gc] = v;
        }
      }
    }
  }
}

// ---------- fused attention: one block per (local b, h); 4 waves, 16 q-rows each ----------
__global__ __launch_bounds__(256) void k_attn(const bf16* __restrict__ qkvl,
                                              const bf16* __restrict__ kvx,
                                              bf16* __restrict__ outp, int n1, int b0) {
  const int bh = blockIdx.x;
  const int bl = bh >> 4, h = bh & 15;
  const int b = b0 + bl;
  __shared__ __align__(16) char Qs[64 * 128];
  __shared__ __align__(16) char Ks[64 * 128];
  __shared__ __align__(16) char Vt[64 * 128];
  __shared__ __align__(16) char Ps[4][16 * 128];
  const int t = threadIdx.x, lane = t & 63, w = t >> 6;
  const int l15 = lane & 15, lg = lane >> 4;

#pragma unroll
  for (int it = 0; it < 2; ++it) {
    int slot = it * 256 + t; int r = slot >> 3, c = slot & 7;
    short8 v = *(const short8*)(qkvl + (size_t)(b * 64 + r) * 3072 + h * 64 + c * 8);
    *(short8*)(Qs + r * 128 + ((c * 16) ^ ((r & 7) << 4))) = v;
  }
  const int n_kv = n1 + 64;
  const int nch = (n_kv + 63) >> 6;
  float m_run[4], l_run[4];
  f32x4 o[4] = {};
#pragma unroll
  for (int r = 0; r < 4; ++r) { m_run[r] = -1e30f; l_run[r] = 0.0f; }

  short8 kreg[2], vreg[2];
  auto loadKV = [&](int ch) {
#pragma unroll
    for (int it = 0; it < 2; ++it) {
      int slot = it * 256 + t; int rr = slot >> 3, c = slot & 7;
      int j = ch * 64 + rr;
      short8 kv = {}; short8 vv = {};
      if (j < n_kv) {
        const bf16* kb;
        if (j < n1) kb = kvx + (size_t)(bl * n1 + j) * 2048 + h * 64;
        else        kb = qkvl + (size_t)(b * 64 + (j - n1)) * 3072 + 1024 + h * 64;
        kv = *(const short8*)(kb + c * 8);
        vv = *(const short8*)(kb + 1024 + c * 8);
      }
      kreg[it] = kv; vreg[it] = vv;
    }
  };
  loadKV(0);

  for (int ch = 0; ch < nch; ++ch) {
    __syncthreads();
#pragma unroll
    for (int it = 0; it < 2; ++it) {
      int slot = it * 256 + t; int rr = slot >> 3, c = slot & 7;
      *(short8*)(Ks + rr * 128 + ((c * 16) ^ ((rr & 7) << 4))) = kreg[it];
#pragma unroll
      for (int j2 = 0; j2 < 8; ++j2) {
        int dh = c * 8 + j2;
        *(short*)(Vt + dh * 128 + ((rr * 2) ^ ((dh & 7) << 4))) = vreg[it][j2];
      }
    }
    __syncthreads();
    if (ch + 1 < nch) loadKV(ch + 1);

    f32x4 s[4] = {};
#pragma unroll
    for (int ks = 0; ks < 2; ++ks) {
      int qr = w * 16 + l15;
      short8 qf = *(const short8*)(Qs + qr * 128 + ((ks * 64 + lg * 16) ^ ((qr & 7) << 4)));
#pragma unroll
      for (int n = 0; n < 4; ++n) {
        int kr = n * 16 + l15;
        short8 kf = *(const short8*)(Ks + kr * 128 + ((ks * 64 + lg * 16) ^ ((kr & 7) << 4)));
        mfma16(s[n], qf, kf);
      }
    }
    float p[4][4];
#pragma unroll
    for (int r = 0; r < 4; ++r) {
      float mx = m_run[r];
#pragma unroll
      for (int n = 0; n < 4; ++n) {
        float v = s[n][r] * 0.125f;
        int kvi = ch * 64 + n * 16 + l15;
        if (kvi >= n_kv) v = -1e30f;
        s[n][r] = v;
        mx = fmaxf(mx, v);
      }
#pragma unroll
      for (int off = 1; off < 16; off <<= 1) mx = fmaxf(mx, __shfl_xor(mx, off));
      float scl = __expf(m_run[r] - mx);
      m_run[r] = mx;
      float rs = 0.0f;
#pragma unroll
      for (int n = 0; n < 4; ++n) { float pv = __expf(s[n][r] - mx); p[n][r] = pv; rs += pv; }
#pragma unroll
      for (int off = 1; off < 16; off <<= 1) rs += __shfl_xor(rs, off);
      l_run[r] = l_run[r] * scl + rs;
#pragma unroll
      for (int nn = 0; nn < 4; ++nn) o[nn][r] *= scl;
    }
#pragma unroll
    for (int n = 0; n < 4; ++n)
#pragma unroll
      for (int r = 0; r < 4; ++r) {
        int q = lg * 4 + r; int kv = n * 16 + l15;
        *(unsigned short*)(Ps[w] + q * 128 + ((kv * 2) ^ ((q & 7) << 4))) = f2b_bits(p[n][r]);
      }
#pragma unroll
    for (int ks = 0; ks < 2; ++ks) {
      short8 pf = *(const short8*)(Ps[w] + l15 * 128 + ((ks * 64 + lg * 16) ^ ((l15 & 7) << 4)));
#pragma unroll
      for (int nn = 0; nn < 4; ++nn) {
        int dh = nn * 16 + l15;
        short8 vf = *(const short8*)(Vt + dh * 128 + ((ks * 64 + lg * 16) ^ ((dh & 7) << 4)));
        mfma16(o[nn], pf, vf);
      }
    }
  }
#pragma unroll
  for (int nn = 0; nn < 4; ++nn)
#pragma unroll
    for (int r = 0; r < 4; ++r) {
      int qr = w * 16 + lg * 4 + r;
      int dh = nn * 16 + l15;
      float v = o[nn][r] / l_run[r];
      outp[(size_t)(b * 64 + qr) * 1024 + h * 64 + dh] = __float2bfloat16(v);
    }
}

// =========================== host ===========================
extern "C" void kernel_launch(void* const* d_in, const int* in_sizes, int n_in,
                              void* d_out, int out_size, void* d_ws, size_t ws_size,
                              hipStream_t stream) {
  (void)in_sizes; (void)n_in; (void)out_size;
  const float* id_emb = (const float*)d_in[0];
  const float* f_in[4]  = {(const float*)d_in[4],  (const float*)d_in[3],
                           (const float*)d_in[2],  (const float*)d_in[1]};
  const float* pw_in[4] = {(const float*)d_in[11], (const float*)d_in[9],
                           (const float*)d_in[7],  (const float*)d_in[5]};
  const float* pb_in[4] = {(const float*)d_in[12], (const float*)d_in[10],
                           (const float*)d_in[8],  (const float*)d_in[6]};
  const float* ln1w = (const float*)d_in[13];
  const float* ln1b = (const float*)d_in[14];
  const float* ln2w = (const float*)d_in[15];
  const float* ln2b = (const float*)d_in[16];
  const float* wq   = (const float*)d_in[17];
  const float* wkv  = (const float*)d_in[18];
  const float* wo   = (const float*)d_in[19];
  const float* fflnw = (const float*)d_in[20];
  const float* fflnb = (const float*)d_in[21];
  const float* ffw1  = (const float*)d_in[22];
  const float* ffw2  = (const float*)d_in[23];
  const float* projw = (const float*)d_in[24];
  const float* projb = (const float*)d_in[25];
  const float* normw = (const float*)d_in[26];
  const float* normb = (const float*)d_in[27];

  static const int N1S[4]  = {49, 196, 784, 3136};
  static const int FRDS[4] = {512, 256, 128, 64};
  const size_t LW = 4718592;   // lean per-scale weight block (elems): 3072*768 + 2048*768 + 768*1024

  bf16 *zfeat[4], *fbf[4], *pT[4], *projT;
  float *qkvl_bias, *kvx_bias, *ff_bias, *lat, *headtmp;
  bf16 *qkvl_act, *attnout, *zlat, *latbf, *ffh;
  bf16 *wqkvlT = nullptr, *wkvxT = nullptr, *woT = nullptr, *w1T = nullptr, *w2T = nullptr;
  bf16 *wbuf = nullptr;
  char *big;

  auto assign = [&](bool fullw, int bc) -> size_t {
    size_t off = 0; char* base = (char*)d_ws;
    auto A = [&](size_t b) -> char* {
      char* p = base + off; off = (off + b + 255) & ~(size_t)255; return p;
    };
    for (int i = 0; i < 4; ++i) zfeat[i] = (bf16*)A((size_t)16 * N1S[i] * 768 * 2);
    for (int i = 0; i < 4; ++i) fbf[i]   = (bf16*)A((size_t)16 * N1S[i] * FRDS[i] * 2);
    for (int i = 0; i < 4; ++i) pT[i]    = (bf16*)A((size_t)768 * FRDS[i] * 2);
    projT     = (bf16*)A(768ull * 768 * 2);
    qkvl_bias = (float*)A(24ull * 3072 * 4);
    kvx_bias  = (float*)A(24ull * 2048 * 4);
    ff_bias   = (float*)A(6ull * 3072 * 4);
    qkvl_act  = (bf16*)A(1024ull * 3072 * 2);
    attnout   = (bf16*)A(1024ull * 1024 * 2);
    lat       = (float*)A(1024ull * 768 * 4);
    zlat      = (bf16*)A(1024ull * 768 * 2);
    if (fullw) {
      wqkvlT = (bf16*)A(24ull * 3072 * 768 * 2);
      wkvxT  = (bf16*)A(24ull * 2048 * 768 * 2);
      woT    = (bf16*)A(24ull * 768 * 1024 * 2);
      w1T    = (bf16*)A(6ull * 3072 * 768 * 2);
      w2T    = (bf16*)A(6ull * 768 * 3072 * 2);
      wbuf = nullptr;
    } else {
      wbuf = (bf16*)A(4ull * LW * 2);   // 4 scales of one depth, folded together
      wqkvlT = wkvxT = woT = w1T = w2T = nullptr;
    }
    big = A((size_t)bc * 3136 * 2048 * 2);
    ffh = qkvl_act; headtmp = (float*)qkvl_act; latbf = zlat;
    return off;
  };

  static const bool FULLS[10] = {true,true,false,true,false,true,true,false,false,false};
  static const int  BCS[10]   = {16,  8,   16,   4,   8,    2,   1,   4,    2,    1};
  bool fullw = false; int bc = 1; bool ok = false;
  for (int c = 0; c < 10; ++c) {
    if (assign(FULLS[c], BCS[c]) <= ws_size) { fullw = FULLS[c]; bc = BCS[c]; ok = true; break; }
  }
  if (!ok) return;

  float* featf32 = (float*)big;
  bf16*  kvxbuf  = (bf16*)big;

  auto gemm = [&](int tile, const bf16* A, const bf16* Bt, void* C,
                  const float* bias, const float* res, int M, int N, int K,
                  bool obf, bool gl) {
    if (tile == 128) {
      int nxt = N / 128, nwg = nxt * ((M + 127) / 128);
      if (obf && gl) k_gemm<128,128,true ,true ><<<nwg,256,0,stream>>>(A,Bt,C,bias,res,M,N,K,nxt,nwg);
      else if (obf)  k_gemm<128,128,true ,false><<<nwg,256,0,stream>>>(A,Bt,C,bias,res,M,N,K,nxt,nwg);
      else           k_gemm<128,128,false,false><<<nwg,256,0,stream>>>(A,Bt,C,bias,res,M,N,K,nxt,nwg);
    } else if (tile == 64) {
      int nxt = N / 64, nwg = nxt * ((M + 63) / 64);
      if (obf && gl)  k_gemm<64,64,true ,true ><<<nwg,256,0,stream>>>(A,Bt,C,bias,res,M,N,K,nxt,nwg);
      else if (obf)   k_gemm<64,64,true ,false><<<nwg,256,0,stream>>>(A,Bt,C,bias,res,M,N,K,nxt,nwg);
      else            k_gemm<64,64,false,false><<<nwg,256,0,stream>>>(A,Bt,C,bias,res,M,N,K,nxt,nwg);
    } else {
      int nxt = N / 64, nwg = nxt * ((M + 31) / 32);
      if (obf && gl)  k_gemm<32,64,true ,true ><<<nwg,256,0,stream>>>(A,Bt,C,bias,res,M,N,K,nxt,nwg);
      else if (obf)   k_gemm<32,64,true ,false><<<nwg,256,0,stream>>>(A,Bt,C,bias,res,M,N,K,nxt,nwg);
      else            k_gemm<32,64,false,false><<<nwg,256,0,stream>>>(A,Bt,C,bias,res,M,N,K,nxt,nwg);
    }
  };
  auto pick = [&](int M, int N) -> int {
    return M >= 2048 ? 128 : (N >= 1536 ? 64 : 32);
  };

  dim3 tb(32, 8);

  // ---- bias folds (k-parallel GEMV; wkv read ONCE for both LN biases) ----
  k_bfold <<<dim3(16, 24), 256, 0, stream>>>(wq,  ln2b, qkvl_bias, 768, 1024, 768LL*1024, 768, 3072);
  k_bfold2<<<dim3(32, 24), 256, 0, stream>>>(wkv, ln2b, ln1b, qkvl_bias + 1024, kvx_bias,
                                             768, 2048, 768LL*2048, 768, 3072, 2048);
  k_bfold <<<dim3(48, 6),  256, 0, stream>>>(ffw1, fflnb, ff_bias, 768, 3072, 768LL*3072, 768, 3072);

  // ---- small folded weights (always) ----
  for (int i = 0; i < 4; ++i)
    k_tfold<<<dim3(24, FRDS[i] / 32, 1), tb, 0, stream>>>(pw_in[i], nullptr, pT[i], FRDS[i], 768, 0, 0, 0);
  k_tfold<<<dim3(24, 24, 1), tb, 0, stream>>>(projw, nullptr, projT, 768, 768, 0, 0, 0);

  // ---- full-mode weight folds (batched over all 24 layers; wkv read ONCE) ----
  if (fullw) {
    k_tfold <<<dim3(32, 24, 24), tb, 0, stream>>>(wq,  ln2w, wqkvlT, 768, 1024, 768LL*1024, 768, 3072LL*768);
    k_tfold2<<<dim3(64, 24, 24), tb, 0, stream>>>(wkv, ln2w, ln1w, wqkvlT + 1024LL*768, wkvxT,
                                                  768, 2048, 768LL*2048, 768, 3072LL*768, 2048LL*768);
    k_tfold <<<dim3(24, 32, 24), tb, 0, stream>>>(wo,  nullptr, woT, 1024, 768, 1024LL*768, 0, 768LL*1024);
    k_tfold <<<dim3(96, 24, 6),  tb, 0, stream>>>(ffw1, fflnw, w1T, 768, 3072, 768LL*3072, 768, 3072LL*768);
    k_tfold <<<dim3(24, 96, 6),  tb, 0, stream>>>(ffw2, nullptr, w2T, 3072, 768, 3072LL*768, 0, 768LL*3072);
  }

  // ---- lean mode: fold one depth's 4 attn weight sets in 3 batched launches ----
  auto foldDepthAttn = [&](int d) {
    k_tfold <<<dim3(32, 24, 4), tb, 0, stream>>>(wq  + (size_t)d*4*768*1024, ln2w + (size_t)d*4*768,
                                                 wbuf, 768, 1024, 768LL*1024, 768, (long long)LW);
    k_tfold2<<<dim3(64, 24, 4), tb, 0, stream>>>(wkv + (size_t)d*4*768*2048, ln2w + (size_t)d*4*768,
                                                 ln1w + (size_t)d*4*768,
                                                 wbuf + 1024ull*768, wbuf + 3072ull*768,
                                                 768, 2048, 768LL*2048, 768, (long long)LW, (long long)LW);
    k_tfold <<<dim3(24, 32, 4), tb, 0, stream>>>(wo  + (size_t)d*4*1024*768, nullptr,
                                                 wbuf + 3932160ull, 1024, 768, 1024LL*768, 0, (long long)LW);
  };
  auto attnW = [&](int di, const bf16*& qkvlT_p, const bf16*& kvxT_p, const bf16*& woT_p) {
    if (fullw) {
      qkvlT_p = wqkvlT + (size_t)di * 3072 * 768;
      kvxT_p  = wkvxT  + (size_t)di * 2048 * 768;
      woT_p   = woT    + (size_t)di * 768 * 1024;
    } else {
      bf16* base = wbuf + (size_t)(di & 3) * LW;
      qkvlT_p = base;
      kvxT_p  = base + 2359296ull;   // 3072*768
      woT_p   = base + 3932160ull;   // + 2048*768
    }
  };
  auto ffW = [&](int d, const bf16*& w1p, const bf16*& w2p) {
    if (fullw) {
      w1p = w1T + (size_t)d * 3072 * 768;
      w2p = w2T + (size_t)d * 768 * 3072;
    } else {
      bf16* d1 = wbuf;
      bf16* d2 = wbuf + 3072ull * 768;
      k_tfold<<<dim3(96, 24, 1), tb, 0, stream>>>(ffw1 + (size_t)d*768*3072, fflnw + 768ull*d, d1,  768, 3072, 0, 0, 0);
      k_tfold<<<dim3(24, 96, 1), tb, 0, stream>>>(ffw2 + (size_t)d*3072*768, nullptr,          d2, 3072,  768, 0, 0, 0);
      w1p = d1; w2p = d2;
    }
  };

  // ---- feature projection + standardize ----
  for (int i = 0; i < 4; ++i) {
    int n1 = N1S[i], frd = FRDS[i];
    size_t cnt = (size_t)16 * n1 * frd;
    k_cvt<<<(int)(cnt / 1024), 256, 0, stream>>>(f_in[i], fbf[i], (int)(cnt / 4));
    for (int b0 = 0; b0 < 16; b0 += bc) {
      int rows = bc * n1;
      gemm(pick(rows, 768), fbf[i] + (size_t)b0 * n1 * frd, pT[i], featf32,
           pb_in[i], nullptr, rows, 768, frd, false, false);
      k_std<<<rows, 256, 0, stream>>>(featf32, zfeat[i] + (size_t)b0 * n1 * 768);
    }
  }

  hipMemcpyAsync(lat, id_emb, 1024ull * 768 * 4, hipMemcpyDeviceToDevice, stream);

  // ---- depth loop ----
  for (int d = 0; d < 6; ++d) {
    if (!fullw) foldDepthAttn(d);
    for (int i = 0; i < 4; ++i) {
      int di = d * 4 + i, n1 = N1S[i];
      const bf16 *qkvlT_p, *kvxT_p, *woT_p;
      attnW(di, qkvlT_p, kvxT_p, woT_p);
      k_std<<<1024, 256, 0, stream>>>(lat, zlat);
      gemm(64, zlat, qkvlT_p, qkvl_act, qkvl_bias + 3072ull * di, nullptr,
           1024, 3072, 768, true, false);
      for (int b0 = 0; b0 < 16; b0 += bc) {
        int rows = bc * n1;
        gemm(pick(rows, 2048), zfeat[i] + (size_t)b0 * n1 * 768, kvxT_p, kvxbuf,
             kvx_bias + 2048ull * di, nullptr, rows, 2048, 768, true, false);
        k_attn<<<bc * 16, 256, 0, stream>>>(qkvl_act, kvxbuf, attnout, n1, b0);
      }
      gemm(32, attnout, woT_p, lat, nullptr, lat, 1024, 768, 1024, false, false);
    }
    const bf16 *w1p, *w2p;
    ffW(d, w1p, w2p);
    k_std<<<1024, 256, 0, stream>>>(lat, zlat);
    gemm(64, zlat, w1p, ffh, ff_bias + 3072ull * d, nullptr, 1024, 3072, 768, true, true);
    gemm(32, ffh, w2p, lat, nullptr, lat, 1024, 768, 3072, false, false);
  }

  // ---- head ----
  k_cvt<<<768, 256, 0, stream>>>(lat, latbf, 196608);
  gemm(32, latbf, projT, headtmp, projb, nullptr, 1024, 768, 768, false, false);
  k_lnout<<<1024, 256, 0, stream>>>(headtmp, normw, normb, (float*)d_out);
}

// Round 7
// 5342.794 us; speedup vs baseline: 1.2663x; 1.1407x over previous
//
#include <hip/hip_runtime.h>
#include <hip/hip_bf16.h>
#include <cstdint>
#include <cstddef>

typedef __hip_bfloat16 bf16;
typedef float  f32x4   __attribute__((ext_vector_type(4)));
typedef float  float4v __attribute__((ext_vector_type(4)));
typedef short  short8  __attribute__((ext_vector_type(8)));
typedef short  short4v __attribute__((ext_vector_type(4)));
typedef __bf16 bf16x8  __attribute__((ext_vector_type(8)));

__device__ __forceinline__ void mfma16(f32x4& d, short8 a, short8 b) {
  d = __builtin_amdgcn_mfma_f32_16x16x32_bf16(
      __builtin_bit_cast(bf16x8, a), __builtin_bit_cast(bf16x8, b), d, 0, 0, 0);
}
__device__ __forceinline__ unsigned short f2b_bits(float x) {
  __hip_bfloat16 h = __float2bfloat16(x);
  return __builtin_bit_cast(unsigned short, h);
}
__device__ __forceinline__ float gelu_exact(float x) {
  return 0.5f * x * (1.0f + erff(x * 0.7071067811865475f));
}

// ---------- f32 -> bf16 convert, 4 elems/thread ----------
__global__ __launch_bounds__(256) void k_cvt(const float* __restrict__ src,
                                             bf16* __restrict__ dst, int n4) {
  int i = blockIdx.x * 256 + threadIdx.x;
  if (i >= n4) return;
  float4v v = *(const float4v*)(src + (size_t)i * 4);
  short4v s;
  s[0] = (short)f2b_bits(v[0]); s[1] = (short)f2b_bits(v[1]);
  s[2] = (short)f2b_bits(v[2]); s[3] = (short)f2b_bits(v[3]);
  *(short4v*)((short*)dst + (size_t)i * 4) = s;
}

// ---------- transpose (+optional per-k scale): f32 (K,N) -> bf16 (N,K) ----------
__global__ void k_tfold(const float* __restrict__ src, const float* __restrict__ scale,
                        bf16* __restrict__ dst, int K, int N,
                        long long src_bs, long long scale_bs, long long dst_bs) {
  src += (size_t)blockIdx.z * src_bs;
  dst += (size_t)blockIdx.z * dst_bs;
  const float* sc = scale ? scale + (size_t)blockIdx.z * scale_bs : nullptr;
  __shared__ float tile[32][33];
  int n0 = blockIdx.x * 32, k0 = blockIdx.y * 32;
  int tx = threadIdx.x, ty = threadIdx.y;
#pragma unroll
  for (int j = 0; j < 4; ++j) {
    int k = k0 + ty + j * 8;
    float s = sc ? sc[k] : 1.0f;
    tile[ty + j * 8][tx] = src[(size_t)k * N + n0 + tx] * s;
  }
  __syncthreads();
#pragma unroll
  for (int j = 0; j < 4; ++j) {
    int n = n0 + ty + j * 8;
    dst[(size_t)n * K + k0 + tx] = __float2bfloat16(tile[tx][ty + j * 8]);
  }
}

// ---------- dual transpose-fold: read W once, write two scaled transposes ----------
__global__ void k_tfold2(const float* __restrict__ src,
                         const float* __restrict__ s1, const float* __restrict__ s2,
                         bf16* __restrict__ d1, bf16* __restrict__ d2, int K, int N,
                         long long src_bs, long long s_bs,
                         long long d1_bs, long long d2_bs) {
  src += (size_t)blockIdx.z * src_bs;
  d1  += (size_t)blockIdx.z * d1_bs;
  d2  += (size_t)blockIdx.z * d2_bs;
  s1  += (size_t)blockIdx.z * s_bs;
  s2  += (size_t)blockIdx.z * s_bs;
  __shared__ float tile[32][33];
  __shared__ float sc1[32], sc2[32];
  int n0 = blockIdx.x * 32, k0 = blockIdx.y * 32;
  int tx = threadIdx.x, ty = threadIdx.y;
  if (ty == 0) { sc1[tx] = s1[k0 + tx]; sc2[tx] = s2[k0 + tx]; }
#pragma unroll
  for (int j = 0; j < 4; ++j) {
    int k = k0 + ty + j * 8;
    tile[ty + j * 8][tx] = src[(size_t)k * N + n0 + tx];
  }
  __syncthreads();
#pragma unroll
  for (int j = 0; j < 4; ++j) {
    int n = n0 + ty + j * 8;
    float v = tile[tx][ty + j * 8];
    d1[(size_t)n * K + k0 + tx] = __float2bfloat16(v * sc1[tx]);
    d2[(size_t)n * K + k0 + tx] = __float2bfloat16(v * sc2[tx]);
  }
}

// ---------- bias fold: out[n] = sum_k lnb[k]*W[k][n], k-parallel ----------
__global__ __launch_bounds__(256) void k_bfold(const float* __restrict__ W,
                                               const float* __restrict__ lnb,
                                               float* __restrict__ out, int K, int N,
                                               long long w_bs, long long b_bs, long long o_bs) {
  W   += (size_t)blockIdx.y * w_bs;
  lnb += (size_t)blockIdx.y * b_bs;
  out += (size_t)blockIdx.y * o_bs;
  const int l = threadIdx.x & 63, kg = threadIdx.x >> 6;
  const int n = blockIdx.x * 64 + l;
  float a = 0.0f;
  for (int k = kg; k < K; k += 4) a = fmaf(lnb[k], W[(size_t)k * N + n], a);
  __shared__ float red[4][64];
  red[kg][l] = a;
  __syncthreads();
  if (kg == 0) out[n] = (red[0][l] + red[1][l]) + (red[2][l] + red[3][l]);
}

// ---------- dual bias fold ----------
__global__ __launch_bounds__(256) void k_bfold2(const float* __restrict__ W,
                                                const float* __restrict__ b1,
                                                const float* __restrict__ b2,
                                                float* __restrict__ o1,
                                                float* __restrict__ o2, int K, int N,
                                                long long w_bs, long long b_bs,
                                                long long o1_bs, long long o2_bs) {
  W  += (size_t)blockIdx.y * w_bs;
  b1 += (size_t)blockIdx.y * b_bs;
  b2 += (size_t)blockIdx.y * b_bs;
  o1 += (size_t)blockIdx.y * o1_bs;
  o2 += (size_t)blockIdx.y * o2_bs;
  const int l = threadIdx.x & 63, kg = threadIdx.x >> 6;
  const int n = blockIdx.x * 64 + l;
  float a1 = 0.0f, a2 = 0.0f;
  for (int k = kg; k < K; k += 4) {
    float wv = W[(size_t)k * N + n];
    a1 = fmaf(b1[k], wv, a1);
    a2 = fmaf(b2[k], wv, a2);
  }
  __shared__ float r1[4][64], r2[4][64];
  r1[kg][l] = a1; r2[kg][l] = a2;
  __syncthreads();
  if (kg == 0) {
    o1[n] = (r1[0][l] + r1[1][l]) + (r1[2][l] + r1[3][l]);
    o2[n] = (r2[0][l] + r2[1][l]) + (r2[2][l] + r2[3][l]);
  }
}

// ---------- row standardize (768-wide), f32 -> bf16 ----------
__global__ __launch_bounds__(256) void k_std(const float* __restrict__ src,
                                             bf16* __restrict__ dst) {
  int row = blockIdx.x;
  const float* x = src + (size_t)row * 768;
  int t = threadIdx.x;
  float a0 = x[t], a1 = x[t + 256], a2 = x[t + 512];
  float s = a0 + a1 + a2;
  float q = a0 * a0 + a1 * a1 + a2 * a2;
#pragma unroll
  for (int off = 1; off < 64; off <<= 1) { s += __shfl_xor(s, off); q += __shfl_xor(q, off); }
  __shared__ float ss[4], qs[4];
  if ((t & 63) == 0) { ss[t >> 6] = s; qs[t >> 6] = q; }
  __syncthreads();
  s = ss[0] + ss[1] + ss[2] + ss[3];
  q = qs[0] + qs[1] + qs[2] + qs[3];
  float mean = s * (1.0f / 768.0f);
  float var  = q * (1.0f / 768.0f) - mean * mean;
  float inv  = rsqrtf(var + 1e-5f);
  bf16* d = dst + (size_t)row * 768;
  d[t]       = __float2bfloat16((a0 - mean) * inv);
  d[t + 256] = __float2bfloat16((a1 - mean) * inv);
  d[t + 512] = __float2bfloat16((a2 - mean) * inv);
}

// ---------- final layernorm (768-wide) with w,b: f32 -> f32 ----------
__global__ __launch_bounds__(256) void k_lnout(const float* __restrict__ src,
                                               const float* __restrict__ w,
                                               const float* __restrict__ b,
                                               float* __restrict__ dst) {
  int row = blockIdx.x;
  const float* x = src + (size_t)row * 768;
  int t = threadIdx.x;
  float a0 = x[t], a1 = x[t + 256], a2 = x[t + 512];
  float s = a0 + a1 + a2;
  float q = a0 * a0 + a1 * a1 + a2 * a2;
#pragma unroll
  for (int off = 1; off < 64; off <<= 1) { s += __shfl_xor(s, off); q += __shfl_xor(q, off); }
  __shared__ float ss[4], qs[4];
  if ((t & 63) == 0) { ss[t >> 6] = s; qs[t >> 6] = q; }
  __syncthreads();
  s = ss[0] + ss[1] + ss[2] + ss[3];
  q = qs[0] + qs[1] + qs[2] + qs[3];
  float mean = s * (1.0f / 768.0f);
  float var  = q * (1.0f / 768.0f) - mean * mean;
  float inv  = rsqrtf(var + 1e-5f);
  float* d = dst + (size_t)row * 768;
  d[t]       = (a0 - mean) * inv * w[t]       + b[t];
  d[t + 256] = (a1 - mean) * inv * w[t + 256] + b[t + 256];
  d[t + 512] = (a2 - mean) * inv * w[t + 512] + b[t + 512];
}

// ---------- MFMA GEMM (R6 config: reg-staged pipeline + XCD swizzle) ----------
template <int BM, int BN, bool OBF16, bool GELU>
__global__ __launch_bounds__(256) void k_gemm(const bf16* __restrict__ A,
                                              const bf16* __restrict__ Bt,
                                              void* __restrict__ Cv,
                                              const float* __restrict__ bias,
                                              const float* __restrict__ res,
                                              int M, int N, int K, int nxt, int nwg) {
  constexpr int AI = BM / 32, BI = BN / 32;
  constexpr int MF = BM / 32, NF = BN / 32;
  __shared__ __align__(16) char As[BM * 128];
  __shared__ __align__(16) char Bs[BN * 128];

  const int lin = blockIdx.x;
  const int qq = nwg >> 3, r8 = nwg & 7;
  const int xcd = lin & 7, idx = lin >> 3;
  const int swz = (xcd < r8) ? (xcd * (qq + 1) + idx)
                             : (r8 * (qq + 1) + (xcd - r8) * qq + idx);
  const int bm = (swz / nxt) * BM, bn = (swz % nxt) * BN;

  const int t = threadIdx.x, lane = t & 63, w = t >> 6;
  const int wr = w >> 1, wc = w & 1;
  const int l15 = lane & 15, lg = lane >> 4;
  const int srow = t >> 3, scol = t & 7;

  const bf16* aptr[AI]; int aoff[AI];
#pragma unroll
  for (int i = 0; i < AI; ++i) {
    int r = i * 32 + srow;
    int gr = bm + r; if (gr > M - 1) gr = M - 1;
    aptr[i] = A + (size_t)gr * K + scol * 8;
    aoff[i] = r * 128 + ((scol * 16) ^ ((r & 7) << 4));
  }
  const bf16* bptr[BI]; int boff[BI];
#pragma unroll
  for (int i = 0; i < BI; ++i) {
    int r = i * 32 + srow;
    int gc = bn + r; if (gc > N - 1) gc = N - 1;
    bptr[i] = Bt + (size_t)gc * K + scol * 8;
    boff[i] = r * 128 + ((scol * 16) ^ ((r & 7) << 4));
  }

  f32x4 acc[MF][NF] = {};
  short8 av[AI], bv[BI];
#pragma unroll
  for (int i = 0; i < AI; ++i) av[i] = *(const short8*)(aptr[i]);
#pragma unroll
  for (int i = 0; i < BI; ++i) bv[i] = *(const short8*)(bptr[i]);

  const int nk = K / 64;
  for (int kt = 0; kt < nk; ++kt) {
    __syncthreads();
#pragma unroll
    for (int i = 0; i < AI; ++i) *(short8*)(As + aoff[i]) = av[i];
#pragma unroll
    for (int i = 0; i < BI; ++i) *(short8*)(Bs + boff[i]) = bv[i];
    __syncthreads();
    if (kt + 1 < nk) {
#pragma unroll
      for (int i = 0; i < AI; ++i) av[i] = *(const short8*)(aptr[i] + (size_t)(kt + 1) * 64);
#pragma unroll
      for (int i = 0; i < BI; ++i) bv[i] = *(const short8*)(bptr[i] + (size_t)(kt + 1) * 64);
    }
#pragma unroll
    for (int ks = 0; ks < 2; ++ks) {
      short8 af[MF], bfr[NF];
#pragma unroll
      for (int m = 0; m < MF; ++m) {
        int r = wr * (BM / 2) + m * 16 + l15;
        af[m] = *(const short8*)(As + r * 128 + ((ks * 64 + lg * 16) ^ ((r & 7) << 4)));
      }
#pragma unroll
      for (int n = 0; n < NF; ++n) {
        int r = wc * (BN / 2) + n * 16 + l15;
        bfr[n] = *(const short8*)(Bs + r * 128 + ((ks * 64 + lg * 16) ^ ((r & 7) << 4)));
      }
#pragma unroll
      for (int m = 0; m < MF; ++m)
#pragma unroll
        for (int n = 0; n < NF; ++n) mfma16(acc[m][n], af[m], bfr[n]);
    }
  }

#pragma unroll
  for (int m = 0; m < MF; ++m) {
    int gr0 = bm + wr * (BM / 2) + m * 16 + lg * 4;
#pragma unroll
    for (int n = 0; n < NF; ++n) {
      int gc = bn + wc * (BN / 2) + n * 16 + l15;
      float bvs = bias ? bias[gc] : 0.0f;
#pragma unroll
      for (int r = 0; r < 4; ++r) {
        int gr = gr0 + r;
        if (gr < M) {
          float v = acc[m][n][r] + bvs;
          if (GELU) v = gelu_exact(v);
          if (res) v += res[(size_t)gr * N + gc];
          if (OBF16) ((bf16*)Cv)[(size_t)gr * N + gc] = __float2bfloat16(v);
          else       ((float*)Cv)[(size_t)gr * N + gc] = v;
        }
      }
    }
  }
}

// ---------- fused attention, split-KV + swapped-QK^T softmax ----------
// grid = nbloc*16*nseg blocks; block (bl,h,seg). If nseg==1 writes bf16 outp
// directly; else writes f32 partial O (unnormalized) + per-row (m,l).
__global__ __launch_bounds__(256) void k_attn(const bf16* __restrict__ qkvl,
                                              const bf16* __restrict__ kvx,
                                              bf16* __restrict__ outp,
                                              float* __restrict__ opart,
                                              float* __restrict__ mlpart,
                                              int n1, int b0, int nseg, int nbloc) {
  const int s   = blockIdx.x % nseg;
  const int bh  = blockIdx.x / nseg;
  const int bl = bh >> 4, h = bh & 15;
  const int b = b0 + bl;
  const int nb64 = nbloc * 64;
  __shared__ __align__(16) char Qs[64 * 128];
  __shared__ __align__(16) char Ks[64 * 128];
  __shared__ __align__(16) char Vt[64 * 128];
  __shared__ __align__(16) char Ps[4][16 * 128];
  const int t = threadIdx.x, lane = t & 63, w = t >> 6;
  const int l15 = lane & 15, lg = lane >> 4;

#pragma unroll
  for (int it = 0; it < 2; ++it) {
    int slot = it * 256 + t; int r = slot >> 3, c = slot & 7;
    short8 v = *(const short8*)(qkvl + (size_t)(b * 64 + r) * 3072 + h * 64 + c * 8);
    *(short8*)(Qs + r * 128 + ((c * 16) ^ ((r & 7) << 4))) = v;
  }
  const int n_kv = n1 + 64;
  const int nch = (n_kv + 63) >> 6;
  const int cpseg = (nch + nseg - 1) / nseg;
  const int ch0 = s * cpseg;
  const int ch1 = min(nch, ch0 + cpseg);

  float m_run = -1e30f, l_run = 0.0f;   // stats for q-row = w*16 + l15
  f32x4 o[4] = {};                       // o[nn][r] = O[q=w*16+lg*4+r][dh=nn*16+l15]

  short8 kreg[2], vreg[2];
  auto loadKV = [&](int ch) {
#pragma unroll
    for (int it = 0; it < 2; ++it) {
      int slot = it * 256 + t; int rr = slot >> 3, c = slot & 7;
      int j = ch * 64 + rr;
      short8 kv = {}; short8 vv = {};
      if (j < n_kv) {
        const bf16* kb;
        if (j < n1) kb = kvx + (size_t)(bl * n1 + j) * 2048 + h * 64;
        else        kb = qkvl + (size_t)(b * 64 + (j - n1)) * 3072 + 1024 + h * 64;
        kv = *(const short8*)(kb + c * 8);
        vv = *(const short8*)(kb + 1024 + c * 8);
      }
      kreg[it] = kv; vreg[it] = vv;
    }
  };
  loadKV(ch0);

  for (int ch = ch0; ch < ch1; ++ch) {
    __syncthreads();
#pragma unroll
    for (int it = 0; it < 2; ++it) {
      int slot = it * 256 + t; int rr = slot >> 3, c = slot & 7;
      *(short8*)(Ks + rr * 128 + ((c * 16) ^ ((rr & 7) << 4))) = kreg[it];
#pragma unroll
      for (int j2 = 0; j2 < 8; ++j2) {
        int dh = c * 8 + j2;
        *(short*)(Vt + dh * 128 + ((rr * 2) ^ ((dh & 7) << 4))) = vreg[it][j2];
      }
    }
    __syncthreads();
    if (ch + 1 < ch1) loadKV(ch + 1);

    // S^T = K Q^T: s[n][r] = S[kv = ch*64+n*16+lg*4+r][q = w*16+l15]
    f32x4 sc[4] = {};
#pragma unroll
    for (int ks = 0; ks < 2; ++ks) {
      int qr = w * 16 + l15;
      short8 qf = *(const short8*)(Qs + qr * 128 + ((ks * 64 + lg * 16) ^ ((qr & 7) << 4)));
#pragma unroll
      for (int n = 0; n < 4; ++n) {
        int kr = n * 16 + l15;
        short8 kf = *(const short8*)(Ks + kr * 128 + ((ks * 64 + lg * 16) ^ ((kr & 7) << 4)));
        mfma16(sc[n], kf, qf);          // swapped operands
      }
    }
    // lane-local softmax for q = w*16 + l15 (16 scores in regs)
    float mx = m_run;
#pragma unroll
    for (int n = 0; n < 4; ++n)
#pragma unroll
      for (int r = 0; r < 4; ++r) {
        float v = sc[n][r] * 0.125f;
        int kvi = ch * 64 + n * 16 + lg * 4 + r;
        if (kvi >= n_kv) v = -1e30f;
        sc[n][r] = v;
        mx = fmaxf(mx, v);
      }
    mx = fmaxf(mx, __shfl_xor(mx, 16));
    mx = fmaxf(mx, __shfl_xor(mx, 32));
    float scl = __expf(m_run - mx);
    m_run = mx;
    float p[4][4];
    float rs = 0.0f;
#pragma unroll
    for (int n = 0; n < 4; ++n)
#pragma unroll
      for (int r = 0; r < 4; ++r) { float pv = __expf(sc[n][r] - mx); p[n][r] = pv; rs += pv; }
    rs += __shfl_xor(rs, 16);
    rs += __shfl_xor(rs, 32);
    l_run = l_run * scl + rs;
    // redistribute rescale factor to o-row owners (q = lg*4 + r)
    float sclq[4];
#pragma unroll
    for (int r = 0; r < 4; ++r) sclq[r] = __shfl(scl, lg * 4 + r);
#pragma unroll
    for (int nn = 0; nn < 4; ++nn)
#pragma unroll
      for (int r = 0; r < 4; ++r) o[nn][r] *= sclq[r];
    // write P^T -> P (q-major) in LDS
#pragma unroll
    for (int n = 0; n < 4; ++n)
#pragma unroll
      for (int r = 0; r < 4; ++r) {
        int kv = n * 16 + lg * 4 + r;
        *(unsigned short*)(Ps[w] + l15 * 128 + ((kv * 2) ^ ((l15 & 7) << 4))) = f2b_bits(p[n][r]);
      }
#pragma unroll
    for (int ks = 0; ks < 2; ++ks) {
      short8 pf = *(const short8*)(Ps[w] + l15 * 128 + ((ks * 64 + lg * 16) ^ ((l15 & 7) << 4)));
#pragma unroll
      for (int nn = 0; nn < 4; ++nn) {
        int dh = nn * 16 + l15;
        short8 vf = *(const short8*)(Vt + dh * 128 + ((ks * 64 + lg * 16) ^ ((dh & 7) << 4)));
        mfma16(o[nn], pf, vf);
      }
    }
  }

  if (nseg == 1) {
    float lq[4];
#pragma unroll
    for (int r = 0; r < 4; ++r) lq[r] = __shfl(l_run, lg * 4 + r);
#pragma unroll
    for (int nn = 0; nn < 4; ++nn)
#pragma unroll
      for (int r = 0; r < 4; ++r) {
        int qr = w * 16 + lg * 4 + r;
        int dh = nn * 16 + l15;
        outp[(size_t)(b * 64 + qr) * 1024 + h * 64 + dh] = __float2bfloat16(o[nn][r] / lq[r]);
      }
  } else {
#pragma unroll
    for (int nn = 0; nn < 4; ++nn)
#pragma unroll
      for (int r = 0; r < 4; ++r) {
        int qr = w * 16 + lg * 4 + r;
        int dh = nn * 16 + l15;
        opart[((size_t)s * nb64 + bl * 64 + qr) * 1024 + h * 64 + dh] = o[nn][r];
      }
    if (lg == 0) {
      int qr = w * 16 + l15;
      size_t mi = (((size_t)s * nb64 + bl * 64 + qr) * 16 + h) * 2;
      mlpart[mi]     = m_run;
      mlpart[mi + 1] = l_run;
    }
  }
}

// ---------- merge split-KV partials ----------
__global__ __launch_bounds__(256) void k_amerge(const float* __restrict__ opart,
                                                const float* __restrict__ mlpart,
                                                bf16* __restrict__ outp,
                                                int b0, int nseg, int nbloc) {
  const int bh = blockIdx.x;
  const int bl = bh >> 4, h = bh & 15;
  const int nb64 = nbloc * 64;
  const int t = threadIdx.x;
  const int q = t >> 2, quarter = t & 3;

  float ms[8], ls[8];
  float mstar = -1e30f;
  for (int s = 0; s < nseg; ++s) {
    size_t mi = (((size_t)s * nb64 + bl * 64 + q) * 16 + h) * 2;
    ms[s] = mlpart[mi]; ls[s] = mlpart[mi + 1];
    mstar = fmaxf(mstar, ms[s]);
  }
  float L = 0.0f, ws[8];
  for (int s = 0; s < nseg; ++s) { ws[s] = __expf(ms[s] - mstar); L += ws[s] * ls[s]; }
  float inv = 1.0f / L;

  bf16* outrow = outp + (size_t)((b0 + bl) * 64 + q) * 1024 + h * 64;
#pragma unroll
  for (int jj = 0; jj < 4; ++jj) {
    int dh0 = quarter * 16 + jj * 4;
    float4v acc = {0.f, 0.f, 0.f, 0.f};
    for (int s = 0; s < nseg; ++s) {
      const float* orow = opart + ((size_t)s * nb64 + bl * 64 + q) * 1024 + h * 64 + dh0;
      float4v v = *(const float4v*)orow;
      acc[0] += ws[s] * v[0]; acc[1] += ws[s] * v[1];
      acc[2] += ws[s] * v[2]; acc[3] += ws[s] * v[3];
    }
    short4v sv;
    sv[0] = (short)f2b_bits(acc[0] * inv); sv[1] = (short)f2b_bits(acc[1] * inv);
    sv[2] = (short)f2b_bits(acc[2] * inv); sv[3] = (short)f2b_bits(acc[3] * inv);
    *(short4v*)((short*)(outrow + dh0)) = sv;
  }
}

// =========================== host ===========================
extern "C" void kernel_launch(void* const* d_in, const int* in_sizes, int n_in,
                              void* d_out, int out_size, void* d_ws, size_t ws_size,
                              hipStream_t stream) {
  (void)in_sizes; (void)n_in; (void)out_size;
  const float* id_emb = (const float*)d_in[0];
  const float* f_in[4]  = {(const float*)d_in[4],  (const float*)d_in[3],
                           (const float*)d_in[2],  (const float*)d_in[1]};
  const float* pw_in[4] = {(const float*)d_in[11], (const float*)d_in[9],
                           (const float*)d_in[7],  (const float*)d_in[5]};
  const float* pb_in[4] = {(const float*)d_in[12], (const float*)d_in[10],
                           (const float*)d_in[8],  (const float*)d_in[6]};
  const float* ln1w = (const float*)d_in[13];
  const float* ln1b = (const float*)d_in[14];
  const float* ln2w = (const float*)d_in[15];
  const float* ln2b = (const float*)d_in[16];
  const float* wq   = (const float*)d_in[17];
  const float* wkv  = (const float*)d_in[18];
  const float* wo   = (const float*)d_in[19];
  const float* fflnw = (const float*)d_in[20];
  const float* fflnb = (const float*)d_in[21];
  const float* ffw1  = (const float*)d_in[22];
  const float* ffw2  = (const float*)d_in[23];
  const float* projw = (const float*)d_in[24];
  const float* projb = (const float*)d_in[25];
  const float* normw = (const float*)d_in[26];
  const float* normb = (const float*)d_in[27];

  static const int N1S[4]  = {49, 196, 784, 3136};
  static const int FRDS[4] = {512, 256, 128, 64};
  static const int NSEG[4] = {1, 1, 2, 4};
  const size_t LW = 4718592;

  bf16 *zfeat[4], *fbf[4], *pT[4], *projT;
  float *qkvl_bias, *kvx_bias, *ff_bias, *lat, *headtmp;
  float *opart, *mlpart;
  bf16 *qkvl_act, *attnout, *zlat, *latbf, *ffh;
  bf16 *wqkvlT = nullptr, *wkvxT = nullptr, *woT = nullptr, *w1T = nullptr, *w2T = nullptr;
  bf16 *wbuf = nullptr;
  char *big;

  auto assign = [&](bool fullw, int bc) -> size_t {
    size_t off = 0; char* base = (char*)d_ws;
    auto A = [&](size_t b) -> char* {
      char* p = base + off; off = (off + b + 255) & ~(size_t)255; return p;
    };
    for (int i = 0; i < 4; ++i) zfeat[i] = (bf16*)A((size_t)16 * N1S[i] * 768 * 2);
    for (int i = 0; i < 4; ++i) fbf[i]   = (bf16*)A((size_t)16 * N1S[i] * FRDS[i] * 2);
    for (int i = 0; i < 4; ++i) pT[i]    = (bf16*)A((size_t)768 * FRDS[i] * 2);
    projT     = (bf16*)A(768ull * 768 * 2);
    qkvl_bias = (float*)A(24ull * 3072 * 4);
    kvx_bias  = (float*)A(24ull * 2048 * 4);
    ff_bias   = (float*)A(6ull * 3072 * 4);
    qkvl_act  = (bf16*)A(1024ull * 3072 * 2);
    attnout   = (bf16*)A(1024ull * 1024 * 2);
    lat       = (float*)A(1024ull * 768 * 4);
    zlat      = (bf16*)A(1024ull * 768 * 2);
    opart     = (float*)A(4ull * (size_t)bc * 64 * 1024 * 4);
    mlpart    = (float*)A(4ull * (size_t)bc * 64 * 16 * 2 * 4);
    if (fullw) {
      wqkvlT = (bf16*)A(24ull * 3072 * 768 * 2);
      wkvxT  = (bf16*)A(24ull * 2048 * 768 * 2);
      woT    = (bf16*)A(24ull * 768 * 1024 * 2);
      w1T    = (bf16*)A(6ull * 3072 * 768 * 2);
      w2T    = (bf16*)A(6ull * 768 * 3072 * 2);
      wbuf = nullptr;
    } else {
      wbuf = (bf16*)A(4ull * LW * 2);
      wqkvlT = wkvxT = woT = w1T = w2T = nullptr;
    }
    big = A((size_t)bc * 3136 * 2048 * 2);
    ffh = qkvl_act; headtmp = (float*)qkvl_act; latbf = zlat;
    return off;
  };

  static const bool FULLS[10] = {true,true,false,true,false,true,true,false,false,false};
  static const int  BCS[10]   = {16,  8,   16,   4,   8,    2,   1,   4,    2,    1};
  bool fullw = false; int bc = 1; bool ok = false;
  for (int c = 0; c < 10; ++c) {
    if (assign(FULLS[c], BCS[c]) <= ws_size) { fullw = FULLS[c]; bc = BCS[c]; ok = true; break; }
  }
  if (!ok) return;

  float* featf32 = (float*)big;
  bf16*  kvxbuf  = (bf16*)big;

  auto gemm = [&](int tile, const bf16* A, const bf16* Bt, void* C,
                  const float* bias, const float* res, int M, int N, int K,
                  bool obf, bool gl) {
    if (tile == 128) {
      int nxt = N / 128, nwg = nxt * ((M + 127) / 128);
      if (obf && gl) k_gemm<128,128,true ,true ><<<nwg,256,0,stream>>>(A,Bt,C,bias,res,M,N,K,nxt,nwg);
      else if (obf)  k_gemm<128,128,true ,false><<<nwg,256,0,stream>>>(A,Bt,C,bias,res,M,N,K,nxt,nwg);
      else           k_gemm<128,128,false,false><<<nwg,256,0,stream>>>(A,Bt,C,bias,res,M,N,K,nxt,nwg);
    } else if (tile == 64) {
      int nxt = N / 64, nwg = nxt * ((M + 63) / 64);
      if (obf && gl)  k_gemm<64,64,true ,true ><<<nwg,256,0,stream>>>(A,Bt,C,bias,res,M,N,K,nxt,nwg);
      else if (obf)   k_gemm<64,64,true ,false><<<nwg,256,0,stream>>>(A,Bt,C,bias,res,M,N,K,nxt,nwg);
      else            k_gemm<64,64,false,false><<<nwg,256,0,stream>>>(A,Bt,C,bias,res,M,N,K,nxt,nwg);
    } else {
      int nxt = N / 64, nwg = nxt * ((M + 31) / 32);
      if (obf && gl)  k_gemm<32,64,true ,true ><<<nwg,256,0,stream>>>(A,Bt,C,bias,res,M,N,K,nxt,nwg);
      else if (obf)   k_gemm<32,64,true ,false><<<nwg,256,0,stream>>>(A,Bt,C,bias,res,M,N,K,nxt,nwg);
      else            k_gemm<32,64,false,false><<<nwg,256,0,stream>>>(A,Bt,C,bias,res,M,N,K,nxt,nwg);
    }
  };
  auto pick = [&](int M, int N) -> int {
    return M >= 2048 ? 128 : (N >= 1536 ? 64 : 32);
  };

  dim3 tb(32, 8);

  // ---- bias folds ----
  k_bfold <<<dim3(16, 24), 256, 0, stream>>>(wq,  ln2b, qkvl_bias, 768, 1024, 768LL*1024, 768, 3072);
  k_bfold2<<<dim3(32, 24), 256, 0, stream>>>(wkv, ln2b, ln1b, qkvl_bias + 1024, kvx_bias,
                                             768, 2048, 768LL*2048, 768, 3072, 2048);
  k_bfold <<<dim3(48, 6),  256, 0, stream>>>(ffw1, fflnb, ff_bias, 768, 3072, 768LL*3072, 768, 3072);

  // ---- small folded weights ----
  for (int i = 0; i < 4; ++i)
    k_tfold<<<dim3(24, FRDS[i] / 32, 1), tb, 0, stream>>>(pw_in[i], nullptr, pT[i], FRDS[i], 768, 0, 0, 0);
  k_tfold<<<dim3(24, 24, 1), tb, 0, stream>>>(projw, nullptr, projT, 768, 768, 0, 0, 0);

  // ---- full-mode weight folds ----
  if (fullw) {
    k_tfold <<<dim3(32, 24, 24), tb, 0, stream>>>(wq,  ln2w, wqkvlT, 768, 1024, 768LL*1024, 768, 3072LL*768);
    k_tfold2<<<dim3(64, 24, 24), tb, 0, stream>>>(wkv, ln2w, ln1w, wqkvlT + 1024LL*768, wkvxT,
                                                  768, 2048, 768LL*2048, 768, 3072LL*768, 2048LL*768);
    k_tfold <<<dim3(24, 32, 24), tb, 0, stream>>>(wo,  nullptr, woT, 1024, 768, 1024LL*768, 0, 768LL*1024);
    k_tfold <<<dim3(96, 24, 6),  tb, 0, stream>>>(ffw1, fflnw, w1T, 768, 3072, 768LL*3072, 768, 3072LL*768);
    k_tfold <<<dim3(24, 96, 6),  tb, 0, stream>>>(ffw2, nullptr, w2T, 3072, 768, 3072LL*768, 0, 768LL*3072);
  }

  auto foldDepthAttn = [&](int d) {
    k_tfold <<<dim3(32, 24, 4), tb, 0, stream>>>(wq  + (size_t)d*4*768*1024, ln2w + (size_t)d*4*768,
                                                 wbuf, 768, 1024, 768LL*1024, 768, (long long)LW);
    k_tfold2<<<dim3(64, 24, 4), tb, 0, stream>>>(wkv + (size_t)d*4*768*2048, ln2w + (size_t)d*4*768,
                                                 ln1w + (size_t)d*4*768,
                                                 wbuf + 1024ull*768, wbuf + 3072ull*768,
                                                 768, 2048, 768LL*2048, 768, (long long)LW, (long long)LW);
    k_tfold <<<dim3(24, 32, 4), tb, 0, stream>>>(wo  + (size_t)d*4*1024*768, nullptr,
                                                 wbuf + 3932160ull, 1024, 768, 1024LL*768, 0, (long long)LW);
  };
  auto attnW = [&](int di, const bf16*& qkvlT_p, const bf16*& kvxT_p, const bf16*& woT_p) {
    if (fullw) {
      qkvlT_p = wqkvlT + (size_t)di * 3072 * 768;
      kvxT_p  = wkvxT  + (size_t)di * 2048 * 768;
      woT_p   = woT    + (size_t)di * 768 * 1024;
    } else {
      bf16* base = wbuf + (size_t)(di & 3) * LW;
      qkvlT_p = base;
      kvxT_p  = base + 2359296ull;
      woT_p   = base + 3932160ull;
    }
  };
  auto ffW = [&](int d, const bf16*& w1p, const bf16*& w2p) {
    if (fullw) {
      w1p = w1T + (size_t)d * 3072 * 768;
      w2p = w2T + (size_t)d * 768 * 3072;
    } else {
      bf16* d1 = wbuf;
      bf16* d2 = wbuf + 3072ull * 768;
      k_tfold<<<dim3(96, 24, 1), tb, 0, stream>>>(ffw1 + (size_t)d*768*3072, fflnw + 768ull*d, d1,  768, 3072, 0, 0, 0);
      k_tfold<<<dim3(24, 96, 1), tb, 0, stream>>>(ffw2 + (size_t)d*3072*768, nullptr,          d2, 3072,  768, 0, 0, 0);
      w1p = d1; w2p = d2;
    }
  };

  // ---- feature projection + standardize ----
  for (int i = 0; i < 4; ++i) {
    int n1 = N1S[i], frd = FRDS[i];
    size_t cnt = (size_t)16 * n1 * frd;
    k_cvt<<<(int)(cnt / 1024), 256, 0, stream>>>(f_in[i], fbf[i], (int)(cnt / 4));
    for (int b0 = 0; b0 < 16; b0 += bc) {
      int rows = bc * n1;
      gemm(pick(rows, 768), fbf[i] + (size_t)b0 * n1 * frd, pT[i], featf32,
           pb_in[i], nullptr, rows, 768, frd, false, false);
      k_std<<<rows, 256, 0, stream>>>(featf32, zfeat[i] + (size_t)b0 * n1 * 768);
    }
  }

  hipMemcpyAsync(lat, id_emb, 1024ull * 768 * 4, hipMemcpyDeviceToDevice, stream);

  // ---- depth loop ----
  for (int d = 0; d < 6; ++d) {
    if (!fullw) foldDepthAttn(d);
    for (int i = 0; i < 4; ++i) {
      int di = d * 4 + i, n1 = N1S[i], nseg = NSEG[i];
      const bf16 *qkvlT_p, *kvxT_p, *woT_p;
      attnW(di, qkvlT_p, kvxT_p, woT_p);
      k_std<<<1024, 256, 0, stream>>>(lat, zlat);
      gemm(64, zlat, qkvlT_p, qkvl_act, qkvl_bias + 3072ull * di, nullptr,
           1024, 3072, 768, true, false);
      for (int b0 = 0; b0 < 16; b0 += bc) {
        int rows = bc * n1;
        gemm(pick(rows, 2048), zfeat[i] + (size_t)b0 * n1 * 768, kvxT_p, kvxbuf,
             kvx_bias + 2048ull * di, nullptr, rows, 2048, 768, true, false);
        k_attn<<<bc * 16 * nseg, 256, 0, stream>>>(qkvl_act, kvxbuf, attnout,
                                                   opart, mlpart, n1, b0, nseg, bc);
        if (nseg > 1)
          k_amerge<<<bc * 16, 256, 0, stream>>>(opart, mlpart, attnout, b0, nseg, bc);
      }
      gemm(32, attnout, woT_p, lat, nullptr, lat, 1024, 768, 1024, false, false);
    }
    const bf16 *w1p, *w2p;
    ffW(d, w1p, w2p);
    k_std<<<1024, 256, 0, stream>>>(lat, zlat);
    gemm(64, zlat, w1p, ffh, ff_bias + 3072ull * d, nullptr, 1024, 3072, 768, true, true);
    gemm(32, ffh, w2p, lat, nullptr, lat, 1024, 768, 3072, false, false);
  }

  // ---- head ----
  k_cvt<<<768, 256, 0, stream>>>(lat, latbf, 196608);
  gemm(32, latbf, projT, headtmp, projb, nullptr, 1024, 768, 768, false, false);
  k_lnout<<<1024, 256, 0, stream>>>(headtmp, normw, normb, (float*)d_out);
}

// Round 8
// 4069.698 us; speedup vs baseline: 1.6625x; 1.3128x over previous
//
#include <hip/hip_runtime.h>
#include <hip/hip_bf16.h>
#include <cstdint>
#include <cstddef>

typedef __hip_bfloat16 bf16;
typedef float  f32x4   __attribute__((ext_vector_type(4)));
typedef float  float4v __attribute__((ext_vector_type(4)));
typedef short  short8  __attribute__((ext_vector_type(8)));
typedef short  short4v __attribute__((ext_vector_type(4)));
typedef __bf16 bf16x8  __attribute__((ext_vector_type(8)));

__device__ __forceinline__ void mfma16(f32x4& d, short8 a, short8 b) {
  d = __builtin_amdgcn_mfma_f32_16x16x32_bf16(
      __builtin_bit_cast(bf16x8, a), __builtin_bit_cast(bf16x8, b), d, 0, 0, 0);
}
__device__ __forceinline__ unsigned short f2b_bits(float x) {
  __hip_bfloat16 h = __float2bfloat16(x);
  return __builtin_bit_cast(unsigned short, h);
}
__device__ __forceinline__ float gelu_exact(float x) {
  return 0.5f * x * (1.0f + erff(x * 0.7071067811865475f));
}

// ---------- f32 -> bf16 convert, 4 elems/thread ----------
__global__ __launch_bounds__(256) void k_cvt(const float* __restrict__ src,
                                             bf16* __restrict__ dst, int n4) {
  int i = blockIdx.x * 256 + threadIdx.x;
  if (i >= n4) return;
  float4v v = *(const float4v*)(src + (size_t)i * 4);
  short4v s;
  s[0] = (short)f2b_bits(v[0]); s[1] = (short)f2b_bits(v[1]);
  s[2] = (short)f2b_bits(v[2]); s[3] = (short)f2b_bits(v[3]);
  *(short4v*)((short*)dst + (size_t)i * 4) = s;
}

// ---------- transpose (+optional per-k scale): f32 (K,N) -> bf16 (N,K) ----------
__global__ void k_tfold(const float* __restrict__ src, const float* __restrict__ scale,
                        bf16* __restrict__ dst, int K, int N,
                        long long src_bs, long long scale_bs, long long dst_bs) {
  src += (size_t)blockIdx.z * src_bs;
  dst += (size_t)blockIdx.z * dst_bs;
  const float* sc = scale ? scale + (size_t)blockIdx.z * scale_bs : nullptr;
  __shared__ float tile[32][33];
  int n0 = blockIdx.x * 32, k0 = blockIdx.y * 32;
  int tx = threadIdx.x, ty = threadIdx.y;
#pragma unroll
  for (int j = 0; j < 4; ++j) {
    int k = k0 + ty + j * 8;
    float s = sc ? sc[k] : 1.0f;
    tile[ty + j * 8][tx] = src[(size_t)k * N + n0 + tx] * s;
  }
  __syncthreads();
#pragma unroll
  for (int j = 0; j < 4; ++j) {
    int n = n0 + ty + j * 8;
    dst[(size_t)n * K + k0 + tx] = __float2bfloat16(tile[tx][ty + j * 8]);
  }
}

// ---------- dual transpose-fold ----------
__global__ void k_tfold2(const float* __restrict__ src,
                         const float* __restrict__ s1, const float* __restrict__ s2,
                         bf16* __restrict__ d1, bf16* __restrict__ d2, int K, int N,
                         long long src_bs, long long s_bs,
                         long long d1_bs, long long d2_bs) {
  src += (size_t)blockIdx.z * src_bs;
  d1  += (size_t)blockIdx.z * d1_bs;
  d2  += (size_t)blockIdx.z * d2_bs;
  s1  += (size_t)blockIdx.z * s_bs;
  s2  += (size_t)blockIdx.z * s_bs;
  __shared__ float tile[32][33];
  __shared__ float sc1[32], sc2[32];
  int n0 = blockIdx.x * 32, k0 = blockIdx.y * 32;
  int tx = threadIdx.x, ty = threadIdx.y;
  if (ty == 0) { sc1[tx] = s1[k0 + tx]; sc2[tx] = s2[k0 + tx]; }
#pragma unroll
  for (int j = 0; j < 4; ++j) {
    int k = k0 + ty + j * 8;
    tile[ty + j * 8][tx] = src[(size_t)k * N + n0 + tx];
  }
  __syncthreads();
#pragma unroll
  for (int j = 0; j < 4; ++j) {
    int n = n0 + ty + j * 8;
    float v = tile[tx][ty + j * 8];
    d1[(size_t)n * K + k0 + tx] = __float2bfloat16(v * sc1[tx]);
    d2[(size_t)n * K + k0 + tx] = __float2bfloat16(v * sc2[tx]);
  }
}

// ---------- bias fold ----------
__global__ __launch_bounds__(256) void k_bfold(const float* __restrict__ W,
                                               const float* __restrict__ lnb,
                                               float* __restrict__ out, int K, int N,
                                               long long w_bs, long long b_bs, long long o_bs) {
  W   += (size_t)blockIdx.y * w_bs;
  lnb += (size_t)blockIdx.y * b_bs;
  out += (size_t)blockIdx.y * o_bs;
  const int l = threadIdx.x & 63, kg = threadIdx.x >> 6;
  const int n = blockIdx.x * 64 + l;
  float a = 0.0f;
  for (int k = kg; k < K; k += 4) a = fmaf(lnb[k], W[(size_t)k * N + n], a);
  __shared__ float red[4][64];
  red[kg][l] = a;
  __syncthreads();
  if (kg == 0) out[n] = (red[0][l] + red[1][l]) + (red[2][l] + red[3][l]);
}

// ---------- dual bias fold ----------
__global__ __launch_bounds__(256) void k_bfold2(const float* __restrict__ W,
                                                const float* __restrict__ b1,
                                                const float* __restrict__ b2,
                                                float* __restrict__ o1,
                                                float* __restrict__ o2, int K, int N,
                                                long long w_bs, long long b_bs,
                                                long long o1_bs, long long o2_bs) {
  W  += (size_t)blockIdx.y * w_bs;
  b1 += (size_t)blockIdx.y * b_bs;
  b2 += (size_t)blockIdx.y * b_bs;
  o1 += (size_t)blockIdx.y * o1_bs;
  o2 += (size_t)blockIdx.y * o2_bs;
  const int l = threadIdx.x & 63, kg = threadIdx.x >> 6;
  const int n = blockIdx.x * 64 + l;
  float a1 = 0.0f, a2 = 0.0f;
  for (int k = kg; k < K; k += 4) {
    float wv = W[(size_t)k * N + n];
    a1 = fmaf(b1[k], wv, a1);
    a2 = fmaf(b2[k], wv, a2);
  }
  __shared__ float r1[4][64], r2[4][64];
  r1[kg][l] = a1; r2[kg][l] = a2;
  __syncthreads();
  if (kg == 0) {
    o1[n] = (r1[0][l] + r1[1][l]) + (r1[2][l] + r1[3][l]);
    o2[n] = (r2[0][l] + r2[1][l]) + (r2[2][l] + r2[3][l]);
  }
}

// ---------- kv low-rank vectors: s[n]=sum ln1w*wkv, bw[n]=sum (pb*ln1w)*wkv, per di ----------
__global__ __launch_bounds__(256) void k_kvvec(const float* __restrict__ wkv,
                                               const float* __restrict__ ln1w,
                                               const float* __restrict__ b0,
                                               const float* __restrict__ b1,
                                               const float* __restrict__ b2,
                                               const float* __restrict__ b3,
                                               float* __restrict__ sv,
                                               float* __restrict__ bwv) {
  const int di = blockIdx.y;
  const int i = di & 3;
  const float* b = (i == 0) ? b0 : (i == 1) ? b1 : (i == 2) ? b2 : b3;
  const float* W = wkv + (size_t)di * 768 * 2048;
  const float* lw = ln1w + (size_t)di * 768;
  const int l = threadIdx.x & 63, kg = threadIdx.x >> 6;
  const int n = blockIdx.x * 64 + l;
  float a1 = 0.0f, a2 = 0.0f;
  for (int k = kg; k < 768; k += 4) {
    float wv = W[(size_t)k * 2048 + n];
    float lwk = lw[k];
    a1 = fmaf(lwk, wv, a1);
    a2 = fmaf(b[k] * lwk, wv, a2);
  }
  __shared__ float r1[4][64], r2[4][64];
  r1[kg][l] = a1; r2[kg][l] = a2;
  __syncthreads();
  if (kg == 0) {
    sv [(size_t)di * 2048 + n] = (r1[0][l] + r1[1][l]) + (r1[2][l] + r1[3][l]);
    bwv[(size_t)di * 2048 + n] = (r2[0][l] + r2[1][l]) + (r2[2][l] + r2[3][l]);
  }
}

// ---------- row standardize (768-wide), f32 -> bf16 ----------
__global__ __launch_bounds__(256) void k_std(const float* __restrict__ src,
                                             bf16* __restrict__ dst) {
  int row = blockIdx.x;
  const float* x = src + (size_t)row * 768;
  int t = threadIdx.x;
  float a0 = x[t], a1 = x[t + 256], a2 = x[t + 512];
  float s = a0 + a1 + a2;
  float q = a0 * a0 + a1 * a1 + a2 * a2;
#pragma unroll
  for (int off = 1; off < 64; off <<= 1) { s += __shfl_xor(s, off); q += __shfl_xor(q, off); }
  __shared__ float ss[4], qs[4];
  if ((t & 63) == 0) { ss[t >> 6] = s; qs[t >> 6] = q; }
  __syncthreads();
  s = ss[0] + ss[1] + ss[2] + ss[3];
  q = qs[0] + qs[1] + qs[2] + qs[3];
  float mean = s * (1.0f / 768.0f);
  float var  = q * (1.0f / 768.0f) - mean * mean;
  float inv  = rsqrtf(var + 1e-5f);
  bf16* d = dst + (size_t)row * 768;
  d[t]       = __float2bfloat16((a0 - mean) * inv);
  d[t + 256] = __float2bfloat16((a1 - mean) * inv);
  d[t + 512] = __float2bfloat16((a2 - mean) * inv);
}

// ---------- row stats only (768-wide): out[row] = {inv, mean*inv} ----------
__global__ __launch_bounds__(256) void k_stats(const float* __restrict__ src,
                                               float2* __restrict__ out) {
  int row = blockIdx.x;
  const float* x = src + (size_t)row * 768;
  int t = threadIdx.x;
  float a0 = x[t], a1 = x[t + 256], a2 = x[t + 512];
  float s = a0 + a1 + a2;
  float q = a0 * a0 + a1 * a1 + a2 * a2;
#pragma unroll
  for (int off = 1; off < 64; off <<= 1) { s += __shfl_xor(s, off); q += __shfl_xor(q, off); }
  __shared__ float ss[4], qs[4];
  if ((t & 63) == 0) { ss[t >> 6] = s; qs[t >> 6] = q; }
  __syncthreads();
  if (t == 0) {
    float sm = ss[0] + ss[1] + ss[2] + ss[3];
    float qm = qs[0] + qs[1] + qs[2] + qs[3];
    float mean = sm * (1.0f / 768.0f);
    float var  = qm * (1.0f / 768.0f) - mean * mean;
    float inv  = rsqrtf(var + 1e-5f);
    out[row] = make_float2(inv, mean * inv);
  }
}

// ---------- final layernorm (768-wide) with w,b: f32 -> f32 ----------
__global__ __launch_bounds__(256) void k_lnout(const float* __restrict__ src,
                                               const float* __restrict__ w,
                                               const float* __restrict__ b,
                                               float* __restrict__ dst) {
  int row = blockIdx.x;
  const float* x = src + (size_t)row * 768;
  int t = threadIdx.x;
  float a0 = x[t], a1 = x[t + 256], a2 = x[t + 512];
  float s = a0 + a1 + a2;
  float q = a0 * a0 + a1 * a1 + a2 * a2;
#pragma unroll
  for (int off = 1; off < 64; off <<= 1) { s += __shfl_xor(s, off); q += __shfl_xor(q, off); }
  __shared__ float ss[4], qs[4];
  if ((t & 63) == 0) { ss[t >> 6] = s; qs[t >> 6] = q; }
  __syncthreads();
  s = ss[0] + ss[1] + ss[2] + ss[3];
  q = qs[0] + qs[1] + qs[2] + qs[3];
  float mean = s * (1.0f / 768.0f);
  float var  = q * (1.0f / 768.0f) - mean * mean;
  float inv  = rsqrtf(var + 1e-5f);
  float* d = dst + (size_t)row * 768;
  d[t]       = (a0 - mean) * inv * w[t]       + b[t];
  d[t + 256] = (a1 - mean) * inv * w[t + 256] + b[t + 256];
  d[t + 512] = (a2 - mean) * inv * w[t + 512] + b[t + 512];
}

// ---------- MFMA GEMM (reg-staged pipeline + XCD swizzle) ----------
// KVE epilogue: out = (acc + c1[n])*inv_r - muinv_r*cs[n] + bias[n]
template <int BM, int BN, bool OBF16, bool GELU, bool KVE>
__global__ __launch_bounds__(256) void k_gemm(const bf16* __restrict__ A,
                                              const bf16* __restrict__ Bt,
                                              void* __restrict__ Cv,
                                              const float* __restrict__ bias,
                                              const float* __restrict__ res,
                                              const float2* __restrict__ rstats,
                                              const float* __restrict__ c1,
                                              const float* __restrict__ cs,
                                              int M, int N, int K, int nxt, int nwg) {
  constexpr int AI = BM / 32, BI = BN / 32;
  constexpr int MF = BM / 32, NF = BN / 32;
  __shared__ __align__(16) char As[BM * 128];
  __shared__ __align__(16) char Bs[BN * 128];

  const int lin = blockIdx.x;
  const int qq = nwg >> 3, r8 = nwg & 7;
  const int xcd = lin & 7, idx = lin >> 3;
  const int swz = (xcd < r8) ? (xcd * (qq + 1) + idx)
                             : (r8 * (qq + 1) + (xcd - r8) * qq + idx);
  const int bm = (swz / nxt) * BM, bn = (swz % nxt) * BN;

  const int t = threadIdx.x, lane = t & 63, w = t >> 6;
  const int wr = w >> 1, wc = w & 1;
  const int l15 = lane & 15, lg = lane >> 4;
  const int srow = t >> 3, scol = t & 7;

  const bf16* aptr[AI]; int aoff[AI];
#pragma unroll
  for (int i = 0; i < AI; ++i) {
    int r = i * 32 + srow;
    int gr = bm + r; if (gr > M - 1) gr = M - 1;
    aptr[i] = A + (size_t)gr * K + scol * 8;
    aoff[i] = r * 128 + ((scol * 16) ^ ((r & 7) << 4));
  }
  const bf16* bptr[BI]; int boff[BI];
#pragma unroll
  for (int i = 0; i < BI; ++i) {
    int r = i * 32 + srow;
    int gc = bn + r; if (gc > N - 1) gc = N - 1;
    bptr[i] = Bt + (size_t)gc * K + scol * 8;
    boff[i] = r * 128 + ((scol * 16) ^ ((r & 7) << 4));
  }

  f32x4 acc[MF][NF] = {};
  short8 av[AI], bv[BI];
#pragma unroll
  for (int i = 0; i < AI; ++i) av[i] = *(const short8*)(aptr[i]);
#pragma unroll
  for (int i = 0; i < BI; ++i) bv[i] = *(const short8*)(bptr[i]);

  const int nk = K / 64;
  for (int kt = 0; kt < nk; ++kt) {
    __syncthreads();
#pragma unroll
    for (int i = 0; i < AI; ++i) *(short8*)(As + aoff[i]) = av[i];
#pragma unroll
    for (int i = 0; i < BI; ++i) *(short8*)(Bs + boff[i]) = bv[i];
    __syncthreads();
    if (kt + 1 < nk) {
#pragma unroll
      for (int i = 0; i < AI; ++i) av[i] = *(const short8*)(aptr[i] + (size_t)(kt + 1) * 64);
#pragma unroll
      for (int i = 0; i < BI; ++i) bv[i] = *(const short8*)(bptr[i] + (size_t)(kt + 1) * 64);
    }
#pragma unroll
    for (int ks = 0; ks < 2; ++ks) {
      short8 af[MF], bfr[NF];
#pragma unroll
      for (int m = 0; m < MF; ++m) {
        int r = wr * (BM / 2) + m * 16 + l15;
        af[m] = *(const short8*)(As + r * 128 + ((ks * 64 + lg * 16) ^ ((r & 7) << 4)));
      }
#pragma unroll
      for (int n = 0; n < NF; ++n) {
        int r = wc * (BN / 2) + n * 16 + l15;
        bfr[n] = *(const short8*)(Bs + r * 128 + ((ks * 64 + lg * 16) ^ ((r & 7) << 4)));
      }
#pragma unroll
      for (int m = 0; m < MF; ++m)
#pragma unroll
        for (int n = 0; n < NF; ++n) mfma16(acc[m][n], af[m], bfr[n]);
    }
  }

#pragma unroll
  for (int m = 0; m < MF; ++m) {
    int gr0 = bm + wr * (BM / 2) + m * 16 + lg * 4;
#pragma unroll
    for (int n = 0; n < NF; ++n) {
      int gc = bn + wc * (BN / 2) + n * 16 + l15;
      float bvs = bias ? bias[gc] : 0.0f;
      float c1v = 0.0f, csv = 0.0f;
      if (KVE) { c1v = c1[gc]; csv = cs[gc]; }
#pragma unroll
      for (int r = 0; r < 4; ++r) {
        int gr = gr0 + r;
        if (gr < M) {
          float v;
          if (KVE) {
            float2 st = rstats[gr];
            v = (acc[m][n][r] + c1v) * st.x - st.y * csv + bvs;
          } else {
            v = acc[m][n][r] + bvs;
            if (GELU) v = gelu_exact(v);
            if (res) v += res[(size_t)gr * N + gc];
          }
          if (OBF16) ((bf16*)Cv)[(size_t)gr * N + gc] = __float2bfloat16(v);
          else       ((float*)Cv)[(size_t)gr * N + gc] = v;
        }
      }
    }
  }
}

// ---------- fused attention, split-KV + swapped-QK^T softmax ----------
__global__ __launch_bounds__(256) void k_attn(const bf16* __restrict__ qkvl,
                                              const bf16* __restrict__ kvx,
                                              bf16* __restrict__ outp,
                                              float* __restrict__ opart,
                                              float* __restrict__ mlpart,
                                              int n1, int b0, int nseg, int nbloc) {
  const int s   = blockIdx.x % nseg;
  const int bh  = blockIdx.x / nseg;
  const int bl = bh >> 4, h = bh & 15;
  const int b = b0 + bl;
  const int nb64 = nbloc * 64;
  __shared__ __align__(16) char Qs[64 * 128];
  __shared__ __align__(16) char Ks[64 * 128];
  __shared__ __align__(16) char Vt[64 * 128];
  __shared__ __align__(16) char Ps[4][16 * 128];
  const int t = threadIdx.x, lane = t & 63, w = t >> 6;
  const int l15 = lane & 15, lg = lane >> 4;

#pragma unroll
  for (int it = 0; it < 2; ++it) {
    int slot = it * 256 + t; int r = slot >> 3, c = slot & 7;
    short8 v = *(const short8*)(qkvl + (size_t)(b * 64 + r) * 3072 + h * 64 + c * 8);
    *(short8*)(Qs + r * 128 + ((c * 16) ^ ((r & 7) << 4))) = v;
  }
  const int n_kv = n1 + 64;
  const int nch = (n_kv + 63) >> 6;
  const int cpseg = (nch + nseg - 1) / nseg;
  const int ch0 = s * cpseg;
  const int ch1 = min(nch, ch0 + cpseg);

  float m_run = -1e30f, l_run = 0.0f;
  f32x4 o[4] = {};

  short8 kreg[2], vreg[2];
  auto loadKV = [&](int ch) {
#pragma unroll
    for (int it = 0; it < 2; ++it) {
      int slot = it * 256 + t; int rr = slot >> 3, c = slot & 7;
      int j = ch * 64 + rr;
      short8 kv = {}; short8 vv = {};
      if (j < n_kv) {
        const bf16* kb;
        if (j < n1) kb = kvx + (size_t)(bl * n1 + j) * 2048 + h * 64;
        else        kb = qkvl + (size_t)(b * 64 + (j - n1)) * 3072 + 1024 + h * 64;
        kv = *(const short8*)(kb + c * 8);
        vv = *(const short8*)(kb + 1024 + c * 8);
      }
      kreg[it] = kv; vreg[it] = vv;
    }
  };
  loadKV(ch0);

  for (int ch = ch0; ch < ch1; ++ch) {
    __syncthreads();
#pragma unroll
    for (int it = 0; it < 2; ++it) {
      int slot = it * 256 + t; int rr = slot >> 3, c = slot & 7;
      *(short8*)(Ks + rr * 128 + ((c * 16) ^ ((rr & 7) << 4))) = kreg[it];
#pragma unroll
      for (int j2 = 0; j2 < 8; ++j2) {
        int dh = c * 8 + j2;
        *(short*)(Vt + dh * 128 + ((rr * 2) ^ ((dh & 7) << 4))) = vreg[it][j2];
      }
    }
    __syncthreads();
    if (ch + 1 < ch1) loadKV(ch + 1);

    f32x4 sc[4] = {};
#pragma unroll
    for (int ks = 0; ks < 2; ++ks) {
      int qr = w * 16 + l15;
      short8 qf = *(const short8*)(Qs + qr * 128 + ((ks * 64 + lg * 16) ^ ((qr & 7) << 4)));
#pragma unroll
      for (int n = 0; n < 4; ++n) {
        int kr = n * 16 + l15;
        short8 kf = *(const short8*)(Ks + kr * 128 + ((ks * 64 + lg * 16) ^ ((kr & 7) << 4)));
        mfma16(sc[n], kf, qf);
      }
    }
    float mx = m_run;
#pragma unroll
    for (int n = 0; n < 4; ++n)
#pragma unroll
      for (int r = 0; r < 4; ++r) {
        float v = sc[n][r] * 0.125f;
        int kvi = ch * 64 + n * 16 + lg * 4 + r;
        if (kvi >= n_kv) v = -1e30f;
        sc[n][r] = v;
        mx = fmaxf(mx, v);
      }
    mx = fmaxf(mx, __shfl_xor(mx, 16));
    mx = fmaxf(mx, __shfl_xor(mx, 32));
    float scl = __expf(m_run - mx);
    m_run = mx;
    float p[4][4];
    float rs = 0.0f;
#pragma unroll
    for (int n = 0; n < 4; ++n)
#pragma unroll
      for (int r = 0; r < 4; ++r) { float pv = __expf(sc[n][r] - mx); p[n][r] = pv; rs += pv; }
    rs += __shfl_xor(rs, 16);
    rs += __shfl_xor(rs, 32);
    l_run = l_run * scl + rs;
    float sclq[4];
#pragma unroll
    for (int r = 0; r < 4; ++r) sclq[r] = __shfl(scl, lg * 4 + r);
#pragma unroll
    for (int nn = 0; nn < 4; ++nn)
#pragma unroll
      for (int r = 0; r < 4; ++r) o[nn][r] *= sclq[r];
#pragma unroll
    for (int n = 0; n < 4; ++n)
#pragma unroll
      for (int r = 0; r < 4; ++r) {
        int kv = n * 16 + lg * 4 + r;
        *(unsigned short*)(Ps[w] + l15 * 128 + ((kv * 2) ^ ((l15 & 7) << 4))) = f2b_bits(p[n][r]);
      }
#pragma unroll
    for (int ks = 0; ks < 2; ++ks) {
      short8 pf = *(const short8*)(Ps[w] + l15 * 128 + ((ks * 64 + lg * 16) ^ ((l15 & 7) << 4)));
#pragma unroll
      for (int nn = 0; nn < 4; ++nn) {
        int dh = nn * 16 + l15;
        short8 vf = *(const short8*)(Vt + dh * 128 + ((ks * 64 + lg * 16) ^ ((dh & 7) << 4)));
        mfma16(o[nn], pf, vf);
      }
    }
  }

  if (nseg == 1) {
    float lq[4];
#pragma unroll
    for (int r = 0; r < 4; ++r) lq[r] = __shfl(l_run, lg * 4 + r);
#pragma unroll
    for (int nn = 0; nn < 4; ++nn)
#pragma unroll
      for (int r = 0; r < 4; ++r) {
        int qr = w * 16 + lg * 4 + r;
        int dh = nn * 16 + l15;
        outp[(size_t)(b * 64 + qr) * 1024 + h * 64 + dh] = __float2bfloat16(o[nn][r] / lq[r]);
      }
  } else {
#pragma unroll
    for (int nn = 0; nn < 4; ++nn)
#pragma unroll
      for (int r = 0; r < 4; ++r) {
        int qr = w * 16 + lg * 4 + r;
        int dh = nn * 16 + l15;
        opart[((size_t)s * nb64 + bl * 64 + qr) * 1024 + h * 64 + dh] = o[nn][r];
      }
    if (lg == 0) {
      int qr = w * 16 + l15;
      size_t mi = (((size_t)s * nb64 + bl * 64 + qr) * 16 + h) * 2;
      mlpart[mi]     = m_run;
      mlpart[mi + 1] = l_run;
    }
  }
}

// ---------- merge split-KV partials ----------
__global__ __launch_bounds__(256) void k_amerge(const float* __restrict__ opart,
                                                const float* __restrict__ mlpart,
                                                bf16* __restrict__ outp,
                                                int b0, int nseg, int nbloc) {
  const int bh = blockIdx.x;
  const int bl = bh >> 4, h = bh & 15;
  const int nb64 = nbloc * 64;
  const int t = threadIdx.x;
  const int q = t >> 2, quarter = t & 3;

  float ms[8], ls[8];
  float mstar = -1e30f;
  for (int s = 0; s < nseg; ++s) {
    size_t mi = (((size_t)s * nb64 + bl * 64 + q) * 16 + h) * 2;
    ms[s] = mlpart[mi]; ls[s] = mlpart[mi + 1];
    mstar = fmaxf(mstar, ms[s]);
  }
  float L = 0.0f, ws[8];
  for (int s = 0; s < nseg; ++s) { ws[s] = __expf(ms[s] - mstar); L += ws[s] * ls[s]; }
  float inv = 1.0f / L;

  bf16* outrow = outp + (size_t)((b0 + bl) * 64 + q) * 1024 + h * 64;
#pragma unroll
  for (int jj = 0; jj < 4; ++jj) {
    int dh0 = quarter * 16 + jj * 4;
    float4v acc = {0.f, 0.f, 0.f, 0.f};
    for (int s = 0; s < nseg; ++s) {
      const float* orow = opart + ((size_t)s * nb64 + bl * 64 + q) * 1024 + h * 64 + dh0;
      float4v v = *(const float4v*)orow;
      acc[0] += ws[s] * v[0]; acc[1] += ws[s] * v[1];
      acc[2] += ws[s] * v[2]; acc[3] += ws[s] * v[3];
    }
    short4v sv;
    sv[0] = (short)f2b_bits(acc[0] * inv); sv[1] = (short)f2b_bits(acc[1] * inv);
    sv[2] = (short)f2b_bits(acc[2] * inv); sv[3] = (short)f2b_bits(acc[3] * inv);
    *(short4v*)((short*)(outrow + dh0)) = sv;
  }
}

// =========================== host ===========================
extern "C" void kernel_launch(void* const* d_in, const int* in_sizes, int n_in,
                              void* d_out, int out_size, void* d_ws, size_t ws_size,
                              hipStream_t stream) {
  (void)in_sizes; (void)n_in; (void)out_size;
  const float* id_emb = (const float*)d_in[0];
  const float* f_in[4]  = {(const float*)d_in[4],  (const float*)d_in[3],
                           (const float*)d_in[2],  (const float*)d_in[1]};
  const float* pw_in[4] = {(const float*)d_in[11], (const float*)d_in[9],
                           (const float*)d_in[7],  (const float*)d_in[5]};
  const float* pb_in[4] = {(const float*)d_in[12], (const float*)d_in[10],
                           (const float*)d_in[8],  (const float*)d_in[6]};
  const float* ln1w = (const float*)d_in[13];
  const float* ln1b = (const float*)d_in[14];
  const float* ln2w = (const float*)d_in[15];
  const float* ln2b = (const float*)d_in[16];
  const float* wq   = (const float*)d_in[17];
  const float* wkv  = (const float*)d_in[18];
  const float* wo   = (const float*)d_in[19];
  const float* fflnw = (const float*)d_in[20];
  const float* fflnb = (const float*)d_in[21];
  const float* ffw1  = (const float*)d_in[22];
  const float* ffw2  = (const float*)d_in[23];
  const float* projw = (const float*)d_in[24];
  const float* projb = (const float*)d_in[25];
  const float* normw = (const float*)d_in[26];
  const float* normb = (const float*)d_in[27];

  static const int N1S[4]  = {49, 196, 784, 3136};
  static const int FRDS[4] = {512, 256, 128, 64};
  static const int NSEG[4] = {1, 1, 2, 4};
  const size_t LW = 4718592;
  // rstats offsets per scale (rows = 16*n1)
  static const size_t ROFF[4] = {0, 16*49ull, 16*(49+196ull), 16*(49+196+784ull)};

  bf16 *fbf[4], *pT[4], *pbf[4], *projT, *PTbuf;
  float *qkvl_bias, *kvx_bias, *ff_bias, *lat, *headtmp, *svv, *bwv;
  float2 *rstats;
  float *opart, *mlpart;
  bf16 *qkvl_act, *attnout, *zlat, *latbf, *ffh;
  bf16 *wqkvlT = nullptr, *wkvxT = nullptr, *woT = nullptr, *w1T = nullptr, *w2T = nullptr;
  bf16 *wbuf = nullptr;
  char *big;

  auto assign = [&](bool fullw, int bc) -> size_t {
    size_t off = 0; char* base = (char*)d_ws;
    auto A = [&](size_t b) -> char* {
      char* p = base + off; off = (off + b + 255) & ~(size_t)255; return p;
    };
    for (int i = 0; i < 4; ++i) fbf[i] = (bf16*)A((size_t)16 * N1S[i] * FRDS[i] * 2);
    for (int i = 0; i < 4; ++i) pT[i]  = (bf16*)A((size_t)768 * FRDS[i] * 2);
    for (int i = 0; i < 4; ++i) pbf[i] = (bf16*)A((size_t)FRDS[i] * 768 * 2);
    projT     = (bf16*)A(768ull * 768 * 2);
    PTbuf     = (bf16*)A(2048ull * 512 * 2);
    qkvl_bias = (float*)A(24ull * 3072 * 4);
    kvx_bias  = (float*)A(24ull * 2048 * 4);
    ff_bias   = (float*)A(6ull * 3072 * 4);
    svv       = (float*)A(24ull * 2048 * 4);
    bwv       = (float*)A(24ull * 2048 * 4);
    rstats    = (float2*)A(16ull * 4165 * 8);
    qkvl_act  = (bf16*)A(1024ull * 3072 * 2);
    attnout   = (bf16*)A(1024ull * 1024 * 2);
    lat       = (float*)A(1024ull * 768 * 4);
    zlat      = (bf16*)A(1024ull * 768 * 2);
    opart     = (float*)A(4ull * (size_t)bc * 64 * 1024 * 4);
    mlpart    = (float*)A(4ull * (size_t)bc * 64 * 16 * 2 * 4);
    if (fullw) {
      wqkvlT = (bf16*)A(24ull * 3072 * 768 * 2);
      wkvxT  = (bf16*)A(24ull * 2048 * 768 * 2);
      woT    = (bf16*)A(24ull * 768 * 1024 * 2);
      w1T    = (bf16*)A(6ull * 3072 * 768 * 2);
      w2T    = (bf16*)A(6ull * 768 * 3072 * 2);
      wbuf = nullptr;
    } else {
      wbuf = (bf16*)A(4ull * LW * 2);
      wqkvlT = wkvxT = woT = w1T = w2T = nullptr;
    }
    big = A((size_t)bc * 3136 * 2048 * 2);
    ffh = qkvl_act; headtmp = (float*)qkvl_act; latbf = zlat;
    return off;
  };

  static const bool FULLS[10] = {true,true,false,true,false,true,true,false,false,false};
  static const int  BCS[10]   = {16,  8,   16,   4,   8,    2,   1,   4,    2,    1};
  bool fullw = false; int bc = 1; bool ok = false;
  for (int c = 0; c < 10; ++c) {
    if (assign(FULLS[c], BCS[c]) <= ws_size) { fullw = FULLS[c]; bc = BCS[c]; ok = true; break; }
  }
  if (!ok) return;

  float* featf32 = (float*)big;
  bf16*  kvxbuf  = (bf16*)big;

  auto gemm = [&](int tile, const bf16* A, const bf16* Bt, void* C,
                  const float* bias, const float* res, int M, int N, int K,
                  bool obf, bool gl) {
    if (tile == 128) {
      int nxt = N / 128, nwg = nxt * ((M + 127) / 128);
      if (obf && gl) k_gemm<128,128,true ,true ,false><<<nwg,256,0,stream>>>(A,Bt,C,bias,res,nullptr,nullptr,nullptr,M,N,K,nxt,nwg);
      else if (obf)  k_gemm<128,128,true ,false,false><<<nwg,256,0,stream>>>(A,Bt,C,bias,res,nullptr,nullptr,nullptr,M,N,K,nxt,nwg);
      else           k_gemm<128,128,false,false,false><<<nwg,256,0,stream>>>(A,Bt,C,bias,res,nullptr,nullptr,nullptr,M,N,K,nxt,nwg);
    } else if (tile == 64) {
      int nxt = N / 64, nwg = nxt * ((M + 63) / 64);
      if (obf && gl)  k_gemm<64,64,true ,true ,false><<<nwg,256,0,stream>>>(A,Bt,C,bias,res,nullptr,nullptr,nullptr,M,N,K,nxt,nwg);
      else if (obf)   k_gemm<64,64,true ,false,false><<<nwg,256,0,stream>>>(A,Bt,C,bias,res,nullptr,nullptr,nullptr,M,N,K,nxt,nwg);
      else            k_gemm<64,64,false,false,false><<<nwg,256,0,stream>>>(A,Bt,C,bias,res,nullptr,nullptr,nullptr,M,N,K,nxt,nwg);
    } else {
      int nxt = N / 64, nwg = nxt * ((M + 31) / 32);
      if (obf && gl)  k_gemm<32,64,true ,true ,false><<<nwg,256,0,stream>>>(A,Bt,C,bias,res,nullptr,nullptr,nullptr,M,N,K,nxt,nwg);
      else if (obf)   k_gemm<32,64,true ,false,false><<<nwg,256,0,stream>>>(A,Bt,C,bias,res,nullptr,nullptr,nullptr,M,N,K,nxt,nwg);
      else            k_gemm<32,64,false,false,false><<<nwg,256,0,stream>>>(A,Bt,C,bias,res,nullptr,nullptr,nullptr,M,N,K,nxt,nwg);
    }
  };
  auto gemmkv = [&](const bf16* A, const bf16* Bt, void* C,
                    const float* lb, const float2* rst, const float* c1, const float* cs,
                    int M, int N, int K) {
    if (M >= 2048) {
      int nxt = N / 128, nwg = nxt * ((M + 127) / 128);
      k_gemm<128,128,true,false,true><<<nwg,256,0,stream>>>(A,Bt,C,lb,nullptr,rst,c1,cs,M,N,K,nxt,nwg);
    } else {
      int nxt = N / 64, nwg = nxt * ((M + 63) / 64);
      k_gemm<64,64,true,false,true><<<nwg,256,0,stream>>>(A,Bt,C,lb,nullptr,rst,c1,cs,M,N,K,nxt,nwg);
    }
  };
  auto pick = [&](int M, int N) -> int {
    return M >= 2048 ? 128 : (N >= 1536 ? 64 : 32);
  };

  dim3 tb(32, 8);

  // ---- bias folds + kv low-rank vectors ----
  k_bfold <<<dim3(16, 24), 256, 0, stream>>>(wq,  ln2b, qkvl_bias, 768, 1024, 768LL*1024, 768, 3072);
  k_bfold2<<<dim3(32, 24), 256, 0, stream>>>(wkv, ln2b, ln1b, qkvl_bias + 1024, kvx_bias,
                                             768, 2048, 768LL*2048, 768, 3072, 2048);
  k_bfold <<<dim3(48, 6),  256, 0, stream>>>(ffw1, fflnb, ff_bias, 768, 3072, 768LL*3072, 768, 3072);
  k_kvvec <<<dim3(32, 24), 256, 0, stream>>>(wkv, ln1w, pb_in[0], pb_in[1], pb_in[2], pb_in[3],
                                             svv, bwv);

  // ---- small folded weights ----
  for (int i = 0; i < 4; ++i) {
    k_tfold<<<dim3(24, FRDS[i] / 32, 1), tb, 0, stream>>>(pw_in[i], nullptr, pT[i], FRDS[i], 768, 0, 0, 0);
    int cnt = FRDS[i] * 768;
    k_cvt<<<cnt / 1024, 256, 0, stream>>>(pw_in[i], pbf[i], cnt / 4);
  }
  k_tfold<<<dim3(24, 24, 1), tb, 0, stream>>>(projw, nullptr, projT, 768, 768, 0, 0, 0);

  // ---- full-mode weight folds ----
  if (fullw) {
    k_tfold <<<dim3(32, 24, 24), tb, 0, stream>>>(wq,  ln2w, wqkvlT, 768, 1024, 768LL*1024, 768, 3072LL*768);
    k_tfold2<<<dim3(64, 24, 24), tb, 0, stream>>>(wkv, ln2w, ln1w, wqkvlT + 1024LL*768, wkvxT,
                                                  768, 2048, 768LL*2048, 768, 3072LL*768, 2048LL*768);
    k_tfold <<<dim3(24, 32, 24), tb, 0, stream>>>(wo,  nullptr, woT, 1024, 768, 1024LL*768, 0, 768LL*1024);
    k_tfold <<<dim3(96, 24, 6),  tb, 0, stream>>>(ffw1, fflnw, w1T, 768, 3072, 768LL*3072, 768, 3072LL*768);
    k_tfold <<<dim3(24, 96, 6),  tb, 0, stream>>>(ffw2, nullptr, w2T, 3072, 768, 3072LL*768, 0, 768LL*3072);
  }

  auto foldDepthAttn = [&](int d) {
    k_tfold <<<dim3(32, 24, 4), tb, 0, stream>>>(wq  + (size_t)d*4*768*1024, ln2w + (size_t)d*4*768,
                                                 wbuf, 768, 1024, 768LL*1024, 768, (long long)LW);
    k_tfold2<<<dim3(64, 24, 4), tb, 0, stream>>>(wkv + (size_t)d*4*768*2048, ln2w + (size_t)d*4*768,
                                                 ln1w + (size_t)d*4*768,
                                                 wbuf + 1024ull*768, wbuf + 3072ull*768,
                                                 768, 2048, 768LL*2048, 768, (long long)LW, (long long)LW);
    k_tfold <<<dim3(24, 32, 4), tb, 0, stream>>>(wo  + (size_t)d*4*1024*768, nullptr,
                                                 wbuf + 3932160ull, 1024, 768, 1024LL*768, 0, (long long)LW);
  };
  auto attnW = [&](int di, const bf16*& qkvlT_p, const bf16*& kvxT_p, const bf16*& woT_p) {
    if (fullw) {
      qkvlT_p = wqkvlT + (size_t)di * 3072 * 768;
      kvxT_p  = wkvxT  + (size_t)di * 2048 * 768;
      woT_p   = woT    + (size_t)di * 768 * 1024;
    } else {
      bf16* base = wbuf + (size_t)(di & 3) * LW;
      qkvlT_p = base;
      kvxT_p  = base + 2359296ull;
      woT_p   = base + 3932160ull;
    }
  };
  auto ffW = [&](int d, const bf16*& w1p, const bf16*& w2p) {
    if (fullw) {
      w1p = w1T + (size_t)d * 3072 * 768;
      w2p = w2T + (size_t)d * 768 * 3072;
    } else {
      bf16* d1 = wbuf;
      bf16* d2 = wbuf + 3072ull * 768;
      k_tfold<<<dim3(96, 24, 1), tb, 0, stream>>>(ffw1 + (size_t)d*768*3072, fflnw + 768ull*d, d1,  768, 3072, 0, 0, 0);
      k_tfold<<<dim3(24, 96, 1), tb, 0, stream>>>(ffw2 + (size_t)d*3072*768, nullptr,          d2, 3072,  768, 0, 0, 0);
      w1p = d1; w2p = d2;
    }
  };

  // ---- feature projection -> row stats only (no normalized copy needed) ----
  for (int i = 0; i < 4; ++i) {
    int n1 = N1S[i], frd = FRDS[i];
    size_t cnt = (size_t)16 * n1 * frd;
    k_cvt<<<(int)(cnt / 1024), 256, 0, stream>>>(f_in[i], fbf[i], (int)(cnt / 4));
    for (int b0 = 0; b0 < 16; b0 += bc) {
      int rows = bc * n1;
      gemm(pick(rows, 768), fbf[i] + (size_t)b0 * n1 * frd, pT[i], featf32,
           pb_in[i], nullptr, rows, 768, frd, false, false);
      k_stats<<<rows, 256, 0, stream>>>(featf32, rstats + ROFF[i] + (size_t)b0 * n1);
    }
  }

  hipMemcpyAsync(lat, id_emb, 1024ull * 768 * 4, hipMemcpyDeviceToDevice, stream);

  // ---- depth loop ----
  for (int d = 0; d < 6; ++d) {
    if (!fullw) foldDepthAttn(d);
    for (int i = 0; i < 4; ++i) {
      int di = d * 4 + i, n1 = N1S[i], nseg = NSEG[i], frd = FRDS[i];
      const bf16 *qkvlT_p, *kvxT_p, *woT_p;
      attnW(di, qkvlT_p, kvxT_p, woT_p);
      // PT = (diag(ln1w)*wkv)^T @ p^T  -> (2048 x FRD), the Bt operand of low-rank kv
      gemm(64, kvxT_p, pbf[i], PTbuf, nullptr, nullptr, 2048, frd, 768, true, false);
      k_std<<<1024, 256, 0, stream>>>(lat, zlat);
      gemm(64, zlat, qkvlT_p, qkvl_act, qkvl_bias + 3072ull * di, nullptr,
           1024, 3072, 768, true, false);
      for (int b0 = 0; b0 < 16; b0 += bc) {
        int rows = bc * n1;
        gemmkv(fbf[i] + (size_t)b0 * n1 * frd, PTbuf, kvxbuf,
               kvx_bias + 2048ull * di, rstats + ROFF[i] + (size_t)b0 * n1,
               bwv + 2048ull * di, svv + 2048ull * di, rows, 2048, frd);
        k_attn<<<bc * 16 * nseg, 256, 0, stream>>>(qkvl_act, kvxbuf, attnout,
                                                   opart, mlpart, n1, b0, nseg, bc);
        if (nseg > 1)
          k_amerge<<<bc * 16, 256, 0, stream>>>(opart, mlpart, attnout, b0, nseg, bc);
      }
      gemm(32, attnout, woT_p, lat, nullptr, lat, 1024, 768, 1024, false, false);
    }
    const bf16 *w1p, *w2p;
    ffW(d, w1p, w2p);
    k_std<<<1024, 256, 0, stream>>>(lat, zlat);
    gemm(64, zlat, w1p, ffh, ff_bias + 3072ull * d, nullptr, 1024, 3072, 768, true, true);
    gemm(32, ffh, w2p, lat, nullptr, lat, 1024, 768, 3072, false, false);
  }

  // ---- head ----
  k_cvt<<<768, 256, 0, stream>>>(lat, latbf, 196608);
  gemm(32, latbf, projT, headtmp, projb, nullptr, 1024, 768, 768, false, false);
  k_lnout<<<1024, 256, 0, stream>>>(headtmp, normw, normb, (float*)d_out);
}

// Round 9
// 3529.429 us; speedup vs baseline: 1.9169x; 1.1531x over previous
//
#include <hip/hip_runtime.h>
#include <hip/hip_bf16.h>
#include <cstdint>
#include <cstddef>

typedef __hip_bfloat16 bf16;
typedef float  f32x4   __attribute__((ext_vector_type(4)));
typedef float  float4v __attribute__((ext_vector_type(4)));
typedef short  short8  __attribute__((ext_vector_type(8)));
typedef short  short4v __attribute__((ext_vector_type(4)));
typedef __bf16 bf16x8  __attribute__((ext_vector_type(8)));

__device__ __forceinline__ void mfma16(f32x4& d, short8 a, short8 b) {
  d = __builtin_amdgcn_mfma_f32_16x16x32_bf16(
      __builtin_bit_cast(bf16x8, a), __builtin_bit_cast(bf16x8, b), d, 0, 0, 0);
}
__device__ __forceinline__ unsigned short f2b_bits(float x) {
  __hip_bfloat16 h = __float2bfloat16(x);
  return __builtin_bit_cast(unsigned short, h);
}
__device__ __forceinline__ float gelu_exact(float x) {
  return 0.5f * x * (1.0f + erff(x * 0.7071067811865475f));
}

// ---------- f32 -> bf16 convert, 4 elems/thread ----------
__global__ __launch_bounds__(256) void k_cvt(const float* __restrict__ src,
                                             bf16* __restrict__ dst, int n4) {
  int i = blockIdx.x * 256 + threadIdx.x;
  if (i >= n4) return;
  float4v v = *(const float4v*)(src + (size_t)i * 4);
  short4v s;
  s[0] = (short)f2b_bits(v[0]); s[1] = (short)f2b_bits(v[1]);
  s[2] = (short)f2b_bits(v[2]); s[3] = (short)f2b_bits(v[3]);
  *(short4v*)((short*)dst + (size_t)i * 4) = s;
}

// ---------- transpose (+optional per-k scale): f32 (K,N) -> bf16 (N,K) ----------
__global__ void k_tfold(const float* __restrict__ src, const float* __restrict__ scale,
                        bf16* __restrict__ dst, int K, int N,
                        long long src_bs, long long scale_bs, long long dst_bs) {
  src += (size_t)blockIdx.z * src_bs;
  dst += (size_t)blockIdx.z * dst_bs;
  const float* sc = scale ? scale + (size_t)blockIdx.z * scale_bs : nullptr;
  __shared__ float tile[32][33];
  int n0 = blockIdx.x * 32, k0 = blockIdx.y * 32;
  int tx = threadIdx.x, ty = threadIdx.y;
#pragma unroll
  for (int j = 0; j < 4; ++j) {
    int k = k0 + ty + j * 8;
    float s = sc ? sc[k] : 1.0f;
    tile[ty + j * 8][tx] = src[(size_t)k * N + n0 + tx] * s;
  }
  __syncthreads();
#pragma unroll
  for (int j = 0; j < 4; ++j) {
    int n = n0 + ty + j * 8;
    dst[(size_t)n * K + k0 + tx] = __float2bfloat16(tile[tx][ty + j * 8]);
  }
}

// ---------- dual transpose-fold ----------
__global__ void k_tfold2(const float* __restrict__ src,
                         const float* __restrict__ s1, const float* __restrict__ s2,
                         bf16* __restrict__ d1, bf16* __restrict__ d2, int K, int N,
                         long long src_bs, long long s_bs,
                         long long d1_bs, long long d2_bs) {
  src += (size_t)blockIdx.z * src_bs;
  d1  += (size_t)blockIdx.z * d1_bs;
  d2  += (size_t)blockIdx.z * d2_bs;
  s1  += (size_t)blockIdx.z * s_bs;
  s2  += (size_t)blockIdx.z * s_bs;
  __shared__ float tile[32][33];
  __shared__ float sc1[32], sc2[32];
  int n0 = blockIdx.x * 32, k0 = blockIdx.y * 32;
  int tx = threadIdx.x, ty = threadIdx.y;
  if (ty == 0) { sc1[tx] = s1[k0 + tx]; sc2[tx] = s2[k0 + tx]; }
#pragma unroll
  for (int j = 0; j < 4; ++j) {
    int k = k0 + ty + j * 8;
    tile[ty + j * 8][tx] = src[(size_t)k * N + n0 + tx];
  }
  __syncthreads();
#pragma unroll
  for (int j = 0; j < 4; ++j) {
    int n = n0 + ty + j * 8;
    float v = tile[tx][ty + j * 8];
    d1[(size_t)n * K + k0 + tx] = __float2bfloat16(v * sc1[tx]);
    d2[(size_t)n * K + k0 + tx] = __float2bfloat16(v * sc2[tx]);
  }
}

// ---------- bias fold ----------
__global__ __launch_bounds__(256) void k_bfold(const float* __restrict__ W,
                                               const float* __restrict__ lnb,
                                               float* __restrict__ out, int K, int N,
                                               long long w_bs, long long b_bs, long long o_bs) {
  W   += (size_t)blockIdx.y * w_bs;
  lnb += (size_t)blockIdx.y * b_bs;
  out += (size_t)blockIdx.y * o_bs;
  const int l = threadIdx.x & 63, kg = threadIdx.x >> 6;
  const int n = blockIdx.x * 64 + l;
  float a = 0.0f;
  for (int k = kg; k < K; k += 4) a = fmaf(lnb[k], W[(size_t)k * N + n], a);
  __shared__ float red[4][64];
  red[kg][l] = a;
  __syncthreads();
  if (kg == 0) out[n] = (red[0][l] + red[1][l]) + (red[2][l] + red[3][l]);
}

// ---------- dual bias fold ----------
__global__ __launch_bounds__(256) void k_bfold2(const float* __restrict__ W,
                                                const float* __restrict__ b1,
                                                const float* __restrict__ b2,
                                                float* __restrict__ o1,
                                                float* __restrict__ o2, int K, int N,
                                                long long w_bs, long long b_bs,
                                                long long o1_bs, long long o2_bs) {
  W  += (size_t)blockIdx.y * w_bs;
  b1 += (size_t)blockIdx.y * b_bs;
  b2 += (size_t)blockIdx.y * b_bs;
  o1 += (size_t)blockIdx.y * o1_bs;
  o2 += (size_t)blockIdx.y * o2_bs;
  const int l = threadIdx.x & 63, kg = threadIdx.x >> 6;
  const int n = blockIdx.x * 64 + l;
  float a1 = 0.0f, a2 = 0.0f;
  for (int k = kg; k < K; k += 4) {
    float wv = W[(size_t)k * N + n];
    a1 = fmaf(b1[k], wv, a1);
    a2 = fmaf(b2[k], wv, a2);
  }
  __shared__ float r1[4][64], r2[4][64];
  r1[kg][l] = a1; r2[kg][l] = a2;
  __syncthreads();
  if (kg == 0) {
    o1[n] = (r1[0][l] + r1[1][l]) + (r1[2][l] + r1[3][l]);
    o2[n] = (r2[0][l] + r2[1][l]) + (r2[2][l] + r2[3][l]);
  }
}

// ---------- kv low-rank vectors ----------
__global__ __launch_bounds__(256) void k_kvvec(const float* __restrict__ wkv,
                                               const float* __restrict__ ln1w,
                                               const float* __restrict__ b0,
                                               const float* __restrict__ b1,
                                               const float* __restrict__ b2,
                                               const float* __restrict__ b3,
                                               float* __restrict__ sv,
                                               float* __restrict__ bwv) {
  const int di = blockIdx.y;
  const int i = di & 3;
  const float* b = (i == 0) ? b0 : (i == 1) ? b1 : (i == 2) ? b2 : b3;
  const float* W = wkv + (size_t)di * 768 * 2048;
  const float* lw = ln1w + (size_t)di * 768;
  const int l = threadIdx.x & 63, kg = threadIdx.x >> 6;
  const int n = blockIdx.x * 64 + l;
  float a1 = 0.0f, a2 = 0.0f;
  for (int k = kg; k < 768; k += 4) {
    float wv = W[(size_t)k * 2048 + n];
    float lwk = lw[k];
    a1 = fmaf(lwk, wv, a1);
    a2 = fmaf(b[k] * lwk, wv, a2);
  }
  __shared__ float r1[4][64], r2[4][64];
  r1[kg][l] = a1; r2[kg][l] = a2;
  __syncthreads();
  if (kg == 0) {
    sv [(size_t)di * 2048 + n] = (r1[0][l] + r1[1][l]) + (r1[2][l] + r1[3][l]);
    bwv[(size_t)di * 2048 + n] = (r2[0][l] + r2[1][l]) + (r2[2][l] + r2[3][l]);
  }
}

// ---------- row standardize (768-wide), f32 -> bf16 ----------
__global__ __launch_bounds__(256) void k_std(const float* __restrict__ src,
                                             bf16* __restrict__ dst) {
  int row = blockIdx.x;
  const float* x = src + (size_t)row * 768;
  int t = threadIdx.x;
  float a0 = x[t], a1 = x[t + 256], a2 = x[t + 512];
  float s = a0 + a1 + a2;
  float q = a0 * a0 + a1 * a1 + a2 * a2;
#pragma unroll
  for (int off = 1; off < 64; off <<= 1) { s += __shfl_xor(s, off); q += __shfl_xor(q, off); }
  __shared__ float ss[4], qs[4];
  if ((t & 63) == 0) { ss[t >> 6] = s; qs[t >> 6] = q; }
  __syncthreads();
  s = ss[0] + ss[1] + ss[2] + ss[3];
  q = qs[0] + qs[1] + qs[2] + qs[3];
  float mean = s * (1.0f / 768.0f);
  float var  = q * (1.0f / 768.0f) - mean * mean;
  float inv  = rsqrtf(var + 1e-5f);
  bf16* d = dst + (size_t)row * 768;
  d[t]       = __float2bfloat16((a0 - mean) * inv);
  d[t + 256] = __float2bfloat16((a1 - mean) * inv);
  d[t + 512] = __float2bfloat16((a2 - mean) * inv);
}

// ---------- row stats only (768-wide): out[row] = {inv, mean*inv} ----------
__global__ __launch_bounds__(256) void k_stats(const float* __restrict__ src,
                                               float2* __restrict__ out) {
  int row = blockIdx.x;
  const float* x = src + (size_t)row * 768;
  int t = threadIdx.x;
  float a0 = x[t], a1 = x[t + 256], a2 = x[t + 512];
  float s = a0 + a1 + a2;
  float q = a0 * a0 + a1 * a1 + a2 * a2;
#pragma unroll
  for (int off = 1; off < 64; off <<= 1) { s += __shfl_xor(s, off); q += __shfl_xor(q, off); }
  __shared__ float ss[4], qs[4];
  if ((t & 63) == 0) { ss[t >> 6] = s; qs[t >> 6] = q; }
  __syncthreads();
  if (t == 0) {
    float sm = ss[0] + ss[1] + ss[2] + ss[3];
    float qm = qs[0] + qs[1] + qs[2] + qs[3];
    float mean = sm * (1.0f / 768.0f);
    float var  = qm * (1.0f / 768.0f) - mean * mean;
    float inv  = rsqrtf(var + 1e-5f);
    out[row] = make_float2(inv, mean * inv);
  }
}

// ---------- final layernorm (768-wide) with w,b: f32 -> f32 ----------
__global__ __launch_bounds__(256) void k_lnout(const float* __restrict__ src,
                                               const float* __restrict__ w,
                                               const float* __restrict__ b,
                                               float* __restrict__ dst) {
  int row = blockIdx.x;
  const float* x = src + (size_t)row * 768;
  int t = threadIdx.x;
  float a0 = x[t], a1 = x[t + 256], a2 = x[t + 512];
  float s = a0 + a1 + a2;
  float q = a0 * a0 + a1 * a1 + a2 * a2;
#pragma unroll
  for (int off = 1; off < 64; off <<= 1) { s += __shfl_xor(s, off); q += __shfl_xor(q, off); }
  __shared__ float ss[4], qs[4];
  if ((t & 63) == 0) { ss[t >> 6] = s; qs[t >> 6] = q; }
  __syncthreads();
  s = ss[0] + ss[1] + ss[2] + ss[3];
  q = qs[0] + qs[1] + qs[2] + qs[3];
  float mean = s * (1.0f / 768.0f);
  float var  = q * (1.0f / 768.0f) - mean * mean;
  float inv  = rsqrtf(var + 1e-5f);
  float* d = dst + (size_t)row * 768;
  d[t]       = (a0 - mean) * inv * w[t]       + b[t];
  d[t + 256] = (a1 - mean) * inv * w[t + 256] + b[t + 256];
  d[t + 512] = (a2 - mean) * inv * w[t + 512] + b[t + 512];
}

// ---------- MFMA GEMM (reg-staged pipeline + XCD swizzle) ----------
// bf16 output path: staged LDS epilogue -> short8 (16B) coalesced stores.
// KVE epilogue: out = (acc + c1[n])*inv_r - muinv_r*cs[n] + bias[n]
template <int BM, int BN, bool OBF16, bool GELU, bool KVE>
__global__ __launch_bounds__(256) void k_gemm(const bf16* __restrict__ A,
                                              const bf16* __restrict__ Bt,
                                              void* __restrict__ Cv,
                                              const float* __restrict__ bias,
                                              const float* __restrict__ res,
                                              const float2* __restrict__ rstats,
                                              const float* __restrict__ c1,
                                              const float* __restrict__ cs,
                                              int M, int N, int K, int nxt, int nwg) {
  constexpr int AI = BM / 32, BI = BN / 32;
  constexpr int MF = BM / 32, NF = BN / 32;
  __shared__ __align__(16) char smem[(BM + BN) * 128];
  char* As = smem;
  char* Bs = smem + BM * 128;

  const int lin = blockIdx.x;
  const int qq = nwg >> 3, r8 = nwg & 7;
  const int xcd = lin & 7, idx = lin >> 3;
  const int swz = (xcd < r8) ? (xcd * (qq + 1) + idx)
                             : (r8 * (qq + 1) + (xcd - r8) * qq + idx);
  const int bm = (swz / nxt) * BM, bn = (swz % nxt) * BN;

  const int t = threadIdx.x, lane = t & 63, w = t >> 6;
  const int wr = w >> 1, wc = w & 1;
  const int l15 = lane & 15, lg = lane >> 4;
  const int srow = t >> 3, scol = t & 7;

  const bf16* aptr[AI]; int aoff[AI];
#pragma unroll
  for (int i = 0; i < AI; ++i) {
    int r = i * 32 + srow;
    int gr = bm + r; if (gr > M - 1) gr = M - 1;
    aptr[i] = A + (size_t)gr * K + scol * 8;
    aoff[i] = r * 128 + ((scol * 16) ^ ((r & 7) << 4));
  }
  const bf16* bptr[BI]; int boff[BI];
#pragma unroll
  for (int i = 0; i < BI; ++i) {
    int r = i * 32 + srow;
    int gc = bn + r; if (gc > N - 1) gc = N - 1;
    bptr[i] = Bt + (size_t)gc * K + scol * 8;
    boff[i] = r * 128 + ((scol * 16) ^ ((r & 7) << 4));
  }

  f32x4 acc[MF][NF] = {};
  short8 av[AI], bv[BI];
#pragma unroll
  for (int i = 0; i < AI; ++i) av[i] = *(const short8*)(aptr[i]);
#pragma unroll
  for (int i = 0; i < BI; ++i) bv[i] = *(const short8*)(bptr[i]);

  const int nk = K / 64;
  for (int kt = 0; kt < nk; ++kt) {
    __syncthreads();
#pragma unroll
    for (int i = 0; i < AI; ++i) *(short8*)(As + aoff[i]) = av[i];
#pragma unroll
    for (int i = 0; i < BI; ++i) *(short8*)(Bs + boff[i]) = bv[i];
    __syncthreads();
    if (kt + 1 < nk) {
#pragma unroll
      for (int i = 0; i < AI; ++i) av[i] = *(const short8*)(aptr[i] + (size_t)(kt + 1) * 64);
#pragma unroll
      for (int i = 0; i < BI; ++i) bv[i] = *(const short8*)(bptr[i] + (size_t)(kt + 1) * 64);
    }
#pragma unroll
    for (int ks = 0; ks < 2; ++ks) {
      short8 af[MF], bfr[NF];
#pragma unroll
      for (int m = 0; m < MF; ++m) {
        int r = wr * (BM / 2) + m * 16 + l15;
        af[m] = *(const short8*)(As + r * 128 + ((ks * 64 + lg * 16) ^ ((r & 7) << 4)));
      }
#pragma unroll
      for (int n = 0; n < NF; ++n) {
        int r = wc * (BN / 2) + n * 16 + l15;
        bfr[n] = *(const short8*)(Bs + r * 128 + ((ks * 64 + lg * 16) ^ ((r & 7) << 4)));
      }
#pragma unroll
      for (int m = 0; m < MF; ++m)
#pragma unroll
        for (int n = 0; n < NF; ++n) mfma16(acc[m][n], af[m], bfr[n]);
    }
  }

  if (OBF16) {
    // staged epilogue: acc -> bf16 in LDS, then 16B coalesced stores
    __syncthreads();                       // all waves done reading As/Bs
    bf16* cst = (bf16*)smem;               // BM*BN bf16 <= (BM+BN)*128 bytes
#pragma unroll
    for (int m = 0; m < MF; ++m) {
      int lr0 = wr * (BM / 2) + m * 16 + lg * 4;
#pragma unroll
      for (int n = 0; n < NF; ++n) {
        int lc = wc * (BN / 2) + n * 16 + l15;
        int gc = bn + lc;
        float bvs = bias ? bias[gc] : 0.0f;
        float c1v = 0.0f, csv = 0.0f;
        if (KVE) { c1v = c1[gc]; csv = cs[gc]; }
#pragma unroll
        for (int r = 0; r < 4; ++r) {
          int row = lr0 + r;
          float v;
          if (KVE) {
            int gri = bm + row; if (gri > M - 1) gri = M - 1;
            float2 st = rstats[gri];
            v = (acc[m][n][r] + c1v) * st.x - st.y * csv + bvs;
          } else {
            v = acc[m][n][r] + bvs;
            if (GELU) v = gelu_exact(v);
          }
          cst[row * BN + lc] = __float2bfloat16(v);
        }
      }
    }
    __syncthreads();
    constexpr int CB = BN / 8;             // short8 blocks per row
    constexpr int SEGS = BM * CB;
    for (int seg = t; seg < SEGS; seg += 256) {
      int row = seg / CB, cb = seg % CB;
      int gr = bm + row;
      if (gr < M)
        *(short8*)((bf16*)Cv + (size_t)gr * N + bn + cb * 8) =
            *(const short8*)(cst + (size_t)row * BN + cb * 8);
    }
  } else {
#pragma unroll
    for (int m = 0; m < MF; ++m) {
      int gr0 = bm + wr * (BM / 2) + m * 16 + lg * 4;
#pragma unroll
      for (int n = 0; n < NF; ++n) {
        int gc = bn + wc * (BN / 2) + n * 16 + l15;
        float bvs = bias ? bias[gc] : 0.0f;
#pragma unroll
        for (int r = 0; r < 4; ++r) {
          int gr = gr0 + r;
          if (gr < M) {
            float v = acc[m][n][r] + bvs;
            if (GELU) v = gelu_exact(v);
            if (res) v += res[(size_t)gr * N + gc];
            ((float*)Cv)[(size_t)gr * N + gc] = v;
          }
        }
      }
    }
  }
}

// ---------- fused attention, split-KV + swapped-QK^T softmax ----------
__global__ __launch_bounds__(256) void k_attn(const bf16* __restrict__ qkvl,
                                              const bf16* __restrict__ kvx,
                                              bf16* __restrict__ outp,
                                              float* __restrict__ opart,
                                              float* __restrict__ mlpart,
                                              int n1, int b0, int nseg, int nbloc) {
  const int s   = blockIdx.x % nseg;
  const int bh  = blockIdx.x / nseg;
  const int bl = bh >> 4, h = bh & 15;
  const int b = b0 + bl;
  const int nb64 = nbloc * 64;
  __shared__ __align__(16) char Qs[64 * 128];
  __shared__ __align__(16) char Ks[64 * 128];
  __shared__ __align__(16) char Vt[64 * 128];
  __shared__ __align__(16) char Ps[4][16 * 128];
  const int t = threadIdx.x, lane = t & 63, w = t >> 6;
  const int l15 = lane & 15, lg = lane >> 4;

#pragma unroll
  for (int it = 0; it < 2; ++it) {
    int slot = it * 256 + t; int r = slot >> 3, c = slot & 7;
    short8 v = *(const short8*)(qkvl + (size_t)(b * 64 + r) * 3072 + h * 64 + c * 8);
    *(short8*)(Qs + r * 128 + ((c * 16) ^ ((r & 7) << 4))) = v;
  }
  const int n_kv = n1 + 64;
  const int nch = (n_kv + 63) >> 6;
  const int cpseg = (nch + nseg - 1) / nseg;
  const int ch0 = s * cpseg;
  const int ch1 = min(nch, ch0 + cpseg);

  float m_run = -1e30f, l_run = 0.0f;
  f32x4 o[4] = {};

  short8 kreg[2], vreg[2];
  auto loadKV = [&](int ch) {
#pragma unroll
    for (int it = 0; it < 2; ++it) {
      int slot = it * 256 + t; int rr = slot >> 3, c = slot & 7;
      int j = ch * 64 + rr;
      short8 kv = {}; short8 vv = {};
      if (j < n_kv) {
        const bf16* kb;
        if (j < n1) kb = kvx + (size_t)(bl * n1 + j) * 2048 + h * 64;
        else        kb = qkvl + (size_t)(b * 64 + (j - n1)) * 3072 + 1024 + h * 64;
        kv = *(const short8*)(kb + c * 8);
        vv = *(const short8*)(kb + 1024 + c * 8);
      }
      kreg[it] = kv; vreg[it] = vv;
    }
  };
  loadKV(ch0);

  for (int ch = ch0; ch < ch1; ++ch) {
    __syncthreads();
#pragma unroll
    for (int it = 0; it < 2; ++it) {
      int slot = it * 256 + t; int rr = slot >> 3, c = slot & 7;
      *(short8*)(Ks + rr * 128 + ((c * 16) ^ ((rr & 7) << 4))) = kreg[it];
#pragma unroll
      for (int j2 = 0; j2 < 8; ++j2) {
        int dh = c * 8 + j2;
        *(short*)(Vt + dh * 128 + ((rr * 2) ^ ((dh & 7) << 4))) = vreg[it][j2];
      }
    }
    __syncthreads();
    if (ch + 1 < ch1) loadKV(ch + 1);

    f32x4 sc[4] = {};
#pragma unroll
    for (int ks = 0; ks < 2; ++ks) {
      int qr = w * 16 + l15;
      short8 qf = *(const short8*)(Qs + qr * 128 + ((ks * 64 + lg * 16) ^ ((qr & 7) << 4)));
#pragma unroll
      for (int n = 0; n < 4; ++n) {
        int kr = n * 16 + l15;
        short8 kf = *(const short8*)(Ks + kr * 128 + ((ks * 64 + lg * 16) ^ ((kr & 7) << 4)));
        mfma16(sc[n], kf, qf);
      }
    }
    float mx = m_run;
#pragma unroll
    for (int n = 0; n < 4; ++n)
#pragma unroll
      for (int r = 0; r < 4; ++r) {
        float v = sc[n][r] * 0.125f;
        int kvi = ch * 64 + n * 16 + lg * 4 + r;
        if (kvi >= n_kv) v = -1e30f;
        sc[n][r] = v;
        mx = fmaxf(mx, v);
      }
    mx = fmaxf(mx, __shfl_xor(mx, 16));
    mx = fmaxf(mx, __shfl_xor(mx, 32));
    float scl = __expf(m_run - mx);
    m_run = mx;
    float p[4][4];
    float rs = 0.0f;
#pragma unroll
    for (int n = 0; n < 4; ++n)
#pragma unroll
      for (int r = 0; r < 4; ++r) { float pv = __expf(sc[n][r] - mx); p[n][r] = pv; rs += pv; }
    rs += __shfl_xor(rs, 16);
    rs += __shfl_xor(rs, 32);
    l_run = l_run * scl + rs;
    float sclq[4];
#pragma unroll
    for (int r = 0; r < 4; ++r) sclq[r] = __shfl(scl, lg * 4 + r);
#pragma unroll
    for (int nn = 0; nn < 4; ++nn)
#pragma unroll
      for (int r = 0; r < 4; ++r) o[nn][r] *= sclq[r];
#pragma unroll
    for (int n = 0; n < 4; ++n)
#pragma unroll
      for (int r = 0; r < 4; ++r) {
        int kv = n * 16 + lg * 4 + r;
        *(unsigned short*)(Ps[w] + l15 * 128 + ((kv * 2) ^ ((l15 & 7) << 4))) = f2b_bits(p[n][r]);
      }
#pragma unroll
    for (int ks = 0; ks < 2; ++ks) {
      short8 pf = *(const short8*)(Ps[w] + l15 * 128 + ((ks * 64 + lg * 16) ^ ((l15 & 7) << 4)));
#pragma unroll
      for (int nn = 0; nn < 4; ++nn) {
        int dh = nn * 16 + l15;
        short8 vf = *(const short8*)(Vt + dh * 128 + ((ks * 64 + lg * 16) ^ ((dh & 7) << 4)));
        mfma16(o[nn], pf, vf);
      }
    }
  }

  if (nseg == 1) {
    float lq[4];
#pragma unroll
    for (int r = 0; r < 4; ++r) lq[r] = __shfl(l_run, lg * 4 + r);
#pragma unroll
    for (int nn = 0; nn < 4; ++nn)
#pragma unroll
      for (int r = 0; r < 4; ++r) {
        int qr = w * 16 + lg * 4 + r;
        int dh = nn * 16 + l15;
        outp[(size_t)(b * 64 + qr) * 1024 + h * 64 + dh] = __float2bfloat16(o[nn][r] / lq[r]);
      }
  } else {
#pragma unroll
    for (int nn = 0; nn < 4; ++nn)
#pragma unroll
      for (int r = 0; r < 4; ++r) {
        int qr = w * 16 + lg * 4 + r;
        int dh = nn * 16 + l15;
        opart[((size_t)s * nb64 + bl * 64 + qr) * 1024 + h * 64 + dh] = o[nn][r];
      }
    if (lg == 0) {
      int qr = w * 16 + l15;
      size_t mi = (((size_t)s * nb64 + bl * 64 + qr) * 16 + h) * 2;
      mlpart[mi]     = m_run;
      mlpart[mi + 1] = l_run;
    }
  }
}

// ---------- merge split-KV partials ----------
__global__ __launch_bounds__(256) void k_amerge(const float* __restrict__ opart,
                                                const float* __restrict__ mlpart,
                                                bf16* __restrict__ outp,
                                                int b0, int nseg, int nbloc) {
  const int bh = blockIdx.x;
  const int bl = bh >> 4, h = bh & 15;
  const int nb64 = nbloc * 64;
  const int t = threadIdx.x;
  const int q = t >> 2, quarter = t & 3;

  float ms[8], ls[8];
  float mstar = -1e30f;
  for (int s = 0; s < nseg; ++s) {
    size_t mi = (((size_t)s * nb64 + bl * 64 + q) * 16 + h) * 2;
    ms[s] = mlpart[mi]; ls[s] = mlpart[mi + 1];
    mstar = fmaxf(mstar, ms[s]);
  }
  float L = 0.0f, ws[8];
  for (int s = 0; s < nseg; ++s) { ws[s] = __expf(ms[s] - mstar); L += ws[s] * ls[s]; }
  float inv = 1.0f / L;

  bf16* outrow = outp + (size_t)((b0 + bl) * 64 + q) * 1024 + h * 64;
#pragma unroll
  for (int jj = 0; jj < 4; ++jj) {
    int dh0 = quarter * 16 + jj * 4;
    float4v acc = {0.f, 0.f, 0.f, 0.f};
    for (int s = 0; s < nseg; ++s) {
      const float* orow = opart + ((size_t)s * nb64 + bl * 64 + q) * 1024 + h * 64 + dh0;
      float4v v = *(const float4v*)orow;
      acc[0] += ws[s] * v[0]; acc[1] += ws[s] * v[1];
      acc[2] += ws[s] * v[2]; acc[3] += ws[s] * v[3];
    }
    short4v sv;
    sv[0] = (short)f2b_bits(acc[0] * inv); sv[1] = (short)f2b_bits(acc[1] * inv);
    sv[2] = (short)f2b_bits(acc[2] * inv); sv[3] = (short)f2b_bits(acc[3] * inv);
    *(short4v*)((short*)(outrow + dh0)) = sv;
  }
}

// =========================== host ===========================
extern "C" void kernel_launch(void* const* d_in, const int* in_sizes, int n_in,
                              void* d_out, int out_size, void* d_ws, size_t ws_size,
                              hipStream_t stream) {
  (void)in_sizes; (void)n_in; (void)out_size;
  const float* id_emb = (const float*)d_in[0];
  const float* f_in[4]  = {(const float*)d_in[4],  (const float*)d_in[3],
                           (const float*)d_in[2],  (const float*)d_in[1]};
  const float* pw_in[4] = {(const float*)d_in[11], (const float*)d_in[9],
                           (const float*)d_in[7],  (const float*)d_in[5]};
  const float* pb_in[4] = {(const float*)d_in[12], (const float*)d_in[10],
                           (const float*)d_in[8],  (const float*)d_in[6]};
  const float* ln1w = (const float*)d_in[13];
  const float* ln1b = (const float*)d_in[14];
  const float* ln2w = (const float*)d_in[15];
  const float* ln2b = (const float*)d_in[16];
  const float* wq   = (const float*)d_in[17];
  const float* wkv  = (const float*)d_in[18];
  const float* wo   = (const float*)d_in[19];
  const float* fflnw = (const float*)d_in[20];
  const float* fflnb = (const float*)d_in[21];
  const float* ffw1  = (const float*)d_in[22];
  const float* ffw2  = (const float*)d_in[23];
  const float* projw = (const float*)d_in[24];
  const float* projb = (const float*)d_in[25];
  const float* normw = (const float*)d_in[26];
  const float* normb = (const float*)d_in[27];

  static const int N1S[4]  = {49, 196, 784, 3136};
  static const int FRDS[4] = {512, 256, 128, 64};
  static const int NSEG[4] = {1, 1, 2, 4};
  const size_t LW = 4718592;
  static const size_t ROFF[4] = {0, 16*49ull, 16*(49+196ull), 16*(49+196+784ull)};

  bf16 *fbf[4], *pT[4], *pbf[4], *projT, *PTbuf;
  float *qkvl_bias, *kvx_bias, *ff_bias, *lat, *headtmp, *svv, *bwv;
  float2 *rstats;
  float *opart, *mlpart;
  bf16 *qkvl_act, *attnout, *zlat, *latbf, *ffh;
  bf16 *wqkvlT = nullptr, *wkvxT = nullptr, *woT = nullptr, *w1T = nullptr, *w2T = nullptr;
  bf16 *wbuf = nullptr;
  char *big;

  auto assign = [&](bool fullw, int bc) -> size_t {
    size_t off = 0; char* base = (char*)d_ws;
    auto A = [&](size_t b) -> char* {
      char* p = base + off; off = (off + b + 255) & ~(size_t)255; return p;
    };
    for (int i = 0; i < 4; ++i) fbf[i] = (bf16*)A((size_t)16 * N1S[i] * FRDS[i] * 2);
    for (int i = 0; i < 4; ++i) pT[i]  = (bf16*)A((size_t)768 * FRDS[i] * 2);
    for (int i = 0; i < 4; ++i) pbf[i] = (bf16*)A((size_t)FRDS[i] * 768 * 2);
    projT     = (bf16*)A(768ull * 768 * 2);
    PTbuf     = (bf16*)A(2048ull * 512 * 2);
    qkvl_bias = (float*)A(24ull * 3072 * 4);
    kvx_bias  = (float*)A(24ull * 2048 * 4);
    ff_bias   = (float*)A(6ull * 3072 * 4);
    svv       = (float*)A(24ull * 2048 * 4);
    bwv       = (float*)A(24ull * 2048 * 4);
    rstats    = (float2*)A(16ull * 4165 * 8);
    qkvl_act  = (bf16*)A(1024ull * 3072 * 2);
    attnout   = (bf16*)A(1024ull * 1024 * 2);
    lat       = (float*)A(1024ull * 768 * 4);
    zlat      = (bf16*)A(1024ull * 768 * 2);
    opart     = (float*)A(4ull * (size_t)bc * 64 * 1024 * 4);
    mlpart    = (float*)A(4ull * (size_t)bc * 64 * 16 * 2 * 4);
    if (fullw) {
      wqkvlT = (bf16*)A(24ull * 3072 * 768 * 2);
      wkvxT  = (bf16*)A(24ull * 2048 * 768 * 2);
      woT    = (bf16*)A(24ull * 768 * 1024 * 2);
      w1T    = (bf16*)A(6ull * 3072 * 768 * 2);
      w2T    = (bf16*)A(6ull * 768 * 3072 * 2);
      wbuf = nullptr;
    } else {
      wbuf = (bf16*)A(4ull * LW * 2);
      wqkvlT = wkvxT = woT = w1T = w2T = nullptr;
    }
    big = A((size_t)bc * 3136 * 2048 * 2);
    ffh = qkvl_act; headtmp = (float*)qkvl_act; latbf = zlat;
    return off;
  };

  static const bool FULLS[10] = {true,true,false,true,false,true,true,false,false,false};
  static const int  BCS[10]   = {16,  8,   16,   4,   8,    2,   1,   4,    2,    1};
  bool fullw = false; int bc = 1; bool ok = false;
  for (int c = 0; c < 10; ++c) {
    if (assign(FULLS[c], BCS[c]) <= ws_size) { fullw = FULLS[c]; bc = BCS[c]; ok = true; break; }
  }
  if (!ok) return;

  float* featf32 = (float*)big;
  bf16*  kvxbuf  = (bf16*)big;

  auto gemm = [&](int tile, const bf16* A, const bf16* Bt, void* C,
                  const float* bias, const float* res, int M, int N, int K,
                  bool obf, bool gl) {
    if (tile == 128) {
      int nxt = N / 128, nwg = nxt * ((M + 127) / 128);
      if (obf && gl) k_gemm<128,128,true ,true ,false><<<nwg,256,0,stream>>>(A,Bt,C,bias,res,nullptr,nullptr,nullptr,M,N,K,nxt,nwg);
      else if (obf)  k_gemm<128,128,true ,false,false><<<nwg,256,0,stream>>>(A,Bt,C,bias,res,nullptr,nullptr,nullptr,M,N,K,nxt,nwg);
      else           k_gemm<128,128,false,false,false><<<nwg,256,0,stream>>>(A,Bt,C,bias,res,nullptr,nullptr,nullptr,M,N,K,nxt,nwg);
    } else if (tile == 64) {
      int nxt = N / 64, nwg = nxt * ((M + 63) / 64);
      if (obf && gl)  k_gemm<64,64,true ,true ,false><<<nwg,256,0,stream>>>(A,Bt,C,bias,res,nullptr,nullptr,nullptr,M,N,K,nxt,nwg);
      else if (obf)   k_gemm<64,64,true ,false,false><<<nwg,256,0,stream>>>(A,Bt,C,bias,res,nullptr,nullptr,nullptr,M,N,K,nxt,nwg);
      else            k_gemm<64,64,false,false,false><<<nwg,256,0,stream>>>(A,Bt,C,bias,res,nullptr,nullptr,nullptr,M,N,K,nxt,nwg);
    } else {
      int nxt = N / 64, nwg = nxt * ((M + 31) / 32);
      if (obf && gl)  k_gemm<32,64,true ,true ,false><<<nwg,256,0,stream>>>(A,Bt,C,bias,res,nullptr,nullptr,nullptr,M,N,K,nxt,nwg);
      else if (obf)   k_gemm<32,64,true ,false,false><<<nwg,256,0,stream>>>(A,Bt,C,bias,res,nullptr,nullptr,nullptr,M,N,K,nxt,nwg);
      else            k_gemm<32,64,false,false,false><<<nwg,256,0,stream>>>(A,Bt,C,bias,res,nullptr,nullptr,nullptr,M,N,K,nxt,nwg);
    }
  };
  auto gemmkv = [&](const bf16* A, const bf16* Bt, void* C,
                    const float* lb, const float2* rst, const float* c1, const float* cs,
                    int M, int N, int K) {
    if (M >= 2048) {
      int nxt = N / 128, nwg = nxt * ((M + 127) / 128);
      k_gemm<128,128,true,false,true><<<nwg,256,0,stream>>>(A,Bt,C,lb,nullptr,rst,c1,cs,M,N,K,nxt,nwg);
    } else {
      int nxt = N / 64, nwg = nxt * ((M + 63) / 64);
      k_gemm<64,64,true,false,true><<<nwg,256,0,stream>>>(A,Bt,C,lb,nullptr,rst,c1,cs,M,N,K,nxt,nwg);
    }
  };
  auto pick = [&](int M, int N) -> int {
    return M >= 2048 ? 128 : (N >= 1536 ? 64 : 32);
  };

  dim3 tb(32, 8);

  // ---- bias folds + kv low-rank vectors ----
  k_bfold <<<dim3(16, 24), 256, 0, stream>>>(wq,  ln2b, qkvl_bias, 768, 1024, 768LL*1024, 768, 3072);
  k_bfold2<<<dim3(32, 24), 256, 0, stream>>>(wkv, ln2b, ln1b, qkvl_bias + 1024, kvx_bias,
                                             768, 2048, 768LL*2048, 768, 3072, 2048);
  k_bfold <<<dim3(48, 6),  256, 0, stream>>>(ffw1, fflnb, ff_bias, 768, 3072, 768LL*3072, 768, 3072);
  k_kvvec <<<dim3(32, 24), 256, 0, stream>>>(wkv, ln1w, pb_in[0], pb_in[1], pb_in[2], pb_in[3],
                                             svv, bwv);

  // ---- small folded weights ----
  for (int i = 0; i < 4; ++i) {
    k_tfold<<<dim3(24, FRDS[i] / 32, 1), tb, 0, stream>>>(pw_in[i], nullptr, pT[i], FRDS[i], 768, 0, 0, 0);
    int cnt = FRDS[i] * 768;
    k_cvt<<<cnt / 1024, 256, 0, stream>>>(pw_in[i], pbf[i], cnt / 4);
  }
  k_tfold<<<dim3(24, 24, 1), tb, 0, stream>>>(projw, nullptr, projT, 768, 768, 0, 0, 0);

  // ---- full-mode weight folds ----
  if (fullw) {
    k_tfold <<<dim3(32, 24, 24), tb, 0, stream>>>(wq,  ln2w, wqkvlT, 768, 1024, 768LL*1024, 768, 3072LL*768);
    k_tfold2<<<dim3(64, 24, 24), tb, 0, stream>>>(wkv, ln2w, ln1w, wqkvlT + 1024LL*768, wkvxT,
                                                  768, 2048, 768LL*2048, 768, 3072LL*768, 2048LL*768);
    k_tfold <<<dim3(24, 32, 24), tb, 0, stream>>>(wo,  nullptr, woT, 1024, 768, 1024LL*768, 0, 768LL*1024);
    k_tfold <<<dim3(96, 24, 6),  tb, 0, stream>>>(ffw1, fflnw, w1T, 768, 3072, 768LL*3072, 768, 3072LL*768);
    k_tfold <<<dim3(24, 96, 6),  tb, 0, stream>>>(ffw2, nullptr, w2T, 3072, 768, 3072LL*768, 0, 768LL*3072);
  }

  auto foldDepthAttn = [&](int d) {
    k_tfold <<<dim3(32, 24, 4), tb, 0, stream>>>(wq  + (size_t)d*4*768*1024, ln2w + (size_t)d*4*768,
                                                 wbuf, 768, 1024, 768LL*1024, 768, (long long)LW);
    k_tfold2<<<dim3(64, 24, 4), tb, 0, stream>>>(wkv + (size_t)d*4*768*2048, ln2w + (size_t)d*4*768,
                                                 ln1w + (size_t)d*4*768,
                                                 wbuf + 1024ull*768, wbuf + 3072ull*768,
                                                 768, 2048, 768LL*2048, 768, (long long)LW, (long long)LW);
    k_tfold <<<dim3(24, 32, 4), tb, 0, stream>>>(wo  + (size_t)d*4*1024*768, nullptr,
                                                 wbuf + 3932160ull, 1024, 768, 1024LL*768, 0, (long long)LW);
  };
  auto attnW = [&](int di, const bf16*& qkvlT_p, const bf16*& kvxT_p, const bf16*& woT_p) {
    if (fullw) {
      qkvlT_p = wqkvlT + (size_t)di * 3072 * 768;
      kvxT_p  = wkvxT  + (size_t)di * 2048 * 768;
      woT_p   = woT    + (size_t)di * 768 * 1024;
    } else {
      bf16* base = wbuf + (size_t)(di & 3) * LW;
      qkvlT_p = base;
      kvxT_p  = base + 2359296ull;
      woT_p   = base + 3932160ull;
    }
  };
  auto ffW = [&](int d, const bf16*& w1p, const bf16*& w2p) {
    if (fullw) {
      w1p = w1T + (size_t)d * 3072 * 768;
      w2p = w2T + (size_t)d * 768 * 3072;
    } else {
      bf16* d1 = wbuf;
      bf16* d2 = wbuf + 3072ull * 768;
      k_tfold<<<dim3(96, 24, 1), tb, 0, stream>>>(ffw1 + (size_t)d*768*3072, fflnw + 768ull*d, d1,  768, 3072, 0, 0, 0);
      k_tfold<<<dim3(24, 96, 1), tb, 0, stream>>>(ffw2 + (size_t)d*3072*768, nullptr,          d2, 3072,  768, 0, 0, 0);
      w1p = d1; w2p = d2;
    }
  };

  // ---- feature projection -> row stats only ----
  for (int i = 0; i < 4; ++i) {
    int n1 = N1S[i], frd = FRDS[i];
    size_t cnt = (size_t)16 * n1 * frd;
    k_cvt<<<(int)(cnt / 1024), 256, 0, stream>>>(f_in[i], fbf[i], (int)(cnt / 4));
    for (int b0 = 0; b0 < 16; b0 += bc) {
      int rows = bc * n1;
      gemm(pick(rows, 768), fbf[i] + (size_t)b0 * n1 * frd, pT[i], featf32,
           pb_in[i], nullptr, rows, 768, frd, false, false);
      k_stats<<<rows, 256, 0, stream>>>(featf32, rstats + ROFF[i] + (size_t)b0 * n1);
    }
  }

  hipMemcpyAsync(lat, id_emb, 1024ull * 768 * 4, hipMemcpyDeviceToDevice, stream);

  // ---- depth loop ----
  for (int d = 0; d < 6; ++d) {
    if (!fullw) foldDepthAttn(d);
    for (int i = 0; i < 4; ++i) {
      int di = d * 4 + i, n1 = N1S[i], nseg = NSEG[i], frd = FRDS[i];
      const bf16 *qkvlT_p, *kvxT_p, *woT_p;
      attnW(di, qkvlT_p, kvxT_p, woT_p);
      gemm(64, kvxT_p, pbf[i], PTbuf, nullptr, nullptr, 2048, frd, 768, true, false);
      k_std<<<1024, 256, 0, stream>>>(lat, zlat);
      gemm(64, zlat, qkvlT_p, qkvl_act, qkvl_bias + 3072ull * di, nullptr,
           1024, 3072, 768, true, false);
      for (int b0 = 0; b0 < 16; b0 += bc) {
        int rows = bc * n1;
        gemmkv(fbf[i] + (size_t)b0 * n1 * frd, PTbuf, kvxbuf,
               kvx_bias + 2048ull * di, rstats + ROFF[i] + (size_t)b0 * n1,
               bwv + 2048ull * di, svv + 2048ull * di, rows, 2048, frd);
        k_attn<<<bc * 16 * nseg, 256, 0, stream>>>(qkvl_act, kvxbuf, attnout,
                                                   opart, mlpart, n1, b0, nseg, bc);
        if (nseg > 1)
          k_amerge<<<bc * 16, 256, 0, stream>>>(opart, mlpart, attnout, b0, nseg, bc);
      }
      gemm(32, attnout, woT_p, lat, nullptr, lat, 1024, 768, 1024, false, false);
    }
    const bf16 *w1p, *w2p;
    ffW(d, w1p, w2p);
    k_std<<<1024, 256, 0, stream>>>(lat, zlat);
    gemm(64, zlat, w1p, ffh, ff_bias + 3072ull * d, nullptr, 1024, 3072, 768, true, true);
    gemm(32, ffh, w2p, lat, nullptr, lat, 1024, 768, 3072, false, false);
  }

  // ---- head ----
  k_cvt<<<768, 256, 0, stream>>>(lat, latbf, 196608);
  gemm(32, latbf, projT, headtmp, projb, nullptr, 1024, 768, 768, false, false);
  k_lnout<<<1024, 256, 0, stream>>>(headtmp, normw, normb, (float*)d_out);
}

// Round 10
// 3439.509 us; speedup vs baseline: 1.9670x; 1.0261x over previous
//
#include <hip/hip_runtime.h>
#include <hip/hip_bf16.h>
#include <cstdint>
#include <cstddef>

typedef __hip_bfloat16 bf16;
typedef float  f32x4   __attribute__((ext_vector_type(4)));
typedef float  float4v __attribute__((ext_vector_type(4)));
typedef short  short8  __attribute__((ext_vector_type(8)));
typedef short  short4v __attribute__((ext_vector_type(4)));
typedef __bf16 bf16x8  __attribute__((ext_vector_type(8)));

__device__ __forceinline__ void mfma16(f32x4& d, short8 a, short8 b) {
  d = __builtin_amdgcn_mfma_f32_16x16x32_bf16(
      __builtin_bit_cast(bf16x8, a), __builtin_bit_cast(bf16x8, b), d, 0, 0, 0);
}
__device__ __forceinline__ unsigned short f2b_bits(float x) {
  __hip_bfloat16 h = __float2bfloat16(x);
  return __builtin_bit_cast(unsigned short, h);
}
__device__ __forceinline__ float gelu_exact(float x) {
  return 0.5f * x * (1.0f + erff(x * 0.7071067811865475f));
}

// ---------- f32 -> bf16 convert, 4 elems/thread ----------
__global__ __launch_bounds__(256) void k_cvt(const float* __restrict__ src,
                                             bf16* __restrict__ dst, int n4) {
  int i = blockIdx.x * 256 + threadIdx.x;
  if (i >= n4) return;
  float4v v = *(const float4v*)(src + (size_t)i * 4);
  short4v s;
  s[0] = (short)f2b_bits(v[0]); s[1] = (short)f2b_bits(v[1]);
  s[2] = (short)f2b_bits(v[2]); s[3] = (short)f2b_bits(v[3]);
  *(short4v*)((short*)dst + (size_t)i * 4) = s;
}

// ---------- transpose-fold x: f32 (K,N) -> bf16 (N,K) [optional per-k scale, dual out] ----------
// 64x64 tile; float4 global reads; pad-65 LDS; short8 coalesced bf16 stores.
template <bool DUAL>
__global__ __launch_bounds__(256) void k_tfoldx(const float* __restrict__ src,
                                                const float* __restrict__ s1,
                                                const float* __restrict__ s2,
                                                bf16* __restrict__ d1,
                                                bf16* __restrict__ d2,
                                                int K, int N,
                                                long long src_bs, long long s_bs,
                                                long long d1_bs, long long d2_bs) {
  src += (size_t)blockIdx.z * src_bs;
  d1  += (size_t)blockIdx.z * d1_bs;
  if (DUAL) d2 += (size_t)blockIdx.z * d2_bs;
  __shared__ float tile[64][65];
  __shared__ float sc1[64], sc2[64];
  const int n0 = blockIdx.x * 64, k0 = blockIdx.y * 64;
  const int t = threadIdx.x;
  if (t < 64) {
    sc1[t] = s1 ? (s1 + (size_t)blockIdx.z * s_bs)[k0 + t] : 1.0f;
  } else if (DUAL && t < 128) {
    sc2[t - 64] = (s2 + (size_t)blockIdx.z * s_bs)[k0 + t - 64];
  }
#pragma unroll
  for (int j = 0; j < 4; ++j) {
    int f = t + j * 256;
    int row = f >> 4, col = (f & 15) * 4;
    float4v v = *(const float4v*)(src + (size_t)(k0 + row) * N + n0 + col);
    tile[row][col]     = v[0];
    tile[row][col + 1] = v[1];
    tile[row][col + 2] = v[2];
    tile[row][col + 3] = v[3];
  }
  __syncthreads();
#pragma unroll
  for (int j = 0; j < 2; ++j) {
    int s = t + j * 256;
    int n = s >> 3, kc = (s & 7) * 8;
    short8 o1v, o2v;
#pragma unroll
    for (int i = 0; i < 8; ++i) {
      float v = tile[kc + i][n];
      o1v[i] = (short)f2b_bits(v * sc1[kc + i]);
      if (DUAL) o2v[i] = (short)f2b_bits(v * sc2[kc + i]);
    }
    *(short8*)(d1 + (size_t)(n0 + n) * K + k0 + kc) = o1v;
    if (DUAL) *(short8*)(d2 + (size_t)(n0 + n) * K + k0 + kc) = o2v;
  }
}

// ---------- vectorized bias fold: out[n] = sum_k lnb[k]*W[k][n], float4 loads ----------
__global__ __launch_bounds__(256) void k_bfoldv(const float* __restrict__ W,
                                                const float* __restrict__ lnb,
                                                float* __restrict__ out, int K, int N,
                                                long long w_bs, long long b_bs, long long o_bs) {
  W   += (size_t)blockIdx.y * w_bs;
  lnb += (size_t)blockIdx.y * b_bs;
  out += (size_t)blockIdx.y * o_bs;
  __shared__ float sb[768];
  for (int k = threadIdx.x; k < K; k += 256) sb[k] = lnb[k];
  __syncthreads();
  const int lane = threadIdx.x & 63, kg = threadIdx.x >> 6;
  const int n = blockIdx.x * 256 + lane * 4;
  float4v a = {0.f, 0.f, 0.f, 0.f};
  for (int k = kg; k < K; k += 4) {
    float4v wv = *(const float4v*)(W + (size_t)k * N + n);
    float c = sb[k];
    a[0] = fmaf(c, wv[0], a[0]); a[1] = fmaf(c, wv[1], a[1]);
    a[2] = fmaf(c, wv[2], a[2]); a[3] = fmaf(c, wv[3], a[3]);
  }
  __shared__ float4v red[4][64];
  red[kg][lane] = a;
  __syncthreads();
  if (kg == 0) {
    float4v r = red[0][lane] + red[1][lane] + red[2][lane] + red[3][lane];
    *(float4v*)(out + n) = r;
  }
}

// ---------- merged kv fold: reads wkv ONCE, produces 4 fold vectors ----------
// o1 = sum ln2b*W (qkvl_bias+1024), o2 = sum ln1b*W (kvx_bias),
// o3 = sum ln1w*W (svv), o4 = sum (pb*ln1w)*W (bwv)
__global__ __launch_bounds__(256) void k_kvfold(const float* __restrict__ wkv,
                                                const float* __restrict__ ln2b,
                                                const float* __restrict__ ln1b,
                                                const float* __restrict__ ln1w,
                                                const float* __restrict__ b0,
                                                const float* __restrict__ b1,
                                                const float* __restrict__ b2,
                                                const float* __restrict__ b3,
                                                float* __restrict__ qb,
                                                float* __restrict__ kb,
                                                float* __restrict__ sv,
                                                float* __restrict__ bw) {
  const int di = blockIdx.y;
  const int i = di & 3;
  const float* pb = (i == 0) ? b0 : (i == 1) ? b1 : (i == 2) ? b2 : b3;
  const float* W = wkv + (size_t)di * 768 * 2048;
  __shared__ float c2b[768], c1b[768], c1w[768], cpw[768];
  for (int k = threadIdx.x; k < 768; k += 256) {
    float w1 = ln1w[(size_t)di * 768 + k];
    c2b[k] = ln2b[(size_t)di * 768 + k];
    c1b[k] = ln1b[(size_t)di * 768 + k];
    c1w[k] = w1;
    cpw[k] = pb[k] * w1;
  }
  __syncthreads();
  const int lane = threadIdx.x & 63, kg = threadIdx.x >> 6;
  const int n = blockIdx.x * 256 + lane * 4;
  float4v a1 = {0.f,0.f,0.f,0.f}, a2 = a1, a3 = a1, a4 = a1;
  for (int k = kg; k < 768; k += 4) {
    float4v wv = *(const float4v*)(W + (size_t)k * 2048 + n);
    float s1 = c2b[k], s2 = c1b[k], s3 = c1w[k], s4 = cpw[k];
#pragma unroll
    for (int q = 0; q < 4; ++q) {
      a1[q] = fmaf(s1, wv[q], a1[q]);
      a2[q] = fmaf(s2, wv[q], a2[q]);
      a3[q] = fmaf(s3, wv[q], a3[q]);
      a4[q] = fmaf(s4, wv[q], a4[q]);
    }
  }
  __shared__ float4v red[4][64];
  red[kg][lane] = a1; __syncthreads();
  if (kg == 0) {
    float4v r = red[0][lane] + red[1][lane] + red[2][lane] + red[3][lane];
    *(float4v*)(qb + (size_t)di * 3072 + 1024 + n) = r;
  }
  __syncthreads();
  red[kg][lane] = a2; __syncthreads();
  if (kg == 0) {
    float4v r = red[0][lane] + red[1][lane] + red[2][lane] + red[3][lane];
    *(float4v*)(kb + (size_t)di * 2048 + n) = r;
  }
  __syncthreads();
  red[kg][lane] = a3; __syncthreads();
  if (kg == 0) {
    float4v r = red[0][lane] + red[1][lane] + red[2][lane] + red[3][lane];
    *(float4v*)(sv + (size_t)di * 2048 + n) = r;
  }
  __syncthreads();
  red[kg][lane] = a4; __syncthreads();
  if (kg == 0) {
    float4v r = red[0][lane] + red[1][lane] + red[2][lane] + red[3][lane];
    *(float4v*)(bw + (size_t)di * 2048 + n) = r;
  }
}

// ---------- row standardize (768-wide), f32 -> bf16 ----------
__global__ __launch_bounds__(256) void k_std(const float* __restrict__ src,
                                             bf16* __restrict__ dst) {
  int row = blockIdx.x;
  const float* x = src + (size_t)row * 768;
  int t = threadIdx.x;
  float a0 = x[t], a1 = x[t + 256], a2 = x[t + 512];
  float s = a0 + a1 + a2;
  float q = a0 * a0 + a1 * a1 + a2 * a2;
#pragma unroll
  for (int off = 1; off < 64; off <<= 1) { s += __shfl_xor(s, off); q += __shfl_xor(q, off); }
  __shared__ float ss[4], qs[4];
  if ((t & 63) == 0) { ss[t >> 6] = s; qs[t >> 6] = q; }
  __syncthreads();
  s = ss[0] + ss[1] + ss[2] + ss[3];
  q = qs[0] + qs[1] + qs[2] + qs[3];
  float mean = s * (1.0f / 768.0f);
  float var  = q * (1.0f / 768.0f) - mean * mean;
  float inv  = rsqrtf(var + 1e-5f);
  bf16* d = dst + (size_t)row * 768;
  d[t]       = __float2bfloat16((a0 - mean) * inv);
  d[t + 256] = __float2bfloat16((a1 - mean) * inv);
  d[t + 512] = __float2bfloat16((a2 - mean) * inv);
}

// ---------- row stats only (768-wide): out[row] = {inv, mean*inv} ----------
__global__ __launch_bounds__(256) void k_stats(const float* __restrict__ src,
                                               float2* __restrict__ out) {
  int row = blockIdx.x;
  const float* x = src + (size_t)row * 768;
  int t = threadIdx.x;
  float a0 = x[t], a1 = x[t + 256], a2 = x[t + 512];
  float s = a0 + a1 + a2;
  float q = a0 * a0 + a1 * a1 + a2 * a2;
#pragma unroll
  for (int off = 1; off < 64; off <<= 1) { s += __shfl_xor(s, off); q += __shfl_xor(q, off); }
  __shared__ float ss[4], qs[4];
  if ((t & 63) == 0) { ss[t >> 6] = s; qs[t >> 6] = q; }
  __syncthreads();
  if (t == 0) {
    float sm = ss[0] + ss[1] + ss[2] + ss[3];
    float qm = qs[0] + qs[1] + qs[2] + qs[3];
    float mean = sm * (1.0f / 768.0f);
    float var  = qm * (1.0f / 768.0f) - mean * mean;
    float inv  = rsqrtf(var + 1e-5f);
    out[row] = make_float2(inv, mean * inv);
  }
}

// ---------- final layernorm (768-wide) with w,b: f32 -> f32 ----------
__global__ __launch_bounds__(256) void k_lnout(const float* __restrict__ src,
                                               const float* __restrict__ w,
                                               const float* __restrict__ b,
                                               float* __restrict__ dst) {
  int row = blockIdx.x;
  const float* x = src + (size_t)row * 768;
  int t = threadIdx.x;
  float a0 = x[t], a1 = x[t + 256], a2 = x[t + 512];
  float s = a0 + a1 + a2;
  float q = a0 * a0 + a1 * a1 + a2 * a2;
#pragma unroll
  for (int off = 1; off < 64; off <<= 1) { s += __shfl_xor(s, off); q += __shfl_xor(q, off); }
  __shared__ float ss[4], qs[4];
  if ((t & 63) == 0) { ss[t >> 6] = s; qs[t >> 6] = q; }
  __syncthreads();
  s = ss[0] + ss[1] + ss[2] + ss[3];
  q = qs[0] + qs[1] + qs[2] + qs[3];
  float mean = s * (1.0f / 768.0f);
  float var  = q * (1.0f / 768.0f) - mean * mean;
  float inv  = rsqrtf(var + 1e-5f);
  float* d = dst + (size_t)row * 768;
  d[t]       = (a0 - mean) * inv * w[t]       + b[t];
  d[t + 256] = (a1 - mean) * inv * w[t + 256] + b[t + 256];
  d[t + 512] = (a2 - mean) * inv * w[t + 512] + b[t + 512];
}

// ---------- MFMA GEMM (reg-staged pipeline + XCD swizzle) ----------
// bf16 output path: staged LDS epilogue -> short8 (16B) coalesced stores.
// KVE epilogue: out = (acc + c1[n])*inv_r - muinv_r*cs[n] + bias[n]
template <int BM, int BN, bool OBF16, bool GELU, bool KVE>
__global__ __launch_bounds__(256) void k_gemm(const bf16* __restrict__ A,
                                              const bf16* __restrict__ Bt,
                                              void* __restrict__ Cv,
                                              const float* __restrict__ bias,
                                              const float* __restrict__ res,
                                              const float2* __restrict__ rstats,
                                              const float* __restrict__ c1,
                                              const float* __restrict__ cs,
                                              int M, int N, int K, int nxt, int nwg) {
  constexpr int AI = BM / 32, BI = BN / 32;
  constexpr int MF = BM / 32, NF = BN / 32;
  __shared__ __align__(16) char smem[(BM + BN) * 128];
  char* As = smem;
  char* Bs = smem + BM * 128;

  const int lin = blockIdx.x;
  const int qq = nwg >> 3, r8 = nwg & 7;
  const int xcd = lin & 7, idx = lin >> 3;
  const int swz = (xcd < r8) ? (xcd * (qq + 1) + idx)
                             : (r8 * (qq + 1) + (xcd - r8) * qq + idx);
  const int bm = (swz / nxt) * BM, bn = (swz % nxt) * BN;

  const int t = threadIdx.x, lane = t & 63, w = t >> 6;
  const int wr = w >> 1, wc = w & 1;
  const int l15 = lane & 15, lg = lane >> 4;
  const int srow = t >> 3, scol = t & 7;

  const bf16* aptr[AI]; int aoff[AI];
#pragma unroll
  for (int i = 0; i < AI; ++i) {
    int r = i * 32 + srow;
    int gr = bm + r; if (gr > M - 1) gr = M - 1;
    aptr[i] = A + (size_t)gr * K + scol * 8;
    aoff[i] = r * 128 + ((scol * 16) ^ ((r & 7) << 4));
  }
  const bf16* bptr[BI]; int boff[BI];
#pragma unroll
  for (int i = 0; i < BI; ++i) {
    int r = i * 32 + srow;
    int gc = bn + r; if (gc > N - 1) gc = N - 1;
    bptr[i] = Bt + (size_t)gc * K + scol * 8;
    boff[i] = r * 128 + ((scol * 16) ^ ((r & 7) << 4));
  }

  f32x4 acc[MF][NF] = {};
  short8 av[AI], bv[BI];
#pragma unroll
  for (int i = 0; i < AI; ++i) av[i] = *(const short8*)(aptr[i]);
#pragma unroll
  for (int i = 0; i < BI; ++i) bv[i] = *(const short8*)(bptr[i]);

  const int nk = K / 64;
  for (int kt = 0; kt < nk; ++kt) {
    __syncthreads();
#pragma unroll
    for (int i = 0; i < AI; ++i) *(short8*)(As + aoff[i]) = av[i];
#pragma unroll
    for (int i = 0; i < BI; ++i) *(short8*)(Bs + boff[i]) = bv[i];
    __syncthreads();
    if (kt + 1 < nk) {
#pragma unroll
      for (int i = 0; i < AI; ++i) av[i] = *(const short8*)(aptr[i] + (size_t)(kt + 1) * 64);
#pragma unroll
      for (int i = 0; i < BI; ++i) bv[i] = *(const short8*)(bptr[i] + (size_t)(kt + 1) * 64);
    }
#pragma unroll
    for (int ks = 0; ks < 2; ++ks) {
      short8 af[MF], bfr[NF];
#pragma unroll
      for (int m = 0; m < MF; ++m) {
        int r = wr * (BM / 2) + m * 16 + l15;
        af[m] = *(const short8*)(As + r * 128 + ((ks * 64 + lg * 16) ^ ((r & 7) << 4)));
      }
#pragma unroll
      for (int n = 0; n < NF; ++n) {
        int r = wc * (BN / 2) + n * 16 + l15;
        bfr[n] = *(const short8*)(Bs + r * 128 + ((ks * 64 + lg * 16) ^ ((r & 7) << 4)));
      }
#pragma unroll
      for (int m = 0; m < MF; ++m)
#pragma unroll
        for (int n = 0; n < NF; ++n) mfma16(acc[m][n], af[m], bfr[n]);
    }
  }

  if (OBF16) {
    __syncthreads();
    bf16* cst = (bf16*)smem;
#pragma unroll
    for (int m = 0; m < MF; ++m) {
      int lr0 = wr * (BM / 2) + m * 16 + lg * 4;
#pragma unroll
      for (int n = 0; n < NF; ++n) {
        int lc = wc * (BN / 2) + n * 16 + l15;
        int gc = bn + lc;
        float bvs = bias ? bias[gc] : 0.0f;
        float c1v = 0.0f, csv = 0.0f;
        if (KVE) { c1v = c1[gc]; csv = cs[gc]; }
#pragma unroll
        for (int r = 0; r < 4; ++r) {
          int row = lr0 + r;
          float v;
          if (KVE) {
            int gri = bm + row; if (gri > M - 1) gri = M - 1;
            float2 st = rstats[gri];
            v = (acc[m][n][r] + c1v) * st.x - st.y * csv + bvs;
          } else {
            v = acc[m][n][r] + bvs;
            if (GELU) v = gelu_exact(v);
          }
          cst[row * BN + lc] = __float2bfloat16(v);
        }
      }
    }
    __syncthreads();
    constexpr int CB = BN / 8;
    constexpr int SEGS = BM * CB;
    for (int seg = t; seg < SEGS; seg += 256) {
      int row = seg / CB, cb = seg % CB;
      int gr = bm + row;
      if (gr < M)
        *(short8*)((bf16*)Cv + (size_t)gr * N + bn + cb * 8) =
            *(const short8*)(cst + (size_t)row * BN + cb * 8);
    }
  } else {
#pragma unroll
    for (int m = 0; m < MF; ++m) {
      int gr0 = bm + wr * (BM / 2) + m * 16 + lg * 4;
#pragma unroll
      for (int n = 0; n < NF; ++n) {
        int gc = bn + wc * (BN / 2) + n * 16 + l15;
        float bvs = bias ? bias[gc] : 0.0f;
#pragma unroll
        for (int r = 0; r < 4; ++r) {
          int gr = gr0 + r;
          if (gr < M) {
            float v = acc[m][n][r] + bvs;
            if (GELU) v = gelu_exact(v);
            if (res) v += res[(size_t)gr * N + gc];
            ((float*)Cv)[(size_t)gr * N + gc] = v;
          }
        }
      }
    }
  }
}

// ---------- fused attention, split-KV + swapped-QK^T softmax ----------
__global__ __launch_bounds__(256) void k_attn(const bf16* __restrict__ qkvl,
                                              const bf16* __restrict__ kvx,
                                              bf16* __restrict__ outp,
                                              float* __restrict__ opart,
                                              float* __restrict__ mlpart,
                                              int n1, int b0, int nseg, int nbloc) {
  const int s   = blockIdx.x % nseg;
  const int bh  = blockIdx.x / nseg;
  const int bl = bh >> 4, h = bh & 15;
  const int b = b0 + bl;
  const int nb64 = nbloc * 64;
  __shared__ __align__(16) char Qs[64 * 128];
  __shared__ __align__(16) char Ks[64 * 128];
  __shared__ __align__(16) char Vt[64 * 128];
  __shared__ __align__(16) char Ps[4][16 * 128];
  const int t = threadIdx.x, lane = t & 63, w = t >> 6;
  const int l15 = lane & 15, lg = lane >> 4;

#pragma unroll
  for (int it = 0; it < 2; ++it) {
    int slot = it * 256 + t; int r = slot >> 3, c = slot & 7;
    short8 v = *(const short8*)(qkvl + (size_t)(b * 64 + r) * 3072 + h * 64 + c * 8);
    *(short8*)(Qs + r * 128 + ((c * 16) ^ ((r & 7) << 4))) = v;
  }
  const int n_kv = n1 + 64;
  const int nch = (n_kv + 63) >> 6;
  const int cpseg = (nch + nseg - 1) / nseg;
  const int ch0 = s * cpseg;
  const int ch1 = min(nch, ch0 + cpseg);

  float m_run = -1e30f, l_run = 0.0f;
  f32x4 o[4] = {};

  short8 kreg[2], vreg[2];
  auto loadKV = [&](int ch) {
#pragma unroll
    for (int it = 0; it < 2; ++it) {
      int slot = it * 256 + t; int rr = slot >> 3, c = slot & 7;
      int j = ch * 64 + rr;
      short8 kv = {}; short8 vv = {};
      if (j < n_kv) {
        const bf16* kb;
        if (j < n1) kb = kvx + (size_t)(bl * n1 + j) * 2048 + h * 64;
        else        kb = qkvl + (size_t)(b * 64 + (j - n1)) * 3072 + 1024 + h * 64;
        kv = *(const short8*)(kb + c * 8);
        vv = *(const short8*)(kb + 1024 + c * 8);
      }
      kreg[it] = kv; vreg[it] = vv;
    }
  };
  loadKV(ch0);

  for (int ch = ch0; ch < ch1; ++ch) {
    __syncthreads();
#pragma unroll
    for (int it = 0; it < 2; ++it) {
      int slot = it * 256 + t; int rr = slot >> 3, c = slot & 7;
      *(short8*)(Ks + rr * 128 + ((c * 16) ^ ((rr & 7) << 4))) = kreg[it];
#pragma unroll
      for (int j2 = 0; j2 < 8; ++j2) {
        int dh = c * 8 + j2;
        *(short*)(Vt + dh * 128 + ((rr * 2) ^ ((dh & 7) << 4))) = vreg[it][j2];
      }
    }
    __syncthreads();
    if (ch + 1 < ch1) loadKV(ch + 1);

    f32x4 sc[4] = {};
#pragma unroll
    for (int ks = 0; ks < 2; ++ks) {
      int qr = w * 16 + l15;
      short8 qf = *(const short8*)(Qs + qr * 128 + ((ks * 64 + lg * 16) ^ ((qr & 7) << 4)));
#pragma unroll
      for (int n = 0; n < 4; ++n) {
        int kr = n * 16 + l15;
        short8 kf = *(const short8*)(Ks + kr * 128 + ((ks * 64 + lg * 16) ^ ((kr & 7) << 4)));
        mfma16(sc[n], kf, qf);
      }
    }
    float mx = m_run;
#pragma unroll
    for (int n = 0; n < 4; ++n)
#pragma unroll
      for (int r = 0; r < 4; ++r) {
        float v = sc[n][r] * 0.125f;
        int kvi = ch * 64 + n * 16 + lg * 4 + r;
        if (kvi >= n_kv) v = -1e30f;
        sc[n][r] = v;
        mx = fmaxf(mx, v);
      }
    mx = fmaxf(mx, __shfl_xor(mx, 16));
    mx = fmaxf(mx, __shfl_xor(mx, 32));
    float scl = __expf(m_run - mx);
    m_run = mx;
    float p[4][4];
    float rs = 0.0f;
#pragma unroll
    for (int n = 0; n < 4; ++n)
#pragma unroll
      for (int r = 0; r < 4; ++r) { float pv = __expf(sc[n][r] - mx); p[n][r] = pv; rs += pv; }
    rs += __shfl_xor(rs, 16);
    rs += __shfl_xor(rs, 32);
    l_run = l_run * scl + rs;
    float sclq[4];
#pragma unroll
    for (int r = 0; r < 4; ++r) sclq[r] = __shfl(scl, lg * 4 + r);
#pragma unroll
    for (int nn = 0; nn < 4; ++nn)
#pragma unroll
      for (int r = 0; r < 4; ++r) o[nn][r] *= sclq[r];
#pragma unroll
    for (int n = 0; n < 4; ++n)
#pragma unroll
      for (int r = 0; r < 4; ++r) {
        int kv = n * 16 + lg * 4 + r;
        *(unsigned short*)(Ps[w] + l15 * 128 + ((kv * 2) ^ ((l15 & 7) << 4))) = f2b_bits(p[n][r]);
      }
#pragma unroll
    for (int ks = 0; ks < 2; ++ks) {
      short8 pf = *(const short8*)(Ps[w] + l15 * 128 + ((ks * 64 + lg * 16) ^ ((l15 & 7) << 4)));
#pragma unroll
      for (int nn = 0; nn < 4; ++nn) {
        int dh = nn * 16 + l15;
        short8 vf = *(const short8*)(Vt + dh * 128 + ((ks * 64 + lg * 16) ^ ((dh & 7) << 4)));
        mfma16(o[nn], pf, vf);
      }
    }
  }

  if (nseg == 1) {
    float lq[4];
#pragma unroll
    for (int r = 0; r < 4; ++r) lq[r] = __shfl(l_run, lg * 4 + r);
#pragma unroll
    for (int nn = 0; nn < 4; ++nn)
#pragma unroll
      for (int r = 0; r < 4; ++r) {
        int qr = w * 16 + lg * 4 + r;
        int dh = nn * 16 + l15;
        outp[(size_t)(b * 64 + qr) * 1024 + h * 64 + dh] = __float2bfloat16(o[nn][r] / lq[r]);
      }
  } else {
#pragma unroll
    for (int nn = 0; nn < 4; ++nn)
#pragma unroll
      for (int r = 0; r < 4; ++r) {
        int qr = w * 16 + lg * 4 + r;
        int dh = nn * 16 + l15;
        opart[((size_t)s * nb64 + bl * 64 + qr) * 1024 + h * 64 + dh] = o[nn][r];
      }
    if (lg == 0) {
      int qr = w * 16 + l15;
      size_t mi = (((size_t)s * nb64 + bl * 64 + qr) * 16 + h) * 2;
      mlpart[mi]     = m_run;
      mlpart[mi + 1] = l_run;
    }
  }
}

// ---------- merge split-KV partials ----------
__global__ __launch_bounds__(256) void k_amerge(const float* __restrict__ opart,
                                                const float* __restrict__ mlpart,
                                                bf16* __restrict__ outp,
                                                int b0, int nseg, int nbloc) {
  const int bh = blockIdx.x;
  const int bl = bh >> 4, h = bh & 15;
  const int nb64 = nbloc * 64;
  const int t = threadIdx.x;
  const int q = t >> 2, quarter = t & 3;

  float ms[8], ls[8];
  float mstar = -1e30f;
  for (int s = 0; s < nseg; ++s) {
    size_t mi = (((size_t)s * nb64 + bl * 64 + q) * 16 + h) * 2;
    ms[s] = mlpart[mi]; ls[s] = mlpart[mi + 1];
    mstar = fmaxf(mstar, ms[s]);
  }
  float L = 0.0f, ws[8];
  for (int s = 0; s < nseg; ++s) { ws[s] = __expf(ms[s] - mstar); L += ws[s] * ls[s]; }
  float inv = 1.0f / L;

  bf16* outrow = outp + (size_t)((b0 + bl) * 64 + q) * 1024 + h * 64;
#pragma unroll
  for (int jj = 0; jj < 4; ++jj) {
    int dh0 = quarter * 16 + jj * 4;
    float4v acc = {0.f, 0.f, 0.f, 0.f};
    for (int s = 0; s < nseg; ++s) {
      const float* orow = opart + ((size_t)s * nb64 + bl * 64 + q) * 1024 + h * 64 + dh0;
      float4v v = *(const float4v*)orow;
      acc[0] += ws[s] * v[0]; acc[1] += ws[s] * v[1];
      acc[2] += ws[s] * v[2]; acc[3] += ws[s] * v[3];
    }
    short4v sv;
    sv[0] = (short)f2b_bits(acc[0] * inv); sv[1] = (short)f2b_bits(acc[1] * inv);
    sv[2] = (short)f2b_bits(acc[2] * inv); sv[3] = (short)f2b_bits(acc[3] * inv);
    *(short4v*)((short*)(outrow + dh0)) = sv;
  }
}

// =========================== host ===========================
extern "C" void kernel_launch(void* const* d_in, const int* in_sizes, int n_in,
                              void* d_out, int out_size, void* d_ws, size_t ws_size,
                              hipStream_t stream) {
  (void)in_sizes; (void)n_in; (void)out_size;
  const float* id_emb = (const float*)d_in[0];
  const float* f_in[4]  = {(const float*)d_in[4],  (const float*)d_in[3],
                           (const float*)d_in[2],  (const float*)d_in[1]};
  const float* pw_in[4] = {(const float*)d_in[11], (const float*)d_in[9],
                           (const float*)d_in[7],  (const float*)d_in[5]};
  const float* pb_in[4] = {(const float*)d_in[12], (const float*)d_in[10],
                           (const float*)d_in[8],  (const float*)d_in[6]};
  const float* ln1w = (const float*)d_in[13];
  const float* ln1b = (const float*)d_in[14];
  const float* ln2w = (const float*)d_in[15];
  const float* ln2b = (const float*)d_in[16];
  const float* wq   = (const float*)d_in[17];
  const float* wkv  = (const float*)d_in[18];
  const float* wo   = (const float*)d_in[19];
  const float* fflnw = (const float*)d_in[20];
  const float* fflnb = (const float*)d_in[21];
  const float* ffw1  = (const float*)d_in[22];
  const float* ffw2  = (const float*)d_in[23];
  const float* projw = (const float*)d_in[24];
  const float* projb = (const float*)d_in[25];
  const float* normw = (const float*)d_in[26];
  const float* normb = (const float*)d_in[27];

  static const int N1S[4]  = {49, 196, 784, 3136};
  static const int FRDS[4] = {512, 256, 128, 64};
  static const int NSEG[4] = {1, 1, 2, 4};
  const size_t LW = 4718592;
  static const size_t ROFF[4] = {0, 16*49ull, 16*(49+196ull), 16*(49+196+784ull)};

  bf16 *fbf[4], *pT[4], *pbf[4], *projT, *PTbuf;
  float *qkvl_bias, *kvx_bias, *ff_bias, *lat, *headtmp, *svv, *bwv;
  float2 *rstats;
  float *opart, *mlpart;
  bf16 *qkvl_act, *attnout, *zlat, *latbf, *ffh;
  bf16 *wqkvlT = nullptr, *wkvxT = nullptr, *woT = nullptr, *w1T = nullptr, *w2T = nullptr;
  bf16 *wbuf = nullptr;
  char *big;

  auto assign = [&](bool fullw, int bc) -> size_t {
    size_t off = 0; char* base = (char*)d_ws;
    auto A = [&](size_t b) -> char* {
      char* p = base + off; off = (off + b + 255) & ~(size_t)255; return p;
    };
    for (int i = 0; i < 4; ++i) fbf[i] = (bf16*)A((size_t)16 * N1S[i] * FRDS[i] * 2);
    for (int i = 0; i < 4; ++i) pT[i]  = (bf16*)A((size_t)768 * FRDS[i] * 2);
    for (int i = 0; i < 4; ++i) pbf[i] = (bf16*)A((size_t)FRDS[i] * 768 * 2);
    projT     = (bf16*)A(768ull * 768 * 2);
    PTbuf     = (bf16*)A(2048ull * 512 * 2);
    qkvl_bias = (float*)A(24ull * 3072 * 4);
    kvx_bias  = (float*)A(24ull * 2048 * 4);
    ff_bias   = (float*)A(6ull * 3072 * 4);
    svv       = (float*)A(24ull * 2048 * 4);
    bwv       = (float*)A(24ull * 2048 * 4);
    rstats    = (float2*)A(16ull * 4165 * 8);
    qkvl_act  = (bf16*)A(1024ull * 3072 * 2);
    attnout   = (bf16*)A(1024ull * 1024 * 2);
    lat       = (float*)A(1024ull * 768 * 4);
    zlat      = (bf16*)A(1024ull * 768 * 2);
    opart     = (float*)A(4ull * (size_t)bc * 64 * 1024 * 4);
    mlpart    = (float*)A(4ull * (size_t)bc * 64 * 16 * 2 * 4);
    if (fullw) {
      wqkvlT = (bf16*)A(24ull * 3072 * 768 * 2);
      wkvxT  = (bf16*)A(24ull * 2048 * 768 * 2);
      woT    = (bf16*)A(24ull * 768 * 1024 * 2);
      w1T    = (bf16*)A(6ull * 3072 * 768 * 2);
      w2T    = (bf16*)A(6ull * 768 * 3072 * 2);
      wbuf = nullptr;
    } else {
      wbuf = (bf16*)A(4ull * LW * 2);
      wqkvlT = wkvxT = woT = w1T = w2T = nullptr;
    }
    big = A((size_t)bc * 3136 * 2048 * 2);
    ffh = qkvl_act; headtmp = (float*)qkvl_act; latbf = zlat;
    return off;
  };

  static const bool FULLS[10] = {true,true,false,true,false,true,true,false,false,false};
  static const int  BCS[10]   = {16,  8,   16,   4,   8,    2,   1,   4,    2,    1};
  bool fullw = false; int bc = 1; bool ok = false;
  for (int c = 0; c < 10; ++c) {
    if (assign(FULLS[c], BCS[c]) <= ws_size) { fullw = FULLS[c]; bc = BCS[c]; ok = true; break; }
  }
  if (!ok) return;

  float* featf32 = (float*)big;
  bf16*  kvxbuf  = (bf16*)big;

  auto gemm = [&](int tile, const bf16* A, const bf16* Bt, void* C,
                  const float* bias, const float* res, int M, int N, int K,
                  bool obf, bool gl) {
    if (tile == 128) {
      int nxt = N / 128, nwg = nxt * ((M + 127) / 128);
      if (obf && gl) k_gemm<128,128,true ,true ,false><<<nwg,256,0,stream>>>(A,Bt,C,bias,res,nullptr,nullptr,nullptr,M,N,K,nxt,nwg);
      else if (obf)  k_gemm<128,128,true ,false,false><<<nwg,256,0,stream>>>(A,Bt,C,bias,res,nullptr,nullptr,nullptr,M,N,K,nxt,nwg);
      else           k_gemm<128,128,false,false,false><<<nwg,256,0,stream>>>(A,Bt,C,bias,res,nullptr,nullptr,nullptr,M,N,K,nxt,nwg);
    } else if (tile == 64) {
      int nxt = N / 64, nwg = nxt * ((M + 63) / 64);
      if (obf && gl)  k_gemm<64,64,true ,true ,false><<<nwg,256,0,stream>>>(A,Bt,C,bias,res,nullptr,nullptr,nullptr,M,N,K,nxt,nwg);
      else if (obf)   k_gemm<64,64,true ,false,false><<<nwg,256,0,stream>>>(A,Bt,C,bias,res,nullptr,nullptr,nullptr,M,N,K,nxt,nwg);
      else            k_gemm<64,64,false,false,false><<<nwg,256,0,stream>>>(A,Bt,C,bias,res,nullptr,nullptr,nullptr,M,N,K,nxt,nwg);
    } else {
      int nxt = N / 64, nwg = nxt * ((M + 31) / 32);
      if (obf && gl)  k_gemm<32,64,true ,true ,false><<<nwg,256,0,stream>>>(A,Bt,C,bias,res,nullptr,nullptr,nullptr,M,N,K,nxt,nwg);
      else if (obf)   k_gemm<32,64,true ,false,false><<<nwg,256,0,stream>>>(A,Bt,C,bias,res,nullptr,nullptr,nullptr,M,N,K,nxt,nwg);
      else            k_gemm<32,64,false,false,false><<<nwg,256,0,stream>>>(A,Bt,C,bias,res,nullptr,nullptr,nullptr,M,N,K,nxt,nwg);
    }
  };
  auto gemmkv = [&](const bf16* A, const bf16* Bt, void* C,
                    const float* lb, const float2* rst, const float* c1, const float* cs,
                    int M, int N, int K) {
    if (M >= 2048) {
      int nxt = N / 128, nwg = nxt * ((M + 127) / 128);
      k_gemm<128,128,true,false,true><<<nwg,256,0,stream>>>(A,Bt,C,lb,nullptr,rst,c1,cs,M,N,K,nxt,nwg);
    } else {
      int nxt = N / 64, nwg = nxt * ((M + 63) / 64);
      k_gemm<64,64,true,false,true><<<nwg,256,0,stream>>>(A,Bt,C,lb,nullptr,rst,c1,cs,M,N,K,nxt,nwg);
    }
  };
  auto pick = [&](int M, int N) -> int {
    return M >= 2048 ? 128 : (N >= 1536 ? 64 : 32);
  };

  // ---- bias folds (vectorized) + merged kv fold (reads wkv once) ----
  k_bfoldv<<<dim3(4, 24), 256, 0, stream>>>(wq,  ln2b, qkvl_bias, 768, 1024, 768LL*1024, 768, 3072);
  k_kvfold<<<dim3(8, 24), 256, 0, stream>>>(wkv, ln2b, ln1b, ln1w,
                                            pb_in[0], pb_in[1], pb_in[2], pb_in[3],
                                            qkvl_bias, kvx_bias, svv, bwv);
  k_bfoldv<<<dim3(12, 6), 256, 0, stream>>>(ffw1, fflnb, ff_bias, 768, 3072, 768LL*3072, 768, 3072);

  // ---- small folded weights ----
  for (int i = 0; i < 4; ++i) {
    k_tfoldx<false><<<dim3(12, FRDS[i] / 64, 1), 256, 0, stream>>>(
        pw_in[i], nullptr, nullptr, pT[i], nullptr, FRDS[i], 768, 0, 0, 0, 0);
    int cnt = FRDS[i] * 768;
    k_cvt<<<cnt / 1024, 256, 0, stream>>>(pw_in[i], pbf[i], cnt / 4);
  }
  k_tfoldx<false><<<dim3(12, 12, 1), 256, 0, stream>>>(
      projw, nullptr, nullptr, projT, nullptr, 768, 768, 0, 0, 0, 0);

  // ---- full-mode weight folds (batched over all 24 layers; wkv read once here) ----
  if (fullw) {
    k_tfoldx<false><<<dim3(16, 12, 24), 256, 0, stream>>>(
        wq, ln2w, nullptr, wqkvlT, nullptr, 768, 1024, 768LL*1024, 768, 3072LL*768, 0);
    k_tfoldx<true><<<dim3(32, 12, 24), 256, 0, stream>>>(
        wkv, ln2w, ln1w, wqkvlT + 1024LL*768, wkvxT, 768, 2048,
        768LL*2048, 768, 3072LL*768, 2048LL*768);
    k_tfoldx<false><<<dim3(12, 16, 24), 256, 0, stream>>>(
        wo, nullptr, nullptr, woT, nullptr, 1024, 768, 1024LL*768, 0, 768LL*1024, 0);
    k_tfoldx<false><<<dim3(48, 12, 6), 256, 0, stream>>>(
        ffw1, fflnw, nullptr, w1T, nullptr, 768, 3072, 768LL*3072, 768, 3072LL*768, 0);
    k_tfoldx<false><<<dim3(12, 48, 6), 256, 0, stream>>>(
        ffw2, nullptr, nullptr, w2T, nullptr, 3072, 768, 3072LL*768, 0, 768LL*3072, 0);
  }

  auto foldDepthAttn = [&](int d) {
    k_tfoldx<false><<<dim3(16, 12, 4), 256, 0, stream>>>(
        wq + (size_t)d*4*768*1024, ln2w + (size_t)d*4*768, nullptr,
        wbuf, nullptr, 768, 1024, 768LL*1024, 768, (long long)LW, 0);
    k_tfoldx<true><<<dim3(32, 12, 4), 256, 0, stream>>>(
        wkv + (size_t)d*4*768*2048, ln2w + (size_t)d*4*768, ln1w + (size_t)d*4*768,
        wbuf + 1024ull*768, wbuf + 3072ull*768, 768, 2048,
        768LL*2048, 768, (long long)LW, (long long)LW);
    k_tfoldx<false><<<dim3(12, 16, 4), 256, 0, stream>>>(
        wo + (size_t)d*4*1024*768, nullptr, nullptr,
        wbuf + 3932160ull, nullptr, 1024, 768, 1024LL*768, 0, (long long)LW, 0);
  };
  auto attnW = [&](int di, const bf16*& qkvlT_p, const bf16*& kvxT_p, const bf16*& woT_p) {
    if (fullw) {
      qkvlT_p = wqkvlT + (size_t)di * 3072 * 768;
      kvxT_p  = wkvxT  + (size_t)di * 2048 * 768;
      woT_p   = woT    + (size_t)di * 768 * 1024;
    } else {
      bf16* base = wbuf + (size_t)(di & 3) * LW;
      qkvlT_p = base;
      kvxT_p  = base + 2359296ull;
      woT_p   = base + 3932160ull;
    }
  };
  auto ffW = [&](int d, const bf16*& w1p, const bf16*& w2p) {
    if (fullw) {
      w1p = w1T + (size_t)d * 3072 * 768;
      w2p = w2T + (size_t)d * 768 * 3072;
    } else {
      bf16* d1 = wbuf;
      bf16* d2 = wbuf + 3072ull * 768;
      k_tfoldx<false><<<dim3(48, 12, 1), 256, 0, stream>>>(
          ffw1 + (size_t)d*768*3072, fflnw + 768ull*d, nullptr, d1, nullptr,
          768, 3072, 0, 0, 0, 0);
      k_tfoldx<false><<<dim3(12, 48, 1), 256, 0, stream>>>(
          ffw2 + (size_t)d*3072*768, nullptr, nullptr, d2, nullptr,
          3072, 768, 0, 0, 0, 0);
      w1p = d1; w2p = d2;
    }
  };

  // ---- feature projection -> row stats only ----
  for (int i = 0; i < 4; ++i) {
    int n1 = N1S[i], frd = FRDS[i];
    size_t cnt = (size_t)16 * n1 * frd;
    k_cvt<<<(int)(cnt / 1024), 256, 0, stream>>>(f_in[i], fbf[i], (int)(cnt / 4));
    for (int b0 = 0; b0 < 16; b0 += bc) {
      int rows = bc * n1;
      gemm(pick(rows, 768), fbf[i] + (size_t)b0 * n1 * frd, pT[i], featf32,
           pb_in[i], nullptr, rows, 768, frd, false, false);
      k_stats<<<rows, 256, 0, stream>>>(featf32, rstats + ROFF[i] + (size_t)b0 * n1);
    }
  }

  hipMemcpyAsync(lat, id_emb, 1024ull * 768 * 4, hipMemcpyDeviceToDevice, stream);

  // ---- depth loop ----
  for (int d = 0; d < 6; ++d) {
    if (!fullw) foldDepthAttn(d);
    for (int i = 0; i < 4; ++i) {
      int di = d * 4 + i, n1 = N1S[i], nseg = NSEG[i], frd = FRDS[i];
      const bf16 *qkvlT_p, *kvxT_p, *woT_p;
      attnW(di, qkvlT_p, kvxT_p, woT_p);
      gemm(64, kvxT_p, pbf[i], PTbuf, nullptr, nullptr, 2048, frd, 768, true, false);
      k_std<<<1024, 256, 0, stream>>>(lat, zlat);
      gemm(64, zlat, qkvlT_p, qkvl_act, qkvl_bias + 3072ull * di, nullptr,
           1024, 3072, 768, true, false);
      for (int b0 = 0; b0 < 16; b0 += bc) {
        int rows = bc * n1;
        gemmkv(fbf[i] + (size_t)b0 * n1 * frd, PTbuf, kvxbuf,
               kvx_bias + 2048ull * di, rstats + ROFF[i] + (size_t)b0 * n1,
               bwv + 2048ull * di, svv + 2048ull * di, rows, 2048, frd);
        k_attn<<<bc * 16 * nseg, 256, 0, stream>>>(qkvl_act, kvxbuf, attnout,
                                                   opart, mlpart, n1, b0, nseg, bc);
        if (nseg > 1)
          k_amerge<<<bc * 16, 256, 0, stream>>>(opart, mlpart, attnout, b0, nseg, bc);
      }
      gemm(32, attnout, woT_p, lat, nullptr, lat, 1024, 768, 1024, false, false);
    }
    const bf16 *w1p, *w2p;
    ffW(d, w1p, w2p);
    k_std<<<1024, 256, 0, stream>>>(lat, zlat);
    gemm(64, zlat, w1p, ffh, ff_bias + 3072ull * d, nullptr, 1024, 3072, 768, true, true);
    gemm(32, ffh, w2p, lat, nullptr, lat, 1024, 768, 3072, false, false);
  }

  // ---- head ----
  k_cvt<<<768, 256, 0, stream>>>(lat, latbf, 196608);
  gemm(32, latbf, projT, headtmp, projb, nullptr, 1024, 768, 768, false, false);
  k_lnout<<<1024, 256, 0, stream>>>(headtmp, normw, normb, (float*)d_out);
}

// Round 11
// 2951.388 us; speedup vs baseline: 2.2924x; 1.1654x over previous
//
#include <hip/hip_runtime.h>
#include <hip/hip_bf16.h>
#include <cstdint>
#include <cstddef>

typedef __hip_bfloat16 bf16;
typedef float  f32x4   __attribute__((ext_vector_type(4)));
typedef float  float4v __attribute__((ext_vector_type(4)));
typedef short  short8  __attribute__((ext_vector_type(8)));
typedef short  short4v __attribute__((ext_vector_type(4)));
typedef __bf16 bf16x8  __attribute__((ext_vector_type(8)));

__device__ __forceinline__ void mfma16(f32x4& d, short8 a, short8 b) {
  d = __builtin_amdgcn_mfma_f32_16x16x32_bf16(
      __builtin_bit_cast(bf16x8, a), __builtin_bit_cast(bf16x8, b), d, 0, 0, 0);
}
__device__ __forceinline__ unsigned short f2b_bits(float x) {
  __hip_bfloat16 h = __float2bfloat16(x);
  return __builtin_bit_cast(unsigned short, h);
}
__device__ __forceinline__ float gelu_exact(float x) {
  return 0.5f * x * (1.0f + erff(x * 0.7071067811865475f));
}

// ---------- f32 -> bf16 convert ----------
__global__ __launch_bounds__(256) void k_cvt(const float* __restrict__ src,
                                             bf16* __restrict__ dst, int n4) {
  int i = blockIdx.x * 256 + threadIdx.x;
  if (i >= n4) return;
  float4v v = *(const float4v*)(src + (size_t)i * 4);
  short4v s;
  s[0] = (short)f2b_bits(v[0]); s[1] = (short)f2b_bits(v[1]);
  s[2] = (short)f2b_bits(v[2]); s[3] = (short)f2b_bits(v[3]);
  *(short4v*)((short*)dst + (size_t)i * 4) = s;
}

// ---------- transpose-fold x ----------
template <bool DUAL>
__global__ __launch_bounds__(256) void k_tfoldx(const float* __restrict__ src,
                                                const float* __restrict__ s1,
                                                const float* __restrict__ s2,
                                                bf16* __restrict__ d1,
                                                bf16* __restrict__ d2,
                                                int K, int N,
                                                long long src_bs, long long s_bs,
                                                long long d1_bs, long long d2_bs) {
  src += (size_t)blockIdx.z * src_bs;
  d1  += (size_t)blockIdx.z * d1_bs;
  if (DUAL) d2 += (size_t)blockIdx.z * d2_bs;
  __shared__ float tile[64][65];
  __shared__ float sc1[64], sc2[64];
  const int n0 = blockIdx.x * 64, k0 = blockIdx.y * 64;
  const int t = threadIdx.x;
  if (t < 64) {
    sc1[t] = s1 ? (s1 + (size_t)blockIdx.z * s_bs)[k0 + t] : 1.0f;
  } else if (DUAL && t < 128) {
    sc2[t - 64] = (s2 + (size_t)blockIdx.z * s_bs)[k0 + t - 64];
  }
#pragma unroll
  for (int j = 0; j < 4; ++j) {
    int f = t + j * 256;
    int row = f >> 4, col = (f & 15) * 4;
    float4v v = *(const float4v*)(src + (size_t)(k0 + row) * N + n0 + col);
    tile[row][col]     = v[0];
    tile[row][col + 1] = v[1];
    tile[row][col + 2] = v[2];
    tile[row][col + 3] = v[3];
  }
  __syncthreads();
#pragma unroll
  for (int j = 0; j < 2; ++j) {
    int s = t + j * 256;
    int n = s >> 3, kc = (s & 7) * 8;
    short8 o1v, o2v;
#pragma unroll
    for (int i = 0; i < 8; ++i) {
      float v = tile[kc + i][n];
      o1v[i] = (short)f2b_bits(v * sc1[kc + i]);
      if (DUAL) o2v[i] = (short)f2b_bits(v * sc2[kc + i]);
    }
    *(short8*)(d1 + (size_t)(n0 + n) * K + k0 + kc) = o1v;
    if (DUAL) *(short8*)(d2 + (size_t)(n0 + n) * K + k0 + kc) = o2v;
  }
}

// ---------- vectorized bias fold ----------
__global__ __launch_bounds__(256) void k_bfoldv(const float* __restrict__ W,
                                                const float* __restrict__ lnb,
                                                float* __restrict__ out, int K, int N,
                                                long long w_bs, long long b_bs, long long o_bs) {
  W   += (size_t)blockIdx.y * w_bs;
  lnb += (size_t)blockIdx.y * b_bs;
  out += (size_t)blockIdx.y * o_bs;
  __shared__ float sb[768];
  for (int k = threadIdx.x; k < K; k += 256) sb[k] = lnb[k];
  __syncthreads();
  const int lane = threadIdx.x & 63, kg = threadIdx.x >> 6;
  const int n = blockIdx.x * 256 + lane * 4;
  float4v a = {0.f, 0.f, 0.f, 0.f};
  for (int k = kg; k < K; k += 4) {
    float4v wv = *(const float4v*)(W + (size_t)k * N + n);
    float c = sb[k];
    a[0] = fmaf(c, wv[0], a[0]); a[1] = fmaf(c, wv[1], a[1]);
    a[2] = fmaf(c, wv[2], a[2]); a[3] = fmaf(c, wv[3], a[3]);
  }
  __shared__ float4v red[4][64];
  red[kg][lane] = a;
  __syncthreads();
  if (kg == 0) {
    float4v r = red[0][lane] + red[1][lane] + red[2][lane] + red[3][lane];
    *(float4v*)(out + n) = r;
  }
}

// ---------- merged kv fold, K-split (z=8): partials to pbuf ----------
__global__ __launch_bounds__(256) void k_kvfold(const float* __restrict__ wkv,
                                                const float* __restrict__ ln2b,
                                                const float* __restrict__ ln1b,
                                                const float* __restrict__ ln1w,
                                                const float* __restrict__ b0,
                                                const float* __restrict__ b1,
                                                const float* __restrict__ b2,
                                                const float* __restrict__ b3,
                                                float* __restrict__ pbuf) {
  const int di = blockIdx.y;
  const int kz = blockIdx.z;
  const int i = di & 3;
  const float* pb = (i == 0) ? b0 : (i == 1) ? b1 : (i == 2) ? b2 : b3;
  const float* W = wkv + (size_t)di * 768 * 2048;
  __shared__ float c2b[96], c1b[96], c1w[96], cpw[96];
  if (threadIdx.x < 96) {
    int k = kz * 96 + threadIdx.x;
    float w1 = ln1w[(size_t)di * 768 + k];
    c2b[threadIdx.x] = ln2b[(size_t)di * 768 + k];
    c1b[threadIdx.x] = ln1b[(size_t)di * 768 + k];
    c1w[threadIdx.x] = w1;
    cpw[threadIdx.x] = pb[k] * w1;
  }
  __syncthreads();
  const int lane = threadIdx.x & 63, kg = threadIdx.x >> 6;
  const int n = blockIdx.x * 256 + lane * 4;
  float4v a1 = {0.f,0.f,0.f,0.f}, a2 = a1, a3 = a1, a4 = a1;
  for (int kk = kg; kk < 96; kk += 4) {
    float4v wv = *(const float4v*)(W + (size_t)(kz * 96 + kk) * 2048 + n);
    float s1 = c2b[kk], s2 = c1b[kk], s3 = c1w[kk], s4 = cpw[kk];
#pragma unroll
    for (int q = 0; q < 4; ++q) {
      a1[q] = fmaf(s1, wv[q], a1[q]);
      a2[q] = fmaf(s2, wv[q], a2[q]);
      a3[q] = fmaf(s3, wv[q], a3[q]);
      a4[q] = fmaf(s4, wv[q], a4[q]);
    }
  }
  __shared__ float4v red[4][64];
  red[kg][lane] = a1; __syncthreads();
  if (kg == 0) {
    float4v r = red[0][lane] + red[1][lane] + red[2][lane] + red[3][lane];
    *(float4v*)(pbuf + (((size_t)0 * 8 + kz) * 24 + di) * 2048 + n) = r;
  }
  __syncthreads();
  red[kg][lane] = a2; __syncthreads();
  if (kg == 0) {
    float4v r = red[0][lane] + red[1][lane] + red[2][lane] + red[3][lane];
    *(float4v*)(pbuf + (((size_t)1 * 8 + kz) * 24 + di) * 2048 + n) = r;
  }
  __syncthreads();
  red[kg][lane] = a3; __syncthreads();
  if (kg == 0) {
    float4v r = red[0][lane] + red[1][lane] + red[2][lane] + red[3][lane];
    *(float4v*)(pbuf + (((size_t)2 * 8 + kz) * 24 + di) * 2048 + n) = r;
  }
  __syncthreads();
  red[kg][lane] = a4; __syncthreads();
  if (kg == 0) {
    float4v r = red[0][lane] + red[1][lane] + red[2][lane] + red[3][lane];
    *(float4v*)(pbuf + (((size_t)3 * 8 + kz) * 24 + di) * 2048 + n) = r;
  }
}

// ---------- reduce kv fold partials ----------
__global__ __launch_bounds__(256) void k_kvred(const float* __restrict__ pbuf,
                                               float* __restrict__ qb,
                                               float* __restrict__ kb,
                                               float* __restrict__ sv,
                                               float* __restrict__ bw) {
  const int di = blockIdx.y;
  const int n = blockIdx.x * 256 + threadIdx.x;
  float a0 = 0.f, a1 = 0.f, a2 = 0.f, a3 = 0.f;
  for (int kz = 0; kz < 8; ++kz) {
    a0 += pbuf[(((size_t)0 * 8 + kz) * 24 + di) * 2048 + n];
    a1 += pbuf[(((size_t)1 * 8 + kz) * 24 + di) * 2048 + n];
    a2 += pbuf[(((size_t)2 * 8 + kz) * 24 + di) * 2048 + n];
    a3 += pbuf[(((size_t)3 * 8 + kz) * 24 + di) * 2048 + n];
  }
  qb[(size_t)di * 3072 + 1024 + n] = a0;
  kb[(size_t)di * 2048 + n] = a1;
  sv[(size_t)di * 2048 + n] = a2;
  bw[(size_t)di * 2048 + n] = a3;
}

// ---------- row standardize (768-wide), f32 -> bf16 ----------
__global__ __launch_bounds__(256) void k_std(const float* __restrict__ src,
                                             bf16* __restrict__ dst) {
  int row = blockIdx.x;
  const float* x = src + (size_t)row * 768;
  int t = threadIdx.x;
  float a0 = x[t], a1 = x[t + 256], a2 = x[t + 512];
  float s = a0 + a1 + a2;
  float q = a0 * a0 + a1 * a1 + a2 * a2;
#pragma unroll
  for (int off = 1; off < 64; off <<= 1) { s += __shfl_xor(s, off); q += __shfl_xor(q, off); }
  __shared__ float ss[4], qs[4];
  if ((t & 63) == 0) { ss[t >> 6] = s; qs[t >> 6] = q; }
  __syncthreads();
  s = ss[0] + ss[1] + ss[2] + ss[3];
  q = qs[0] + qs[1] + qs[2] + qs[3];
  float mean = s * (1.0f / 768.0f);
  float var  = q * (1.0f / 768.0f) - mean * mean;
  float inv  = rsqrtf(var + 1e-5f);
  bf16* d = dst + (size_t)row * 768;
  d[t]       = __float2bfloat16((a0 - mean) * inv);
  d[t + 256] = __float2bfloat16((a1 - mean) * inv);
  d[t + 512] = __float2bfloat16((a2 - mean) * inv);
}

// ---------- row stats only ----------
__global__ __launch_bounds__(256) void k_stats(const float* __restrict__ src,
                                               float2* __restrict__ out) {
  int row = blockIdx.x;
  const float* x = src + (size_t)row * 768;
  int t = threadIdx.x;
  float a0 = x[t], a1 = x[t + 256], a2 = x[t + 512];
  float s = a0 + a1 + a2;
  float q = a0 * a0 + a1 * a1 + a2 * a2;
#pragma unroll
  for (int off = 1; off < 64; off <<= 1) { s += __shfl_xor(s, off); q += __shfl_xor(q, off); }
  __shared__ float ss[4], qs[4];
  if ((t & 63) == 0) { ss[t >> 6] = s; qs[t >> 6] = q; }
  __syncthreads();
  if (t == 0) {
    float sm = ss[0] + ss[1] + ss[2] + ss[3];
    float qm = qs[0] + qs[1] + qs[2] + qs[3];
    float mean = sm * (1.0f / 768.0f);
    float var  = qm * (1.0f / 768.0f) - mean * mean;
    float inv  = rsqrtf(var + 1e-5f);
    out[row] = make_float2(inv, mean * inv);
  }
}

// ---------- final layernorm ----------
__global__ __launch_bounds__(256) void k_lnout(const float* __restrict__ src,
                                               const float* __restrict__ w,
                                               const float* __restrict__ b,
                                               float* __restrict__ dst) {
  int row = blockIdx.x;
  const float* x = src + (size_t)row * 768;
  int t = threadIdx.x;
  float a0 = x[t], a1 = x[t + 256], a2 = x[t + 512];
  float s = a0 + a1 + a2;
  float q = a0 * a0 + a1 * a1 + a2 * a2;
#pragma unroll
  for (int off = 1; off < 64; off <<= 1) { s += __shfl_xor(s, off); q += __shfl_xor(q, off); }
  __shared__ float ss[4], qs[4];
  if ((t & 63) == 0) { ss[t >> 6] = s; qs[t >> 6] = q; }
  __syncthreads();
  s = ss[0] + ss[1] + ss[2] + ss[3];
  q = qs[0] + qs[1] + qs[2] + qs[3];
  float mean = s * (1.0f / 768.0f);
  float var  = q * (1.0f / 768.0f) - mean * mean;
  float inv  = rsqrtf(var + 1e-5f);
  float* d = dst + (size_t)row * 768;
  d[t]       = (a0 - mean) * inv * w[t]       + b[t];
  d[t + 256] = (a1 - mean) * inv * w[t + 256] + b[t + 256];
  d[t + 512] = (a2 - mean) * inv * w[t + 512] + b[t + 512];
}

// ---------- MFMA GEMM ----------
template <int BM, int BN, bool OBF16, bool GELU, bool KVE>
__global__ __launch_bounds__(256) void k_gemm(const bf16* __restrict__ A,
                                              const bf16* __restrict__ Bt,
                                              void* __restrict__ Cv,
                                              const float* __restrict__ bias,
                                              const float* __restrict__ res,
                                              const float2* __restrict__ rstats,
                                              const float* __restrict__ c1,
                                              const float* __restrict__ cs,
                                              int M, int N, int K, int nxt, int nwg) {
  constexpr int AI = BM / 32, BI = BN / 32;
  constexpr int MF = BM / 32, NF = BN / 32;
  __shared__ __align__(16) char smem[(BM + BN) * 128];
  char* As = smem;
  char* Bs = smem + BM * 128;

  const int lin = blockIdx.x;
  const int qq = nwg >> 3, r8 = nwg & 7;
  const int xcd = lin & 7, idx = lin >> 3;
  const int swz = (xcd < r8) ? (xcd * (qq + 1) + idx)
                             : (r8 * (qq + 1) + (xcd - r8) * qq + idx);
  const int bm = (swz / nxt) * BM, bn = (swz % nxt) * BN;

  const int t = threadIdx.x, lane = t & 63, w = t >> 6;
  const int wr = w >> 1, wc = w & 1;
  const int l15 = lane & 15, lg = lane >> 4;
  const int srow = t >> 3, scol = t & 7;

  const bf16* aptr[AI]; int aoff[AI];
#pragma unroll
  for (int i = 0; i < AI; ++i) {
    int r = i * 32 + srow;
    int gr = bm + r; if (gr > M - 1) gr = M - 1;
    aptr[i] = A + (size_t)gr * K + scol * 8;
    aoff[i] = r * 128 + ((scol * 16) ^ ((r & 7) << 4));
  }
  const bf16* bptr[BI]; int boff[BI];
#pragma unroll
  for (int i = 0; i < BI; ++i) {
    int r = i * 32 + srow;
    int gc = bn + r; if (gc > N - 1) gc = N - 1;
    bptr[i] = Bt + (size_t)gc * K + scol * 8;
    boff[i] = r * 128 + ((scol * 16) ^ ((r & 7) << 4));
  }

  f32x4 acc[MF][NF] = {};
  short8 av[AI], bv[BI];
#pragma unroll
  for (int i = 0; i < AI; ++i) av[i] = *(const short8*)(aptr[i]);
#pragma unroll
  for (int i = 0; i < BI; ++i) bv[i] = *(const short8*)(bptr[i]);

  const int nk = K / 64;
  for (int kt = 0; kt < nk; ++kt) {
    __syncthreads();
#pragma unroll
    for (int i = 0; i < AI; ++i) *(short8*)(As + aoff[i]) = av[i];
#pragma unroll
    for (int i = 0; i < BI; ++i) *(short8*)(Bs + boff[i]) = bv[i];
    __syncthreads();
    if (kt + 1 < nk) {
#pragma unroll
      for (int i = 0; i < AI; ++i) av[i] = *(const short8*)(aptr[i] + (size_t)(kt + 1) * 64);
#pragma unroll
      for (int i = 0; i < BI; ++i) bv[i] = *(const short8*)(bptr[i] + (size_t)(kt + 1) * 64);
    }
#pragma unroll
    for (int ks = 0; ks < 2; ++ks) {
      short8 af[MF], bfr[NF];
#pragma unroll
      for (int m = 0; m < MF; ++m) {
        int r = wr * (BM / 2) + m * 16 + l15;
        af[m] = *(const short8*)(As + r * 128 + ((ks * 64 + lg * 16) ^ ((r & 7) << 4)));
      }
#pragma unroll
      for (int n = 0; n < NF; ++n) {
        int r = wc * (BN / 2) + n * 16 + l15;
        bfr[n] = *(const short8*)(Bs + r * 128 + ((ks * 64 + lg * 16) ^ ((r & 7) << 4)));
      }
#pragma unroll
      for (int m = 0; m < MF; ++m)
#pragma unroll
        for (int n = 0; n < NF; ++n) mfma16(acc[m][n], af[m], bfr[n]);
    }
  }

  if (OBF16) {
    __syncthreads();
    bf16* cst = (bf16*)smem;
#pragma unroll
    for (int m = 0; m < MF; ++m) {
      int lr0 = wr * (BM / 2) + m * 16 + lg * 4;
#pragma unroll
      for (int n = 0; n < NF; ++n) {
        int lc = wc * (BN / 2) + n * 16 + l15;
        int gc = bn + lc;
        float bvs = bias ? bias[gc] : 0.0f;
        float c1v = 0.0f, csv = 0.0f;
        if (KVE) { c1v = c1[gc]; csv = cs[gc]; }
#pragma unroll
        for (int r = 0; r < 4; ++r) {
          int row = lr0 + r;
          float v;
          if (KVE) {
            int gri = bm + row; if (gri > M - 1) gri = M - 1;
            float2 st = rstats[gri];
            v = (acc[m][n][r] + c1v) * st.x - st.y * csv + bvs;
          } else {
            v = acc[m][n][r] + bvs;
            if (GELU) v = gelu_exact(v);
          }
          cst[row * BN + lc] = __float2bfloat16(v);
        }
      }
    }
    __syncthreads();
    constexpr int CB = BN / 8;
    constexpr int SEGS = BM * CB;
    for (int seg = t; seg < SEGS; seg += 256) {
      int row = seg / CB, cb = seg % CB;
      int gr = bm + row;
      if (gr < M)
        *(short8*)((bf16*)Cv + (size_t)gr * N + bn + cb * 8) =
            *(const short8*)(cst + (size_t)row * BN + cb * 8);
    }
  } else {
#pragma unroll
    for (int m = 0; m < MF; ++m) {
      int gr0 = bm + wr * (BM / 2) + m * 16 + lg * 4;
#pragma unroll
      for (int n = 0; n < NF; ++n) {
        int gc = bn + wc * (BN / 2) + n * 16 + l15;
        float bvs = bias ? bias[gc] : 0.0f;
#pragma unroll
        for (int r = 0; r < 4; ++r) {
          int gr = gr0 + r;
          if (gr < M) {
            float v = acc[m][n][r] + bvs;
            if (GELU) v = gelu_exact(v);
            if (res) v += res[(size_t)gr * N + gc];
            ((float*)Cv)[(size_t)gr * N + gc] = v;
          }
        }
      }
    }
  }
}

// ---------- fused attention, split-KV + swapped-QK^T softmax ----------
// FUSED: x-part K/V computed on the fly from f (n1 % 64 == 0 required):
//   K = affine(f @ PTk_h), V = affine(f @ PTv_h) into the same Ks/Vt layout.
template <bool FUSED>
__global__ __launch_bounds__(256) void k_attn(const bf16* __restrict__ qkvl,
                                              const bf16* __restrict__ kvx,
                                              bf16* __restrict__ outp,
                                              float* __restrict__ opart,
                                              float* __restrict__ mlpart,
                                              int n1, int b0, int nseg, int nbloc,
                                              const bf16* __restrict__ fsrc,
                                              const bf16* __restrict__ PT,
                                              const float2* __restrict__ rst,
                                              const float* __restrict__ c1vec,
                                              const float* __restrict__ csvec,
                                              const float* __restrict__ lbvec) {
  const int s   = blockIdx.x % nseg;
  const int bh  = blockIdx.x / nseg;
  const int bl = bh >> 4, h = bh & 15;
  const int b = b0 + bl;
  const int nb64 = nbloc * 64;
  __shared__ __align__(16) char Qs[64 * 128];
  __shared__ __align__(16) char Ks[64 * 128];
  __shared__ __align__(16) char Vt[64 * 128];
  __shared__ __align__(16) char Ps[4][16 * 128];
  __shared__ __align__(16) char Fs[FUSED ? 64 * 128 : 16];
  __shared__ __align__(16) char PTks[FUSED ? 64 * 128 : 16];
  __shared__ __align__(16) char PTvs[FUSED ? 64 * 128 : 16];
  __shared__ float2 Rs[FUSED ? 64 : 1];
  const int t = threadIdx.x, lane = t & 63, w = t >> 6;
  const int l15 = lane & 15, lg = lane >> 4;

#pragma unroll
  for (int it = 0; it < 2; ++it) {
    int slot = it * 256 + t; int r = slot >> 3, c = slot & 7;
    short8 v = *(const short8*)(qkvl + (size_t)(b * 64 + r) * 3072 + h * 64 + c * 8);
    *(short8*)(Qs + r * 128 + ((c * 16) ^ ((r & 7) << 4))) = v;
  }
  float c1k[4], csk[4], lbk[4], c1v_[4], csv_[4], lbv_[4];
  if constexpr (FUSED) {
#pragma unroll
    for (int it = 0; it < 2; ++it) {
      int slot = it * 256 + t; int r = slot >> 3, c = slot & 7;
      *(short8*)(PTks + r * 128 + ((c * 16) ^ ((r & 7) << 4))) =
          *(const short8*)(PT + (size_t)(h * 64 + r) * 64 + c * 8);
      *(short8*)(PTvs + r * 128 + ((c * 16) ^ ((r & 7) << 4))) =
          *(const short8*)(PT + (size_t)(1024 + h * 64 + r) * 64 + c * 8);
    }
#pragma unroll
    for (int n = 0; n < 4; ++n) {
      int dk = h * 64 + n * 16 + l15;
      c1k[n] = c1vec[dk]; csk[n] = csvec[dk]; lbk[n] = lbvec[dk];
      int dv = 1024 + dk;
      c1v_[n] = c1vec[dv]; csv_[n] = csvec[dv]; lbv_[n] = lbvec[dv];
    }
  }
  const int n_kv = n1 + 64;
  const int nch = (n_kv + 63) >> 6;
  const int cpseg = (nch + nseg - 1) / nseg;
  const int ch0 = s * cpseg;
  const int ch1 = min(nch, ch0 + cpseg);

  float m_run = -1e30f, l_run = 0.0f;
  f32x4 o[4] = {};

  short8 kreg[2], vreg[2], freg[2];
  float2 rreg = make_float2(0.f, 0.f);
  auto loadKV = [&](int ch) {
#pragma unroll
    for (int it = 0; it < 2; ++it) {
      int slot = it * 256 + t; int rr = slot >> 3, c = slot & 7;
      int j = ch * 64 + rr;
      short8 kv = {}; short8 vv = {};
      if (j < n_kv) {
        const bf16* kb;
        if (j < n1) kb = kvx + (size_t)(bl * n1 + j) * 2048 + h * 64;
        else        kb = qkvl + (size_t)(b * 64 + (j - n1)) * 3072 + 1024 + h * 64;
        kv = *(const short8*)(kb + c * 8);
        vv = *(const short8*)(kb + 1024 + c * 8);
      }
      kreg[it] = kv; vreg[it] = vv;
    }
  };
  auto loadF = [&](int ch) {
#pragma unroll
    for (int it = 0; it < 2; ++it) {
      int slot = it * 256 + t; int rr = slot >> 3, c = slot & 7;
      freg[it] = *(const short8*)(fsrc + ((size_t)b * n1 + (size_t)ch * 64 + rr) * 64 + c * 8);
    }
    if (t < 64) rreg = rst[(size_t)b * n1 + (size_t)ch * 64 + t];
  };
  auto isLat = [&](int ch) { return ch * 64 >= n1; };

  if (FUSED && !isLat(ch0)) loadF(ch0); else loadKV(ch0);

  for (int ch = ch0; ch < ch1; ++ch) {
    const bool lat = !FUSED || isLat(ch);
    __syncthreads();
    if (lat) {
#pragma unroll
      for (int it = 0; it < 2; ++it) {
        int slot = it * 256 + t; int rr = slot >> 3, c = slot & 7;
        *(short8*)(Ks + rr * 128 + ((c * 16) ^ ((rr & 7) << 4))) = kreg[it];
#pragma unroll
        for (int j2 = 0; j2 < 8; ++j2) {
          int dh = c * 8 + j2;
          *(short*)(Vt + dh * 128 + ((rr * 2) ^ ((dh & 7) << 4))) = vreg[it][j2];
        }
      }
    } else {
#pragma unroll
      for (int it = 0; it < 2; ++it) {
        int slot = it * 256 + t; int rr = slot >> 3, c = slot & 7;
        *(short8*)(Fs + rr * 128 + ((c * 16) ^ ((rr & 7) << 4))) = freg[it];
      }
      if (t < 64) Rs[t] = rreg;
    }
    __syncthreads();
    if (ch + 1 < ch1) {
      if (FUSED && !isLat(ch + 1)) loadF(ch + 1); else loadKV(ch + 1);
    }
    if constexpr (FUSED) {
      if (!lat) {
        // K = affine(f @ PTk_h)
        f32x4 ka[4] = {};
#pragma unroll
        for (int ks = 0; ks < 2; ++ks) {
          int fr = w * 16 + l15;
          short8 ff = *(const short8*)(Fs + fr * 128 + ((ks * 64 + lg * 16) ^ ((fr & 7) << 4)));
#pragma unroll
          for (int n = 0; n < 4; ++n) {
            int pr = n * 16 + l15;
            short8 pk = *(const short8*)(PTks + pr * 128 + ((ks * 64 + lg * 16) ^ ((pr & 7) << 4)));
            mfma16(ka[n], ff, pk);
          }
        }
#pragma unroll
        for (int n = 0; n < 4; ++n)
#pragma unroll
          for (int r = 0; r < 4; ++r) {
            int jl = w * 16 + lg * 4 + r;
            float2 st = Rs[jl];
            float v = (ka[n][r] + c1k[n]) * st.x - st.y * csk[n] + lbk[n];
            int dh = n * 16 + l15;
            *(unsigned short*)(Ks + jl * 128 + ((dh * 2) ^ ((jl & 7) << 4))) = f2b_bits(v);
          }
        // V = affine(f @ PTv_h), transposed into Vt
        f32x4 va[4] = {};
#pragma unroll
        for (int ks = 0; ks < 2; ++ks) {
          int fr = w * 16 + l15;
          short8 ff = *(const short8*)(Fs + fr * 128 + ((ks * 64 + lg * 16) ^ ((fr & 7) << 4)));
#pragma unroll
          for (int n = 0; n < 4; ++n) {
            int pr = n * 16 + l15;
            short8 pv = *(const short8*)(PTvs + pr * 128 + ((ks * 64 + lg * 16) ^ ((pr & 7) << 4)));
            mfma16(va[n], ff, pv);
          }
        }
#pragma unroll
        for (int n = 0; n < 4; ++n)
#pragma unroll
          for (int r = 0; r < 4; ++r) {
            int jl = w * 16 + lg * 4 + r;
            float2 st = Rs[jl];
            float v = (va[n][r] + c1v_[n]) * st.x - st.y * csv_[n] + lbv_[n];
            int dh = n * 16 + l15;
            *(unsigned short*)(Vt + dh * 128 + ((jl * 2) ^ ((dh & 7) << 4))) = f2b_bits(v);
          }
      }
      __syncthreads();
    }

    f32x4 sc[4] = {};
#pragma unroll
    for (int ks = 0; ks < 2; ++ks) {
      int qr = w * 16 + l15;
      short8 qf = *(const short8*)(Qs + qr * 128 + ((ks * 64 + lg * 16) ^ ((qr & 7) << 4)));
#pragma unroll
      for (int n = 0; n < 4; ++n) {
        int kr = n * 16 + l15;
        short8 kf = *(const short8*)(Ks + kr * 128 + ((ks * 64 + lg * 16) ^ ((kr & 7) << 4)));
        mfma16(sc[n], kf, qf);
      }
    }
    float mx = m_run;
#pragma unroll
    for (int n = 0; n < 4; ++n)
#pragma unroll
      for (int r = 0; r < 4; ++r) {
        float v = sc[n][r] * 0.125f;
        int kvi = ch * 64 + n * 16 + lg * 4 + r;
        if (kvi >= n_kv) v = -1e30f;
        sc[n][r] = v;
        mx = fmaxf(mx, v);
      }
    mx = fmaxf(mx, __shfl_xor(mx, 16));
    mx = fmaxf(mx, __shfl_xor(mx, 32));
    float scl = __expf(m_run - mx);
    m_run = mx;
    float p[4][4];
    float rs = 0.0f;
#pragma unroll
    for (int n = 0; n < 4; ++n)
#pragma unroll
      for (int r = 0; r < 4; ++r) { float pv = __expf(sc[n][r] - mx); p[n][r] = pv; rs += pv; }
    rs += __shfl_xor(rs, 16);
    rs += __shfl_xor(rs, 32);
    l_run = l_run * scl + rs;
    float sclq[4];
#pragma unroll
    for (int r = 0; r < 4; ++r) sclq[r] = __shfl(scl, lg * 4 + r);
#pragma unroll
    for (int nn = 0; nn < 4; ++nn)
#pragma unroll
      for (int r = 0; r < 4; ++r) o[nn][r] *= sclq[r];
#pragma unroll
    for (int n = 0; n < 4; ++n)
#pragma unroll
      for (int r = 0; r < 4; ++r) {
        int kv = n * 16 + lg * 4 + r;
        *(unsigned short*)(Ps[w] + l15 * 128 + ((kv * 2) ^ ((l15 & 7) << 4))) = f2b_bits(p[n][r]);
      }
#pragma unroll
    for (int ks = 0; ks < 2; ++ks) {
      short8 pf = *(const short8*)(Ps[w] + l15 * 128 + ((ks * 64 + lg * 16) ^ ((l15 & 7) << 4)));
#pragma unroll
      for (int nn = 0; nn < 4; ++nn) {
        int dh = nn * 16 + l15;
        short8 vf = *(const short8*)(Vt + dh * 128 + ((ks * 64 + lg * 16) ^ ((dh & 7) << 4)));
        mfma16(o[nn], pf, vf);
      }
    }
  }

  if (nseg == 1) {
    float lq[4];
#pragma unroll
    for (int r = 0; r < 4; ++r) lq[r] = __shfl(l_run, lg * 4 + r);
#pragma unroll
    for (int nn = 0; nn < 4; ++nn)
#pragma unroll
      for (int r = 0; r < 4; ++r) {
        int qr = w * 16 + lg * 4 + r;
        int dh = nn * 16 + l15;
        outp[(size_t)(b * 64 + qr) * 1024 + h * 64 + dh] = __float2bfloat16(o[nn][r] / lq[r]);
      }
  } else {
#pragma unroll
    for (int nn = 0; nn < 4; ++nn)
#pragma unroll
      for (int r = 0; r < 4; ++r) {
        int qr = w * 16 + lg * 4 + r;
        int dh = nn * 16 + l15;
        opart[((size_t)s * nb64 + bl * 64 + qr) * 1024 + h * 64 + dh] = o[nn][r];
      }
    if (lg == 0) {
      int qr = w * 16 + l15;
      size_t mi = (((size_t)s * nb64 + bl * 64 + qr) * 16 + h) * 2;
      mlpart[mi]     = m_run;
      mlpart[mi + 1] = l_run;
    }
  }
}

// ---------- merge split-KV partials ----------
__global__ __launch_bounds__(256) void k_amerge(const float* __restrict__ opart,
                                                const float* __restrict__ mlpart,
                                                bf16* __restrict__ outp,
                                                int b0, int nseg, int nbloc) {
  const int bh = blockIdx.x;
  const int bl = bh >> 4, h = bh & 15;
  const int nb64 = nbloc * 64;
  const int t = threadIdx.x;
  const int q = t >> 2, quarter = t & 3;

  float ms[8], ls[8];
  float mstar = -1e30f;
  for (int s = 0; s < nseg; ++s) {
    size_t mi = (((size_t)s * nb64 + bl * 64 + q) * 16 + h) * 2;
    ms[s] = mlpart[mi]; ls[s] = mlpart[mi + 1];
    mstar = fmaxf(mstar, ms[s]);
  }
  float L = 0.0f, ws[8];
  for (int s = 0; s < nseg; ++s) { ws[s] = __expf(ms[s] - mstar); L += ws[s] * ls[s]; }
  float inv = 1.0f / L;

  bf16* outrow = outp + (size_t)((b0 + bl) * 64 + q) * 1024 + h * 64;
#pragma unroll
  for (int jj = 0; jj < 4; ++jj) {
    int dh0 = quarter * 16 + jj * 4;
    float4v acc = {0.f, 0.f, 0.f, 0.f};
    for (int s = 0; s < nseg; ++s) {
      const float* orow = opart + ((size_t)s * nb64 + bl * 64 + q) * 1024 + h * 64 + dh0;
      float4v v = *(const float4v*)orow;
      acc[0] += ws[s] * v[0]; acc[1] += ws[s] * v[1];
      acc[2] += ws[s] * v[2]; acc[3] += ws[s] * v[3];
    }
    short4v sv;
    sv[0] = (short)f2b_bits(acc[0] * inv); sv[1] = (short)f2b_bits(acc[1] * inv);
    sv[2] = (short)f2b_bits(acc[2] * inv); sv[3] = (short)f2b_bits(acc[3] * inv);
    *(short4v*)((short*)(outrow + dh0)) = sv;
  }
}

// =========================== host ===========================
extern "C" void kernel_launch(void* const* d_in, const int* in_sizes, int n_in,
                              void* d_out, int out_size, void* d_ws, size_t ws_size,
                              hipStream_t stream) {
  (void)in_sizes; (void)n_in; (void)out_size;
  const float* id_emb = (const float*)d_in[0];
  const float* f_in[4]  = {(const float*)d_in[4],  (const float*)d_in[3],
                           (const float*)d_in[2],  (const float*)d_in[1]};
  const float* pw_in[4] = {(const float*)d_in[11], (const float*)d_in[9],
                           (const float*)d_in[7],  (const float*)d_in[5]};
  const float* pb_in[4] = {(const float*)d_in[12], (const float*)d_in[10],
                           (const float*)d_in[8],  (const float*)d_in[6]};
  const float* ln1w = (const float*)d_in[13];
  const float* ln1b = (const float*)d_in[14];
  const float* ln2w = (const float*)d_in[15];
  const float* ln2b = (const float*)d_in[16];
  const float* wq   = (const float*)d_in[17];
  const float* wkv  = (const float*)d_in[18];
  const float* wo   = (const float*)d_in[19];
  const float* fflnw = (const float*)d_in[20];
  const float* fflnb = (const float*)d_in[21];
  const float* ffw1  = (const float*)d_in[22];
  const float* ffw2  = (const float*)d_in[23];
  const float* projw = (const float*)d_in[24];
  const float* projb = (const float*)d_in[25];
  const float* normw = (const float*)d_in[26];
  const float* normb = (const float*)d_in[27];

  static const int N1S[4]  = {49, 196, 784, 3136};
  static const int FRDS[4] = {512, 256, 128, 64};
  static const int NSEG[4] = {1, 1, 2, 4};
  const size_t LW = 4718592;
  static const size_t ROFF[4] = {0, 16*49ull, 16*(49+196ull), 16*(49+196+784ull)};

  bf16 *fbf[4], *pT[4], *pbf[4], *projT, *PTbuf;
  float *qkvl_bias, *kvx_bias, *ff_bias, *lat, *headtmp, *svv, *bwv, *pbuf;
  float2 *rstats;
  float *opart, *mlpart;
  bf16 *qkvl_act, *attnout, *zlat, *latbf, *ffh;
  bf16 *wqkvlT = nullptr, *wkvxT = nullptr, *woT = nullptr, *w1T = nullptr, *w2T = nullptr;
  bf16 *wbuf = nullptr;
  char *big;

  auto assign = [&](bool fullw, int bc) -> size_t {
    size_t off = 0; char* base = (char*)d_ws;
    auto A = [&](size_t b) -> char* {
      char* p = base + off; off = (off + b + 255) & ~(size_t)255; return p;
    };
    for (int i = 0; i < 4; ++i) fbf[i] = (bf16*)A((size_t)16 * N1S[i] * FRDS[i] * 2);
    for (int i = 0; i < 4; ++i) pT[i]  = (bf16*)A((size_t)768 * FRDS[i] * 2);
    for (int i = 0; i < 4; ++i) pbf[i] = (bf16*)A((size_t)FRDS[i] * 768 * 2);
    projT     = (bf16*)A(768ull * 768 * 2);
    PTbuf     = (bf16*)A(2048ull * 512 * 2);
    qkvl_bias = (float*)A(24ull * 3072 * 4);
    kvx_bias  = (float*)A(24ull * 2048 * 4);
    ff_bias   = (float*)A(6ull * 3072 * 4);
    svv       = (float*)A(24ull * 2048 * 4);
    bwv       = (float*)A(24ull * 2048 * 4);
    pbuf      = (float*)A(4ull * 8 * 24 * 2048 * 4);
    rstats    = (float2*)A(16ull * 4165 * 8);
    qkvl_act  = (bf16*)A(1024ull * 3072 * 2);
    attnout   = (bf16*)A(1024ull * 1024 * 2);
    lat       = (float*)A(1024ull * 768 * 4);
    zlat      = (bf16*)A(1024ull * 768 * 2);
    opart     = (float*)A(4ull * (size_t)bc * 64 * 1024 * 4);
    mlpart    = (float*)A(4ull * (size_t)bc * 64 * 16 * 2 * 4);
    if (fullw) {
      wqkvlT = (bf16*)A(24ull * 3072 * 768 * 2);
      wkvxT  = (bf16*)A(24ull * 2048 * 768 * 2);
      woT    = (bf16*)A(24ull * 768 * 1024 * 2);
      w1T    = (bf16*)A(6ull * 3072 * 768 * 2);
      w2T    = (bf16*)A(6ull * 768 * 3072 * 2);
      wbuf = nullptr;
    } else {
      wbuf = (bf16*)A(4ull * LW * 2);
      wqkvlT = wkvxT = woT = w1T = w2T = nullptr;
    }
    big = A((size_t)bc * 3136 * 2048 * 2);
    ffh = qkvl_act; headtmp = (float*)qkvl_act; latbf = zlat;
    return off;
  };

  static const bool FULLS[10] = {true,true,false,true,false,true,true,false,false,false};
  static const int  BCS[10]   = {16,  8,   16,   4,   8,    2,   1,   4,    2,    1};
  bool fullw = false; int bc = 1; bool ok = false;
  for (int c = 0; c < 10; ++c) {
    if (assign(FULLS[c], BCS[c]) <= ws_size) { fullw = FULLS[c]; bc = BCS[c]; ok = true; break; }
  }
  if (!ok) return;

  float* featf32 = (float*)big;
  bf16*  kvxbuf  = (bf16*)big;

  auto gemm = [&](int tile, const bf16* A, const bf16* Bt, void* C,
                  const float* bias, const float* res, int M, int N, int K,
                  bool obf, bool gl) {
    if (tile == 128) {
      int nxt = N / 128, nwg = nxt * ((M + 127) / 128);
      if (obf && gl) k_gemm<128,128,true ,true ,false><<<nwg,256,0,stream>>>(A,Bt,C,bias,res,nullptr,nullptr,nullptr,M,N,K,nxt,nwg);
      else if (obf)  k_gemm<128,128,true ,false,false><<<nwg,256,0,stream>>>(A,Bt,C,bias,res,nullptr,nullptr,nullptr,M,N,K,nxt,nwg);
      else           k_gemm<128,128,false,false,false><<<nwg,256,0,stream>>>(A,Bt,C,bias,res,nullptr,nullptr,nullptr,M,N,K,nxt,nwg);
    } else if (tile == 64) {
      int nxt = N / 64, nwg = nxt * ((M + 63) / 64);
      if (obf && gl)  k_gemm<64,64,true ,true ,false><<<nwg,256,0,stream>>>(A,Bt,C,bias,res,nullptr,nullptr,nullptr,M,N,K,nxt,nwg);
      else if (obf)   k_gemm<64,64,true ,false,false><<<nwg,256,0,stream>>>(A,Bt,C,bias,res,nullptr,nullptr,nullptr,M,N,K,nxt,nwg);
      else            k_gemm<64,64,false,false,false><<<nwg,256,0,stream>>>(A,Bt,C,bias,res,nullptr,nullptr,nullptr,M,N,K,nxt,nwg);
    } else {
      int nxt = N / 64, nwg = nxt * ((M + 31) / 32);
      if (obf && gl)  k_gemm<32,64,true ,true ,false><<<nwg,256,0,stream>>>(A,Bt,C,bias,res,nullptr,nullptr,nullptr,M,N,K,nxt,nwg);
      else if (obf)   k_gemm<32,64,true ,false,false><<<nwg,256,0,stream>>>(A,Bt,C,bias,res,nullptr,nullptr,nullptr,M,N,K,nxt,nwg);
      else            k_gemm<32,64,false,false,false><<<nwg,256,0,stream>>>(A,Bt,C,bias,res,nullptr,nullptr,nullptr,M,N,K,nxt,nwg);
    }
  };
  auto gemmkv = [&](const bf16* A, const bf16* Bt, void* C,
                    const float* lb, const float2* rst, const float* c1, const float* cs,
                    int M, int N, int K) {
    if (M >= 2048) {
      int nxt = N / 128, nwg = nxt * ((M + 127) / 128);
      k_gemm<128,128,true,false,true><<<nwg,256,0,stream>>>(A,Bt,C,lb,nullptr,rst,c1,cs,M,N,K,nxt,nwg);
    } else {
      int nxt = N / 64, nwg = nxt * ((M + 63) / 64);
      k_gemm<64,64,true,false,true><<<nwg,256,0,stream>>>(A,Bt,C,lb,nullptr,rst,c1,cs,M,N,K,nxt,nwg);
    }
  };
  auto pick = [&](int M, int N) -> int {
    return M >= 2048 ? 128 : (N >= 1536 ? 64 : 32);
  };

  // ---- bias folds + merged kv fold (K-split, then reduce) ----
  k_bfoldv<<<dim3(4, 24), 256, 0, stream>>>(wq,  ln2b, qkvl_bias, 768, 1024, 768LL*1024, 768, 3072);
  k_kvfold<<<dim3(8, 24, 8), 256, 0, stream>>>(wkv, ln2b, ln1b, ln1w,
                                               pb_in[0], pb_in[1], pb_in[2], pb_in[3], pbuf);
  k_kvred<<<dim3(8, 24), 256, 0, stream>>>(pbuf, qkvl_bias, kvx_bias, svv, bwv);
  k_bfoldv<<<dim3(12, 6), 256, 0, stream>>>(ffw1, fflnb, ff_bias, 768, 3072, 768LL*3072, 768, 3072);

  // ---- small folded weights ----
  for (int i = 0; i < 4; ++i) {
    k_tfoldx<false><<<dim3(12, FRDS[i] / 64, 1), 256, 0, stream>>>(
        pw_in[i], nullptr, nullptr, pT[i], nullptr, FRDS[i], 768, 0, 0, 0, 0);
    int cnt = FRDS[i] * 768;
    k_cvt<<<cnt / 1024, 256, 0, stream>>>(pw_in[i], pbf[i], cnt / 4);
  }
  k_tfoldx<false><<<dim3(12, 12, 1), 256, 0, stream>>>(
      projw, nullptr, nullptr, projT, nullptr, 768, 768, 0, 0, 0, 0);

  // ---- full-mode weight folds ----
  if (fullw) {
    k_tfoldx<false><<<dim3(16, 12, 24), 256, 0, stream>>>(
        wq, ln2w, nullptr, wqkvlT, nullptr, 768, 1024, 768LL*1024, 768, 3072LL*768, 0);
    k_tfoldx<true><<<dim3(32, 12, 24), 256, 0, stream>>>(
        wkv, ln2w, ln1w, wqkvlT + 1024LL*768, wkvxT, 768, 2048,
        768LL*2048, 768, 3072LL*768, 2048LL*768);
    k_tfoldx<false><<<dim3(12, 16, 24), 256, 0, stream>>>(
        wo, nullptr, nullptr, woT, nullptr, 1024, 768, 1024LL*768, 0, 768LL*1024, 0);
    k_tfoldx<false><<<dim3(48, 12, 6), 256, 0, stream>>>(
        ffw1, fflnw, nullptr, w1T, nullptr, 768, 3072, 768LL*3072, 768, 3072LL*768, 0);
    k_tfoldx<false><<<dim3(12, 48, 6), 256, 0, stream>>>(
        ffw2, nullptr, nullptr, w2T, nullptr, 3072, 768, 3072LL*768, 0, 768LL*3072, 0);
  }

  auto foldDepthAttn = [&](int d) {
    k_tfoldx<false><<<dim3(16, 12, 4), 256, 0, stream>>>(
        wq + (size_t)d*4*768*1024, ln2w + (size_t)d*4*768, nullptr,
        wbuf, nullptr, 768, 1024, 768LL*1024, 768, (long long)LW, 0);
    k_tfoldx<true><<<dim3(32, 12, 4), 256, 0, stream>>>(
        wkv + (size_t)d*4*768*2048, ln2w + (size_t)d*4*768, ln1w + (size_t)d*4*768,
        wbuf + 1024ull*768, wbuf + 3072ull*768, 768, 2048,
        768LL*2048, 768, (long long)LW, (long long)LW);
    k_tfoldx<false><<<dim3(12, 16, 4), 256, 0, stream>>>(
        wo + (size_t)d*4*1024*768, nullptr, nullptr,
        wbuf + 3932160ull, nullptr, 1024, 768, 1024LL*768, 0, (long long)LW, 0);
  };
  auto attnW = [&](int di, const bf16*& qkvlT_p, const bf16*& kvxT_p, const bf16*& woT_p) {
    if (fullw) {
      qkvlT_p = wqkvlT + (size_t)di * 3072 * 768;
      kvxT_p  = wkvxT  + (size_t)di * 2048 * 768;
      woT_p   = woT    + (size_t)di * 768 * 1024;
    } else {
      bf16* base = wbuf + (size_t)(di & 3) * LW;
      qkvlT_p = base;
      kvxT_p  = base + 2359296ull;
      woT_p   = base + 3932160ull;
    }
  };
  auto ffW = [&](int d, const bf16*& w1p, const bf16*& w2p) {
    if (fullw) {
      w1p = w1T + (size_t)d * 3072 * 768;
      w2p = w2T + (size_t)d * 768 * 3072;
    } else {
      bf16* d1 = wbuf;
      bf16* d2 = wbuf + 3072ull * 768;
      k_tfoldx<false><<<dim3(48, 12, 1), 256, 0, stream>>>(
          ffw1 + (size_t)d*768*3072, fflnw + 768ull*d, nullptr, d1, nullptr,
          768, 3072, 0, 0, 0, 0);
      k_tfoldx<false><<<dim3(12, 48, 1), 256, 0, stream>>>(
          ffw2 + (size_t)d*3072*768, nullptr, nullptr, d2, nullptr,
          3072, 768, 0, 0, 0, 0);
      w1p = d1; w2p = d2;
    }
  };

  // ---- feature projection -> row stats only ----
  for (int i = 0; i < 4; ++i) {
    int n1 = N1S[i], frd = FRDS[i];
    size_t cnt = (size_t)16 * n1 * frd;
    k_cvt<<<(int)(cnt / 1024), 256, 0, stream>>>(f_in[i], fbf[i], (int)(cnt / 4));
    for (int b0 = 0; b0 < 16; b0 += bc) {
      int rows = bc * n1;
      gemm(pick(rows, 768), fbf[i] + (size_t)b0 * n1 * frd, pT[i], featf32,
           pb_in[i], nullptr, rows, 768, frd, false, false);
      k_stats<<<rows, 256, 0, stream>>>(featf32, rstats + ROFF[i] + (size_t)b0 * n1);
    }
  }

  hipMemcpyAsync(lat, id_emb, 1024ull * 768 * 4, hipMemcpyDeviceToDevice, stream);

  // ---- depth loop ----
  for (int d = 0; d < 6; ++d) {
    if (!fullw) foldDepthAttn(d);
    for (int i = 0; i < 4; ++i) {
      int di = d * 4 + i, n1 = N1S[i], nseg = NSEG[i], frd = FRDS[i];
      const bf16 *qkvlT_p, *kvxT_p, *woT_p;
      attnW(di, qkvlT_p, kvxT_p, woT_p);
      gemm(64, kvxT_p, pbf[i], PTbuf, nullptr, nullptr, 2048, frd, 768, true, false);
      k_std<<<1024, 256, 0, stream>>>(lat, zlat);
      gemm(64, zlat, qkvlT_p, qkvl_act, qkvl_bias + 3072ull * di, nullptr,
           1024, 3072, 768, true, false);
      for (int b0 = 0; b0 < 16; b0 += bc) {
        int rows = bc * n1;
        if (i == 3) {
          // fused: K/V computed in-attn from f (FRD=64, n1 % 64 == 0)
          k_attn<true><<<bc * 16 * nseg, 256, 0, stream>>>(
              qkvl_act, kvxbuf, attnout, opart, mlpart, n1, b0, nseg, bc,
              fbf[3], PTbuf, rstats + ROFF[3],
              bwv + 2048ull * di, svv + 2048ull * di, kvx_bias + 2048ull * di);
        } else {
          gemmkv(fbf[i] + (size_t)b0 * n1 * frd, PTbuf, kvxbuf,
                 kvx_bias + 2048ull * di, rstats + ROFF[i] + (size_t)b0 * n1,
                 bwv + 2048ull * di, svv + 2048ull * di, rows, 2048, frd);
          k_attn<false><<<bc * 16 * nseg, 256, 0, stream>>>(
              qkvl_act, kvxbuf, attnout, opart, mlpart, n1, b0, nseg, bc,
              nullptr, nullptr, nullptr, nullptr, nullptr, nullptr);
        }
        if (nseg > 1)
          k_amerge<<<bc * 16, 256, 0, stream>>>(opart, mlpart, attnout, b0, nseg, bc);
      }
      gemm(32, attnout, woT_p, lat, nullptr, lat, 1024, 768, 1024, false, false);
    }
    const bf16 *w1p, *w2p;
    ffW(d, w1p, w2p);
    k_std<<<1024, 256, 0, stream>>>(lat, zlat);
    gemm(64, zlat, w1p, ffh, ff_bias + 3072ull * d, nullptr, 1024, 3072, 768, true, true);
    gemm(32, ffh, w2p, lat, nullptr, lat, 1024, 768, 3072, false, false);
  }

  // ---- head ----
  k_cvt<<<768, 256, 0, stream>>>(lat, latbf, 196608);
  gemm(32, latbf, projT, headtmp, projb, nullptr, 1024, 768, 768, false, false);
  k_lnout<<<1024, 256, 0, stream>>>(headtmp, normw, normb, (float*)d_out);
}

// Round 12
// 2632.415 us; speedup vs baseline: 2.5701x; 1.1212x over previous
//
#include <hip/hip_runtime.h>
#include <hip/hip_bf16.h>
#include <cstdint>
#include <cstddef>

typedef __hip_bfloat16 bf16;
typedef float  f32x4   __attribute__((ext_vector_type(4)));
typedef float  float4v __attribute__((ext_vector_type(4)));
typedef short  short8  __attribute__((ext_vector_type(8)));
typedef short  short4v __attribute__((ext_vector_type(4)));
typedef __bf16 bf16x8  __attribute__((ext_vector_type(8)));

__device__ __forceinline__ void mfma16(f32x4& d, short8 a, short8 b) {
  d = __builtin_amdgcn_mfma_f32_16x16x32_bf16(
      __builtin_bit_cast(bf16x8, a), __builtin_bit_cast(bf16x8, b), d, 0, 0, 0);
}
__device__ __forceinline__ unsigned short f2b_bits(float x) {
  __hip_bfloat16 h = __float2bfloat16(x);
  return __builtin_bit_cast(unsigned short, h);
}
__device__ __forceinline__ float gelu_exact(float x) {
  return 0.5f * x * (1.0f + erff(x * 0.7071067811865475f));
}

// ---------- f32 -> bf16 convert ----------
__global__ __launch_bounds__(256) void k_cvt(const float* __restrict__ src,
                                             bf16* __restrict__ dst, int n4) {
  int i = blockIdx.x * 256 + threadIdx.x;
  if (i >= n4) return;
  float4v v = *(const float4v*)(src + (size_t)i * 4);
  short4v s;
  s[0] = (short)f2b_bits(v[0]); s[1] = (short)f2b_bits(v[1]);
  s[2] = (short)f2b_bits(v[2]); s[3] = (short)f2b_bits(v[3]);
  *(short4v*)((short*)dst + (size_t)i * 4) = s;
}

// ---------- transpose-fold x ----------
template <bool DUAL>
__global__ __launch_bounds__(256) void k_tfoldx(const float* __restrict__ src,
                                                const float* __restrict__ s1,
                                                const float* __restrict__ s2,
                                                bf16* __restrict__ d1,
                                                bf16* __restrict__ d2,
                                                int K, int N,
                                                long long src_bs, long long s_bs,
                                                long long d1_bs, long long d2_bs) {
  src += (size_t)blockIdx.z * src_bs;
  d1  += (size_t)blockIdx.z * d1_bs;
  if (DUAL) d2 += (size_t)blockIdx.z * d2_bs;
  __shared__ float tile[64][65];
  __shared__ float sc1[64], sc2[64];
  const int n0 = blockIdx.x * 64, k0 = blockIdx.y * 64;
  const int t = threadIdx.x;
  if (t < 64) {
    sc1[t] = s1 ? (s1 + (size_t)blockIdx.z * s_bs)[k0 + t] : 1.0f;
  } else if (DUAL && t < 128) {
    sc2[t - 64] = (s2 + (size_t)blockIdx.z * s_bs)[k0 + t - 64];
  }
#pragma unroll
  for (int j = 0; j < 4; ++j) {
    int f = t + j * 256;
    int row = f >> 4, col = (f & 15) * 4;
    float4v v = *(const float4v*)(src + (size_t)(k0 + row) * N + n0 + col);
    tile[row][col]     = v[0];
    tile[row][col + 1] = v[1];
    tile[row][col + 2] = v[2];
    tile[row][col + 3] = v[3];
  }
  __syncthreads();
#pragma unroll
  for (int j = 0; j < 2; ++j) {
    int s = t + j * 256;
    int n = s >> 3, kc = (s & 7) * 8;
    short8 o1v, o2v;
#pragma unroll
    for (int i = 0; i < 8; ++i) {
      float v = tile[kc + i][n];
      o1v[i] = (short)f2b_bits(v * sc1[kc + i]);
      if (DUAL) o2v[i] = (short)f2b_bits(v * sc2[kc + i]);
    }
    *(short8*)(d1 + (size_t)(n0 + n) * K + k0 + kc) = o1v;
    if (DUAL) *(short8*)(d2 + (size_t)(n0 + n) * K + k0 + kc) = o2v;
  }
}

// ---------- K-split bias fold: partials[(kz*NB+by)*N + n] ----------
__global__ __launch_bounds__(256) void k_bfoldz(const float* __restrict__ W,
                                                const float* __restrict__ b,
                                                float* __restrict__ pbuf, int K, int N,
                                                long long w_bs, long long b_bs) {
  W += (size_t)blockIdx.y * w_bs;
  b += (size_t)blockIdx.y * b_bs;
  const int kz = blockIdx.z, kpz = K >> 3;
  __shared__ float sb[96];
  if ((int)threadIdx.x < kpz) sb[threadIdx.x] = b[kz * kpz + threadIdx.x];
  __syncthreads();
  const int lane = threadIdx.x & 63, kg = threadIdx.x >> 6;
  const int n = blockIdx.x * 256 + lane * 4;
  float4v a = {0.f, 0.f, 0.f, 0.f};
  for (int kk = kg; kk < kpz; kk += 4) {
    float4v wv = *(const float4v*)(W + (size_t)(kz * kpz + kk) * N + n);
    float c = sb[kk];
    a[0] = fmaf(c, wv[0], a[0]); a[1] = fmaf(c, wv[1], a[1]);
    a[2] = fmaf(c, wv[2], a[2]); a[3] = fmaf(c, wv[3], a[3]);
  }
  __shared__ float4v red[4][64];
  red[kg][lane] = a;
  __syncthreads();
  if (kg == 0) {
    float4v r = red[0][lane] + red[1][lane] + red[2][lane] + red[3][lane];
    *(float4v*)(pbuf + ((size_t)kz * gridDim.y + blockIdx.y) * N + n) = r;
  }
}

// ---------- reduce bias-fold partials ----------
__global__ __launch_bounds__(256) void k_bred(const float* __restrict__ pbuf,
                                              float* __restrict__ out, int N, int NB,
                                              long long o_bs) {
  const int by = blockIdx.y;
  const int n = blockIdx.x * 256 + threadIdx.x;
  float a = 0.f;
  for (int kz = 0; kz < 8; ++kz) a += pbuf[((size_t)kz * NB + by) * N + n];
  out[(size_t)by * o_bs + n] = a;
}

// ---------- merged kv fold, K-split (z=8) ----------
__global__ __launch_bounds__(256) void k_kvfold(const float* __restrict__ wkv,
                                                const float* __restrict__ ln2b,
                                                const float* __restrict__ ln1b,
                                                const float* __restrict__ ln1w,
                                                const float* __restrict__ b0,
                                                const float* __restrict__ b1,
                                                const float* __restrict__ b2,
                                                const float* __restrict__ b3,
                                                float* __restrict__ pbuf) {
  const int di = blockIdx.y;
  const int kz = blockIdx.z;
  const int i = di & 3;
  const float* pb = (i == 0) ? b0 : (i == 1) ? b1 : (i == 2) ? b2 : b3;
  const float* W = wkv + (size_t)di * 768 * 2048;
  __shared__ float c2b[96], c1b[96], c1w[96], cpw[96];
  if (threadIdx.x < 96) {
    int k = kz * 96 + threadIdx.x;
    float w1 = ln1w[(size_t)di * 768 + k];
    c2b[threadIdx.x] = ln2b[(size_t)di * 768 + k];
    c1b[threadIdx.x] = ln1b[(size_t)di * 768 + k];
    c1w[threadIdx.x] = w1;
    cpw[threadIdx.x] = pb[k] * w1;
  }
  __syncthreads();
  const int lane = threadIdx.x & 63, kg = threadIdx.x >> 6;
  const int n = blockIdx.x * 256 + lane * 4;
  float4v a1 = {0.f,0.f,0.f,0.f}, a2 = a1, a3 = a1, a4 = a1;
  for (int kk = kg; kk < 96; kk += 4) {
    float4v wv = *(const float4v*)(W + (size_t)(kz * 96 + kk) * 2048 + n);
    float s1 = c2b[kk], s2 = c1b[kk], s3 = c1w[kk], s4 = cpw[kk];
#pragma unroll
    for (int q = 0; q < 4; ++q) {
      a1[q] = fmaf(s1, wv[q], a1[q]);
      a2[q] = fmaf(s2, wv[q], a2[q]);
      a3[q] = fmaf(s3, wv[q], a3[q]);
      a4[q] = fmaf(s4, wv[q], a4[q]);
    }
  }
  __shared__ float4v red[4][64];
  red[kg][lane] = a1; __syncthreads();
  if (kg == 0) {
    float4v r = red[0][lane] + red[1][lane] + red[2][lane] + red[3][lane];
    *(float4v*)(pbuf + (((size_t)0 * 8 + kz) * 24 + di) * 2048 + n) = r;
  }
  __syncthreads();
  red[kg][lane] = a2; __syncthreads();
  if (kg == 0) {
    float4v r = red[0][lane] + red[1][lane] + red[2][lane] + red[3][lane];
    *(float4v*)(pbuf + (((size_t)1 * 8 + kz) * 24 + di) * 2048 + n) = r;
  }
  __syncthreads();
  red[kg][lane] = a3; __syncthreads();
  if (kg == 0) {
    float4v r = red[0][lane] + red[1][lane] + red[2][lane] + red[3][lane];
    *(float4v*)(pbuf + (((size_t)2 * 8 + kz) * 24 + di) * 2048 + n) = r;
  }
  __syncthreads();
  red[kg][lane] = a4; __syncthreads();
  if (kg == 0) {
    float4v r = red[0][lane] + red[1][lane] + red[2][lane] + red[3][lane];
    *(float4v*)(pbuf + (((size_t)3 * 8 + kz) * 24 + di) * 2048 + n) = r;
  }
}

// ---------- reduce kv fold partials ----------
__global__ __launch_bounds__(256) void k_kvred(const float* __restrict__ pbuf,
                                               float* __restrict__ qb,
                                               float* __restrict__ kb,
                                               float* __restrict__ sv,
                                               float* __restrict__ bw) {
  const int di = blockIdx.y;
  const int n = blockIdx.x * 256 + threadIdx.x;
  float a0 = 0.f, a1 = 0.f, a2 = 0.f, a3 = 0.f;
  for (int kz = 0; kz < 8; ++kz) {
    a0 += pbuf[(((size_t)0 * 8 + kz) * 24 + di) * 2048 + n];
    a1 += pbuf[(((size_t)1 * 8 + kz) * 24 + di) * 2048 + n];
    a2 += pbuf[(((size_t)2 * 8 + kz) * 24 + di) * 2048 + n];
    a3 += pbuf[(((size_t)3 * 8 + kz) * 24 + di) * 2048 + n];
  }
  qb[(size_t)di * 3072 + 1024 + n] = a0;
  kb[(size_t)di * 2048 + n] = a1;
  sv[(size_t)di * 2048 + n] = a2;
  bw[(size_t)di * 2048 + n] = a3;
}

// ---------- row standardize (768-wide), f32 -> bf16 ----------
__global__ __launch_bounds__(256) void k_std(const float* __restrict__ src,
                                             bf16* __restrict__ dst) {
  int row = blockIdx.x;
  const float* x = src + (size_t)row * 768;
  int t = threadIdx.x;
  float a0 = x[t], a1 = x[t + 256], a2 = x[t + 512];
  float s = a0 + a1 + a2;
  float q = a0 * a0 + a1 * a1 + a2 * a2;
#pragma unroll
  for (int off = 1; off < 64; off <<= 1) { s += __shfl_xor(s, off); q += __shfl_xor(q, off); }
  __shared__ float ss[4], qs[4];
  if ((t & 63) == 0) { ss[t >> 6] = s; qs[t >> 6] = q; }
  __syncthreads();
  s = ss[0] + ss[1] + ss[2] + ss[3];
  q = qs[0] + qs[1] + qs[2] + qs[3];
  float mean = s * (1.0f / 768.0f);
  float var  = q * (1.0f / 768.0f) - mean * mean;
  float inv  = rsqrtf(var + 1e-5f);
  bf16* d = dst + (size_t)row * 768;
  d[t]       = __float2bfloat16((a0 - mean) * inv);
  d[t + 256] = __float2bfloat16((a1 - mean) * inv);
  d[t + 512] = __float2bfloat16((a2 - mean) * inv);
}

// ---------- row stats only ----------
__global__ __launch_bounds__(256) void k_stats(const float* __restrict__ src,
                                               float2* __restrict__ out) {
  int row = blockIdx.x;
  const float* x = src + (size_t)row * 768;
  int t = threadIdx.x;
  float a0 = x[t], a1 = x[t + 256], a2 = x[t + 512];
  float s = a0 + a1 + a2;
  float q = a0 * a0 + a1 * a1 + a2 * a2;
#pragma unroll
  for (int off = 1; off < 64; off <<= 1) { s += __shfl_xor(s, off); q += __shfl_xor(q, off); }
  __shared__ float ss[4], qs[4];
  if ((t & 63) == 0) { ss[t >> 6] = s; qs[t >> 6] = q; }
  __syncthreads();
  if (t == 0) {
    float sm = ss[0] + ss[1] + ss[2] + ss[3];
    float qm = qs[0] + qs[1] + qs[2] + qs[3];
    float mean = sm * (1.0f / 768.0f);
    float var  = qm * (1.0f / 768.0f) - mean * mean;
    float inv  = rsqrtf(var + 1e-5f);
    out[row] = make_float2(inv, mean * inv);
  }
}

// ---------- final layernorm ----------
__global__ __launch_bounds__(256) void k_lnout(const float* __restrict__ src,
                                               const float* __restrict__ w,
                                               const float* __restrict__ b,
                                               float* __restrict__ dst) {
  int row = blockIdx.x;
  const float* x = src + (size_t)row * 768;
  int t = threadIdx.x;
  float a0 = x[t], a1 = x[t + 256], a2 = x[t + 512];
  float s = a0 + a1 + a2;
  float q = a0 * a0 + a1 * a1 + a2 * a2;
#pragma unroll
  for (int off = 1; off < 64; off <<= 1) { s += __shfl_xor(s, off); q += __shfl_xor(q, off); }
  __shared__ float ss[4], qs[4];
  if ((t & 63) == 0) { ss[t >> 6] = s; qs[t >> 6] = q; }
  __syncthreads();
  s = ss[0] + ss[1] + ss[2] + ss[3];
  q = qs[0] + qs[1] + qs[2] + qs[3];
  float mean = s * (1.0f / 768.0f);
  float var  = q * (1.0f / 768.0f) - mean * mean;
  float inv  = rsqrtf(var + 1e-5f);
  float* d = dst + (size_t)row * 768;
  d[t]       = (a0 - mean) * inv * w[t]       + b[t];
  d[t + 256] = (a1 - mean) * inv * w[t + 256] + b[t + 256];
  d[t + 512] = (a2 - mean) * inv * w[t + 512] + b[t + 512];
}

// ---------- MFMA GEMM (reg-staged pipeline + XCD swizzle + z-batch strides) ----------
template <int BM, int BN, bool OBF16, bool GELU, bool KVE>
__global__ __launch_bounds__(256) void k_gemm(const bf16* __restrict__ A,
                                              const bf16* __restrict__ Bt,
                                              void* __restrict__ Cv,
                                              const float* __restrict__ bias,
                                              const float* __restrict__ res,
                                              const float2* __restrict__ rstats,
                                              const float* __restrict__ c1,
                                              const float* __restrict__ cs,
                                              int M, int N, int K,
                                              long long azb, long long czb,
                                              int nxt, int nwg) {
  constexpr int AI = BM / 32, BI = BN / 32;
  constexpr int MF = BM / 32, NF = BN / 32;
  __shared__ __align__(16) char smem[(BM + BN) * 128];
  char* As = smem;
  char* Bs = smem + BM * 128;

  A  = (const bf16*)((const char*)A + (size_t)blockIdx.y * azb);
  Cv = (void*)((char*)Cv + (size_t)blockIdx.y * czb);

  const int lin = blockIdx.x;
  const int qq = nwg >> 3, r8 = nwg & 7;
  const int xcd = lin & 7, idx = lin >> 3;
  const int swz = (xcd < r8) ? (xcd * (qq + 1) + idx)
                             : (r8 * (qq + 1) + (xcd - r8) * qq + idx);
  const int bm = (swz / nxt) * BM, bn = (swz % nxt) * BN;

  const int t = threadIdx.x, lane = t & 63, w = t >> 6;
  const int wr = w >> 1, wc = w & 1;
  const int l15 = lane & 15, lg = lane >> 4;
  const int srow = t >> 3, scol = t & 7;

  const bf16* aptr[AI]; int aoff[AI];
#pragma unroll
  for (int i = 0; i < AI; ++i) {
    int r = i * 32 + srow;
    int gr = bm + r; if (gr > M - 1) gr = M - 1;
    aptr[i] = A + (size_t)gr * K + scol * 8;
    aoff[i] = r * 128 + ((scol * 16) ^ ((r & 7) << 4));
  }
  const bf16* bptr[BI]; int boff[BI];
#pragma unroll
  for (int i = 0; i < BI; ++i) {
    int r = i * 32 + srow;
    int gc = bn + r; if (gc > N - 1) gc = N - 1;
    bptr[i] = Bt + (size_t)gc * K + scol * 8;
    boff[i] = r * 128 + ((scol * 16) ^ ((r & 7) << 4));
  }

  f32x4 acc[MF][NF] = {};
  short8 av[AI], bv[BI];
#pragma unroll
  for (int i = 0; i < AI; ++i) av[i] = *(const short8*)(aptr[i]);
#pragma unroll
  for (int i = 0; i < BI; ++i) bv[i] = *(const short8*)(bptr[i]);

  const int nk = K / 64;
  for (int kt = 0; kt < nk; ++kt) {
    __syncthreads();
#pragma unroll
    for (int i = 0; i < AI; ++i) *(short8*)(As + aoff[i]) = av[i];
#pragma unroll
    for (int i = 0; i < BI; ++i) *(short8*)(Bs + boff[i]) = bv[i];
    __syncthreads();
    if (kt + 1 < nk) {
#pragma unroll
      for (int i = 0; i < AI; ++i) av[i] = *(const short8*)(aptr[i] + (size_t)(kt + 1) * 64);
#pragma unroll
      for (int i = 0; i < BI; ++i) bv[i] = *(const short8*)(bptr[i] + (size_t)(kt + 1) * 64);
    }
#pragma unroll
    for (int ks = 0; ks < 2; ++ks) {
      short8 af[MF], bfr[NF];
#pragma unroll
      for (int m = 0; m < MF; ++m) {
        int r = wr * (BM / 2) + m * 16 + l15;
        af[m] = *(const short8*)(As + r * 128 + ((ks * 64 + lg * 16) ^ ((r & 7) << 4)));
      }
#pragma unroll
      for (int n = 0; n < NF; ++n) {
        int r = wc * (BN / 2) + n * 16 + l15;
        bfr[n] = *(const short8*)(Bs + r * 128 + ((ks * 64 + lg * 16) ^ ((r & 7) << 4)));
      }
#pragma unroll
      for (int m = 0; m < MF; ++m)
#pragma unroll
        for (int n = 0; n < NF; ++n) mfma16(acc[m][n], af[m], bfr[n]);
    }
  }

  if (OBF16) {
    __syncthreads();
    bf16* cst = (bf16*)smem;
#pragma unroll
    for (int m = 0; m < MF; ++m) {
      int lr0 = wr * (BM / 2) + m * 16 + lg * 4;
#pragma unroll
      for (int n = 0; n < NF; ++n) {
        int lc = wc * (BN / 2) + n * 16 + l15;
        int gc = bn + lc;
        float bvs = bias ? bias[gc] : 0.0f;
        float c1v = 0.0f, csv = 0.0f;
        if (KVE) { c1v = c1[gc]; csv = cs[gc]; }
#pragma unroll
        for (int r = 0; r < 4; ++r) {
          int row = lr0 + r;
          float v;
          if (KVE) {
            int gri = bm + row; if (gri > M - 1) gri = M - 1;
            float2 st = rstats[gri];
            v = (acc[m][n][r] + c1v) * st.x - st.y * csv + bvs;
          } else {
            v = acc[m][n][r] + bvs;
            if (GELU) v = gelu_exact(v);
          }
          cst[row * BN + lc] = __float2bfloat16(v);
        }
      }
    }
    __syncthreads();
    constexpr int CB = BN / 8;
    constexpr int SEGS = BM * CB;
    for (int seg = t; seg < SEGS; seg += 256) {
      int row = seg / CB, cb = seg % CB;
      int gr = bm + row;
      if (gr < M)
        *(short8*)((bf16*)Cv + (size_t)gr * N + bn + cb * 8) =
            *(const short8*)(cst + (size_t)row * BN + cb * 8);
    }
  } else {
#pragma unroll
    for (int m = 0; m < MF; ++m) {
      int gr0 = bm + wr * (BM / 2) + m * 16 + lg * 4;
#pragma unroll
      for (int n = 0; n < NF; ++n) {
        int gc = bn + wc * (BN / 2) + n * 16 + l15;
        float bvs = bias ? bias[gc] : 0.0f;
#pragma unroll
        for (int r = 0; r < 4; ++r) {
          int gr = gr0 + r;
          if (gr < M) {
            float v = acc[m][n][r] + bvs;
            if (GELU) v = gelu_exact(v);
            if (res) v += res[(size_t)gr * N + gc];
            ((float*)Cv)[(size_t)gr * N + gc] = v;
          }
        }
      }
    }
  }
}

// ---------- fused attention, split-KV + swapped-QK^T softmax ----------
template <bool FUSED>
__global__ __launch_bounds__(256) void k_attn(const bf16* __restrict__ qkvl,
                                              const bf16* __restrict__ kvx,
                                              bf16* __restrict__ outp,
                                              float* __restrict__ opart,
                                              float* __restrict__ mlpart,
                                              int n1, int b0, int nseg, int nbloc,
                                              const bf16* __restrict__ fsrc,
                                              const bf16* __restrict__ PT,
                                              const float2* __restrict__ rst,
                                              const float* __restrict__ c1vec,
                                              const float* __restrict__ csvec,
                                              const float* __restrict__ lbvec) {
  const int s   = blockIdx.x % nseg;
  const int bh  = blockIdx.x / nseg;
  const int bl = bh >> 4, h = bh & 15;
  const int b = b0 + bl;
  const int nb64 = nbloc * 64;
  __shared__ __align__(16) char Qs[64 * 128];
  __shared__ __align__(16) char Ks[64 * 128];
  __shared__ __align__(16) char Vt[64 * 128];
  __shared__ __align__(16) char Ps[4][16 * 128];
  __shared__ __align__(16) char Fs[FUSED ? 64 * 128 : 16];
  __shared__ __align__(16) char PTks[FUSED ? 64 * 128 : 16];
  __shared__ __align__(16) char PTvs[FUSED ? 64 * 128 : 16];
  __shared__ float2 Rs[FUSED ? 64 : 1];
  const int t = threadIdx.x, lane = t & 63, w = t >> 6;
  const int l15 = lane & 15, lg = lane >> 4;

#pragma unroll
  for (int it = 0; it < 2; ++it) {
    int slot = it * 256 + t; int r = slot >> 3, c = slot & 7;
    short8 v = *(const short8*)(qkvl + (size_t)(b * 64 + r) * 3072 + h * 64 + c * 8);
    *(short8*)(Qs + r * 128 + ((c * 16) ^ ((r & 7) << 4))) = v;
  }
  float c1k[4], csk[4], lbk[4], c1v_[4], csv_[4], lbv_[4];
  if constexpr (FUSED) {
#pragma unroll
    for (int it = 0; it < 2; ++it) {
      int slot = it * 256 + t; int r = slot >> 3, c = slot & 7;
      *(short8*)(PTks + r * 128 + ((c * 16) ^ ((r & 7) << 4))) =
          *(const short8*)(PT + (size_t)(h * 64 + r) * 64 + c * 8);
      *(short8*)(PTvs + r * 128 + ((c * 16) ^ ((r & 7) << 4))) =
          *(const short8*)(PT + (size_t)(1024 + h * 64 + r) * 64 + c * 8);
    }
#pragma unroll
    for (int n = 0; n < 4; ++n) {
      int dk = h * 64 + n * 16 + l15;
      c1k[n] = c1vec[dk]; csk[n] = csvec[dk]; lbk[n] = lbvec[dk];
      int dv = 1024 + dk;
      c1v_[n] = c1vec[dv]; csv_[n] = csvec[dv]; lbv_[n] = lbvec[dv];
    }
  }
  const int n_kv = n1 + 64;
  const int nch = (n_kv + 63) >> 6;
  const int cpseg = (nch + nseg - 1) / nseg;
  const int ch0 = s * cpseg;
  const int ch1 = min(nch, ch0 + cpseg);

  float m_run = -1e30f, l_run = 0.0f;
  f32x4 o[4] = {};

  short8 kreg[2], vreg[2], freg[2];
  float2 rreg = make_float2(0.f, 0.f);
  auto loadKV = [&](int ch) {
#pragma unroll
    for (int it = 0; it < 2; ++it) {
      int slot = it * 256 + t; int rr = slot >> 3, c = slot & 7;
      int j = ch * 64 + rr;
      short8 kv = {}; short8 vv = {};
      if (j < n_kv) {
        const bf16* kb;
        if (j < n1) kb = kvx + (size_t)(bl * n1 + j) * 2048 + h * 64;
        else        kb = qkvl + (size_t)(b * 64 + (j - n1)) * 3072 + 1024 + h * 64;
        kv = *(const short8*)(kb + c * 8);
        vv = *(const short8*)(kb + 1024 + c * 8);
      }
      kreg[it] = kv; vreg[it] = vv;
    }
  };
  auto loadF = [&](int ch) {
#pragma unroll
    for (int it = 0; it < 2; ++it) {
      int slot = it * 256 + t; int rr = slot >> 3, c = slot & 7;
      freg[it] = *(const short8*)(fsrc + ((size_t)b * n1 + (size_t)ch * 64 + rr) * 64 + c * 8);
    }
    if (t < 64) rreg = rst[(size_t)b * n1 + (size_t)ch * 64 + t];
  };
  auto isLat = [&](int ch) { return ch * 64 >= n1; };

  if (FUSED && !isLat(ch0)) loadF(ch0); else loadKV(ch0);

  for (int ch = ch0; ch < ch1; ++ch) {
    const bool lat = !FUSED || isLat(ch);
    __syncthreads();
    if (lat) {
#pragma unroll
      for (int it = 0; it < 2; ++it) {
        int slot = it * 256 + t; int rr = slot >> 3, c = slot & 7;
        *(short8*)(Ks + rr * 128 + ((c * 16) ^ ((rr & 7) << 4))) = kreg[it];
#pragma unroll
        for (int j2 = 0; j2 < 8; ++j2) {
          int dh = c * 8 + j2;
          *(short*)(Vt + dh * 128 + ((rr * 2) ^ ((dh & 7) << 4))) = vreg[it][j2];
        }
      }
    } else {
#pragma unroll
      for (int it = 0; it < 2; ++it) {
        int slot = it * 256 + t; int rr = slot >> 3, c = slot & 7;
        *(short8*)(Fs + rr * 128 + ((c * 16) ^ ((rr & 7) << 4))) = freg[it];
      }
      if (t < 64) Rs[t] = rreg;
    }
    __syncthreads();
    if (ch + 1 < ch1) {
      if (FUSED && !isLat(ch + 1)) loadF(ch + 1); else loadKV(ch + 1);
    }
    if constexpr (FUSED) {
      if (!lat) {
        f32x4 ka[4] = {};
#pragma unroll
        for (int ks = 0; ks < 2; ++ks) {
          int fr = w * 16 + l15;
          short8 ff = *(const short8*)(Fs + fr * 128 + ((ks * 64 + lg * 16) ^ ((fr & 7) << 4)));
#pragma unroll
          for (int n = 0; n < 4; ++n) {
            int pr = n * 16 + l15;
            short8 pk = *(const short8*)(PTks + pr * 128 + ((ks * 64 + lg * 16) ^ ((pr & 7) << 4)));
            mfma16(ka[n], ff, pk);
          }
        }
#pragma unroll
        for (int n = 0; n < 4; ++n)
#pragma unroll
          for (int r = 0; r < 4; ++r) {
            int jl = w * 16 + lg * 4 + r;
            float2 st = Rs[jl];
            float v = (ka[n][r] + c1k[n]) * st.x - st.y * csk[n] + lbk[n];
            int dh = n * 16 + l15;
            *(unsigned short*)(Ks + jl * 128 + ((dh * 2) ^ ((jl & 7) << 4))) = f2b_bits(v);
          }
        f32x4 va[4] = {};
#pragma unroll
        for (int ks = 0; ks < 2; ++ks) {
          int fr = w * 16 + l15;
          short8 ff = *(const short8*)(Fs + fr * 128 + ((ks * 64 + lg * 16) ^ ((fr & 7) << 4)));
#pragma unroll
          for (int n = 0; n < 4; ++n) {
            int pr = n * 16 + l15;
            short8 pv = *(const short8*)(PTvs + pr * 128 + ((ks * 64 + lg * 16) ^ ((pr & 7) << 4)));
            mfma16(va[n], ff, pv);
          }
        }
#pragma unroll
        for (int n = 0; n < 4; ++n)
#pragma unroll
          for (int r = 0; r < 4; ++r) {
            int jl = w * 16 + lg * 4 + r;
            float2 st = Rs[jl];
            float v = (va[n][r] + c1v_[n]) * st.x - st.y * csv_[n] + lbv_[n];
            int dh = n * 16 + l15;
            *(unsigned short*)(Vt + dh * 128 + ((jl * 2) ^ ((dh & 7) << 4))) = f2b_bits(v);
          }
      }
      __syncthreads();
    }

    f32x4 sc[4] = {};
#pragma unroll
    for (int ks = 0; ks < 2; ++ks) {
      int qr = w * 16 + l15;
      short8 qf = *(const short8*)(Qs + qr * 128 + ((ks * 64 + lg * 16) ^ ((qr & 7) << 4)));
#pragma unroll
      for (int n = 0; n < 4; ++n) {
        int kr = n * 16 + l15;
        short8 kf = *(const short8*)(Ks + kr * 128 + ((ks * 64 + lg * 16) ^ ((kr & 7) << 4)));
        mfma16(sc[n], kf, qf);
      }
    }
    float mx = m_run;
#pragma unroll
    for (int n = 0; n < 4; ++n)
#pragma unroll
      for (int r = 0; r < 4; ++r) {
        float v = sc[n][r] * 0.125f;
        int kvi = ch * 64 + n * 16 + lg * 4 + r;
        if (kvi >= n_kv) v = -1e30f;
        sc[n][r] = v;
        mx = fmaxf(mx, v);
      }
    mx = fmaxf(mx, __shfl_xor(mx, 16));
    mx = fmaxf(mx, __shfl_xor(mx, 32));
    float scl = __expf(m_run - mx);
    m_run = mx;
    float p[4][4];
    float rs = 0.0f;
#pragma unroll
    for (int n = 0; n < 4; ++n)
#pragma unroll
      for (int r = 0; r < 4; ++r) { float pv = __expf(sc[n][r] - mx); p[n][r] = pv; rs += pv; }
    rs += __shfl_xor(rs, 16);
    rs += __shfl_xor(rs, 32);
    l_run = l_run * scl + rs;
    float sclq[4];
#pragma unroll
    for (int r = 0; r < 4; ++r) sclq[r] = __shfl(scl, lg * 4 + r);
#pragma unroll
    for (int nn = 0; nn < 4; ++nn)
#pragma unroll
      for (int r = 0; r < 4; ++r) o[nn][r] *= sclq[r];
#pragma unroll
    for (int n = 0; n < 4; ++n)
#pragma unroll
      for (int r = 0; r < 4; ++r) {
        int kv = n * 16 + lg * 4 + r;
        *(unsigned short*)(Ps[w] + l15 * 128 + ((kv * 2) ^ ((l15 & 7) << 4))) = f2b_bits(p[n][r]);
      }
#pragma unroll
    for (int ks = 0; ks < 2; ++ks) {
      short8 pf = *(const short8*)(Ps[w] + l15 * 128 + ((ks * 64 + lg * 16) ^ ((l15 & 7) << 4)));
#pragma unroll
      for (int nn = 0; nn < 4; ++nn) {
        int dh = nn * 16 + l15;
        short8 vf = *(const short8*)(Vt + dh * 128 + ((ks * 64 + lg * 16) ^ ((dh & 7) << 4)));
        mfma16(o[nn], pf, vf);
      }
    }
  }

  if (nseg == 1) {
    float lq[4];
#pragma unroll
    for (int r = 0; r < 4; ++r) lq[r] = __shfl(l_run, lg * 4 + r);
#pragma unroll
    for (int nn = 0; nn < 4; ++nn)
#pragma unroll
      for (int r = 0; r < 4; ++r) {
        int qr = w * 16 + lg * 4 + r;
        int dh = nn * 16 + l15;
        outp[(size_t)(b * 64 + qr) * 1024 + h * 64 + dh] = __float2bfloat16(o[nn][r] / lq[r]);
      }
  } else {
#pragma unroll
    for (int nn = 0; nn < 4; ++nn)
#pragma unroll
      for (int r = 0; r < 4; ++r) {
        int qr = w * 16 + lg * 4 + r;
        int dh = nn * 16 + l15;
        opart[((size_t)s * nb64 + bl * 64 + qr) * 1024 + h * 64 + dh] = o[nn][r];
      }
    if (lg == 0) {
      int qr = w * 16 + l15;
      size_t mi = (((size_t)s * nb64 + bl * 64 + qr) * 16 + h) * 2;
      mlpart[mi]     = m_run;
      mlpart[mi + 1] = l_run;
    }
  }
}

// ---------- merge split-KV partials ----------
__global__ __launch_bounds__(256) void k_amerge(const float* __restrict__ opart,
                                                const float* __restrict__ mlpart,
                                                bf16* __restrict__ outp,
                                                int b0, int nseg, int nbloc) {
  const int bh = blockIdx.x;
  const int bl = bh >> 4, h = bh & 15;
  const int nb64 = nbloc * 64;
  const int t = threadIdx.x;
  const int q = t >> 2, quarter = t & 3;

  float ms[8], ls[8];
  float mstar = -1e30f;
  for (int s = 0; s < nseg; ++s) {
    size_t mi = (((size_t)s * nb64 + bl * 64 + q) * 16 + h) * 2;
    ms[s] = mlpart[mi]; ls[s] = mlpart[mi + 1];
    mstar = fmaxf(mstar, ms[s]);
  }
  float L = 0.0f, ws[8];
  for (int s = 0; s < nseg; ++s) { ws[s] = __expf(ms[s] - mstar); L += ws[s] * ls[s]; }
  float inv = 1.0f / L;

  bf16* outrow = outp + (size_t)((b0 + bl) * 64 + q) * 1024 + h * 64;
#pragma unroll
  for (int jj = 0; jj < 4; ++jj) {
    int dh0 = quarter * 16 + jj * 4;
    float4v acc = {0.f, 0.f, 0.f, 0.f};
    for (int s = 0; s < nseg; ++s) {
      const float* orow = opart + ((size_t)s * nb64 + bl * 64 + q) * 1024 + h * 64 + dh0;
      float4v v = *(const float4v*)orow;
      acc[0] += ws[s] * v[0]; acc[1] += ws[s] * v[1];
      acc[2] += ws[s] * v[2]; acc[3] += ws[s] * v[3];
    }
    short4v sv;
    sv[0] = (short)f2b_bits(acc[0] * inv); sv[1] = (short)f2b_bits(acc[1] * inv);
    sv[2] = (short)f2b_bits(acc[2] * inv); sv[3] = (short)f2b_bits(acc[3] * inv);
    *(short4v*)((short*)(outrow + dh0)) = sv;
  }
}

// =========================== host ===========================
extern "C" void kernel_launch(void* const* d_in, const int* in_sizes, int n_in,
                              void* d_out, int out_size, void* d_ws, size_t ws_size,
                              hipStream_t stream) {
  (void)in_sizes; (void)n_in; (void)out_size;
  const float* id_emb = (const float*)d_in[0];
  const float* f_in[4]  = {(const float*)d_in[4],  (const float*)d_in[3],
                           (const float*)d_in[2],  (const float*)d_in[1]};
  const float* pw_in[4] = {(const float*)d_in[11], (const float*)d_in[9],
                           (const float*)d_in[7],  (const float*)d_in[5]};
  const float* pb_in[4] = {(const float*)d_in[12], (const float*)d_in[10],
                           (const float*)d_in[8],  (const float*)d_in[6]};
  const float* ln1w = (const float*)d_in[13];
  const float* ln1b = (const float*)d_in[14];
  const float* ln2w = (const float*)d_in[15];
  const float* ln2b = (const float*)d_in[16];
  const float* wq   = (const float*)d_in[17];
  const float* wkv  = (const float*)d_in[18];
  const float* wo   = (const float*)d_in[19];
  const float* fflnw = (const float*)d_in[20];
  const float* fflnb = (const float*)d_in[21];
  const float* ffw1  = (const float*)d_in[22];
  const float* ffw2  = (const float*)d_in[23];
  const float* projw = (const float*)d_in[24];
  const float* projb = (const float*)d_in[25];
  const float* normw = (const float*)d_in[26];
  const float* normb = (const float*)d_in[27];

  static const int N1S[4]  = {49, 196, 784, 3136};
  static const int FRDS[4] = {512, 256, 128, 64};
  static const int NSEG[4] = {1, 1, 2, 4};
  const size_t LW = 4718592;
  static const size_t ROFF[4] = {0, 16*49ull, 16*(49+196ull), 16*(49+196+784ull)};
  static const size_t PTO[4]  = {0, 6ull*2048*512, 6ull*2048*(512+256), 6ull*2048*(512+256+128)};

  bf16 *fbf[4], *pT[4], *pbf[4], *projT, *PTbuf, *PTall;
  float *qkvl_bias, *kvx_bias, *ff_bias, *lat, *headtmp, *svv, *bwv, *pbuf, *pbuf2;
  float2 *rstats;
  float *opart, *mlpart;
  bf16 *qkvl_act, *attnout, *zlat, *latbf, *ffh;
  bf16 *wqkvlT = nullptr, *wkvxT = nullptr, *woT = nullptr, *w1T = nullptr, *w2T = nullptr;
  bf16 *wbuf = nullptr;
  char *big;

  auto assign = [&](bool fullw, int bc) -> size_t {
    size_t off = 0; char* base = (char*)d_ws;
    auto A = [&](size_t b) -> char* {
      char* p = base + off; off = (off + b + 255) & ~(size_t)255; return p;
    };
    for (int i = 0; i < 4; ++i) fbf[i] = (bf16*)A((size_t)16 * N1S[i] * FRDS[i] * 2);
    for (int i = 0; i < 4; ++i) pT[i]  = (bf16*)A((size_t)768 * FRDS[i] * 2);
    for (int i = 0; i < 4; ++i) pbf[i] = (bf16*)A((size_t)FRDS[i] * 768 * 2);
    projT     = (bf16*)A(768ull * 768 * 2);
    PTbuf     = (bf16*)A(2048ull * 512 * 2);
    qkvl_bias = (float*)A(24ull * 3072 * 4);
    kvx_bias  = (float*)A(24ull * 2048 * 4);
    ff_bias   = (float*)A(6ull * 3072 * 4);
    svv       = (float*)A(24ull * 2048 * 4);
    bwv       = (float*)A(24ull * 2048 * 4);
    pbuf      = (float*)A(4ull * 8 * 24 * 2048 * 4);
    pbuf2     = (float*)A(8ull * 24 * 3072 * 4);
    rstats    = (float2*)A(16ull * 4165 * 8);
    qkvl_act  = (bf16*)A(1024ull * 3072 * 2);
    attnout   = (bf16*)A(1024ull * 1024 * 2);
    lat       = (float*)A(1024ull * 768 * 4);
    zlat      = (bf16*)A(1024ull * 768 * 2);
    opart     = (float*)A(4ull * (size_t)bc * 64 * 1024 * 4);
    mlpart    = (float*)A(4ull * (size_t)bc * 64 * 16 * 2 * 4);
    if (fullw) {
      wqkvlT = (bf16*)A(24ull * 3072 * 768 * 2);
      wkvxT  = (bf16*)A(24ull * 2048 * 768 * 2);
      woT    = (bf16*)A(24ull * 768 * 1024 * 2);
      w1T    = (bf16*)A(6ull * 3072 * 768 * 2);
      w2T    = (bf16*)A(6ull * 768 * 3072 * 2);
      PTall  = (bf16*)A(6ull * 2048 * 960 * 2);
      wbuf = nullptr;
    } else {
      wbuf = (bf16*)A(4ull * LW * 2);
      wqkvlT = wkvxT = woT = w1T = w2T = nullptr;
      PTall = nullptr;
    }
    big = A((size_t)bc * 3136 * 2048 * 2);
    ffh = qkvl_act; headtmp = (float*)qkvl_act; latbf = zlat;
    return off;
  };

  static const bool FULLS[10] = {true,true,false,true,false,true,true,false,false,false};
  static const int  BCS[10]   = {16,  8,   16,   4,   8,    2,   1,   4,    2,    1};
  bool fullw = false; int bc = 1; bool ok = false;
  for (int c = 0; c < 10; ++c) {
    if (assign(FULLS[c], BCS[c]) <= ws_size) { fullw = FULLS[c]; bc = BCS[c]; ok = true; break; }
  }
  if (!ok) return;

  float* featf32 = (float*)big;
  bf16*  kvxbuf  = (bf16*)big;

  auto gemm = [&](int tile, const bf16* A, const bf16* Bt, void* C,
                  const float* bias, const float* res, int M, int N, int K,
                  bool obf, bool gl) {
    if (tile == 128) {
      int nxt = N / 128, nwg = nxt * ((M + 127) / 128);
      if (obf && gl) k_gemm<128,128,true ,true ,false><<<nwg,256,0,stream>>>(A,Bt,C,bias,res,nullptr,nullptr,nullptr,M,N,K,0,0,nxt,nwg);
      else if (obf)  k_gemm<128,128,true ,false,false><<<nwg,256,0,stream>>>(A,Bt,C,bias,res,nullptr,nullptr,nullptr,M,N,K,0,0,nxt,nwg);
      else           k_gemm<128,128,false,false,false><<<nwg,256,0,stream>>>(A,Bt,C,bias,res,nullptr,nullptr,nullptr,M,N,K,0,0,nxt,nwg);
    } else if (tile == 64) {
      int nxt = N / 64, nwg = nxt * ((M + 63) / 64);
      if (obf && gl)  k_gemm<64,64,true ,true ,false><<<nwg,256,0,stream>>>(A,Bt,C,bias,res,nullptr,nullptr,nullptr,M,N,K,0,0,nxt,nwg);
      else if (obf)   k_gemm<64,64,true ,false,false><<<nwg,256,0,stream>>>(A,Bt,C,bias,res,nullptr,nullptr,nullptr,M,N,K,0,0,nxt,nwg);
      else            k_gemm<64,64,false,false,false><<<nwg,256,0,stream>>>(A,Bt,C,bias,res,nullptr,nullptr,nullptr,M,N,K,0,0,nxt,nwg);
    } else {
      int nxt = N / 64, nwg = nxt * ((M + 31) / 32);
      if (obf && gl)  k_gemm<32,64,true ,true ,false><<<nwg,256,0,stream>>>(A,Bt,C,bias,res,nullptr,nullptr,nullptr,M,N,K,0,0,nxt,nwg);
      else if (obf)   k_gemm<32,64,true ,false,false><<<nwg,256,0,stream>>>(A,Bt,C,bias,res,nullptr,nullptr,nullptr,M,N,K,0,0,nxt,nwg);
      else            k_gemm<32,64,false,false,false><<<nwg,256,0,stream>>>(A,Bt,C,bias,res,nullptr,nullptr,nullptr,M,N,K,0,0,nxt,nwg);
    }
  };
  auto gemmkv = [&](const bf16* A, const bf16* Bt, void* C,
                    const float* lb, const float2* rst, const float* c1, const float* cs,
                    int M, int N, int K) {
    if (M >= 2048) {
      int nxt = N / 128, nwg = nxt * ((M + 127) / 128);
      k_gemm<128,128,true,false,true><<<nwg,256,0,stream>>>(A,Bt,C,lb,nullptr,rst,c1,cs,M,N,K,0,0,nxt,nwg);
    } else {
      int nxt = N / 64, nwg = nxt * ((M + 63) / 64);
      k_gemm<64,64,true,false,true><<<nwg,256,0,stream>>>(A,Bt,C,lb,nullptr,rst,c1,cs,M,N,K,0,0,nxt,nwg);
    }
  };
  auto pick = [&](int M, int N) -> int {
    return M >= 2048 ? 128 : (N >= 1536 ? 64 : 32);
  };

  // ---- bias folds (K-split) + merged kv fold (K-split) ----
  k_bfoldz<<<dim3(4, 24, 8), 256, 0, stream>>>(wq, ln2b, pbuf2, 768, 1024, 768LL*1024, 768);
  k_bred  <<<dim3(4, 24), 256, 0, stream>>>(pbuf2, qkvl_bias, 1024, 24, 3072);
  k_kvfold<<<dim3(8, 24, 8), 256, 0, stream>>>(wkv, ln2b, ln1b, ln1w,
                                               pb_in[0], pb_in[1], pb_in[2], pb_in[3], pbuf);
  k_kvred <<<dim3(8, 24), 256, 0, stream>>>(pbuf, qkvl_bias, kvx_bias, svv, bwv);
  k_bfoldz<<<dim3(12, 6, 8), 256, 0, stream>>>(ffw1, fflnb, pbuf2, 768, 3072, 768LL*3072, 768);
  k_bred  <<<dim3(12, 6), 256, 0, stream>>>(pbuf2, ff_bias, 3072, 6, 3072);

  // ---- small folded weights ----
  for (int i = 0; i < 4; ++i) {
    k_tfoldx<false><<<dim3(12, FRDS[i] / 64, 1), 256, 0, stream>>>(
        pw_in[i], nullptr, nullptr, pT[i], nullptr, FRDS[i], 768, 0, 0, 0, 0);
    int cnt = FRDS[i] * 768;
    k_cvt<<<cnt / 1024, 256, 0, stream>>>(pw_in[i], pbf[i], cnt / 4);
  }
  k_tfoldx<false><<<dim3(12, 12, 1), 256, 0, stream>>>(
      projw, nullptr, nullptr, projT, nullptr, 768, 768, 0, 0, 0, 0);

  // ---- full-mode weight folds + batched PT precompute ----
  if (fullw) {
    k_tfoldx<false><<<dim3(16, 12, 24), 256, 0, stream>>>(
        wq, ln2w, nullptr, wqkvlT, nullptr, 768, 1024, 768LL*1024, 768, 3072LL*768, 0);
    k_tfoldx<true><<<dim3(32, 12, 24), 256, 0, stream>>>(
        wkv, ln2w, ln1w, wqkvlT + 1024LL*768, wkvxT, 768, 2048,
        768LL*2048, 768, 3072LL*768, 2048LL*768);
    k_tfoldx<false><<<dim3(12, 16, 24), 256, 0, stream>>>(
        wo, nullptr, nullptr, woT, nullptr, 1024, 768, 1024LL*768, 0, 768LL*1024, 0);
    k_tfoldx<false><<<dim3(48, 12, 6), 256, 0, stream>>>(
        ffw1, fflnw, nullptr, w1T, nullptr, 768, 3072, 768LL*3072, 768, 3072LL*768, 0);
    k_tfoldx<false><<<dim3(12, 48, 6), 256, 0, stream>>>(
        ffw2, nullptr, nullptr, w2T, nullptr, 3072, 768, 3072LL*768, 0, 768LL*3072, 0);
    // all 24 PT matrices, batched over depth (z=6) per scale
    for (int i = 0; i < 4; ++i) {
      int frd = FRDS[i];
      int nxt = frd / 64, nwg = nxt * 32;
      k_gemm<64,64,true,false,false><<<dim3(nwg, 6), 256, 0, stream>>>(
          wkvxT + (size_t)i * 2048 * 768, pbf[i], PTall + PTO[i],
          nullptr, nullptr, nullptr, nullptr, nullptr, 2048, frd, 768,
          4LL * 2048 * 768 * 2, (long long)2048 * frd * 2, nxt, nwg);
    }
  }

  auto foldDepthAttn = [&](int d) {
    k_tfoldx<false><<<dim3(16, 12, 4), 256, 0, stream>>>(
        wq + (size_t)d*4*768*1024, ln2w + (size_t)d*4*768, nullptr,
        wbuf, nullptr, 768, 1024, 768LL*1024, 768, (long long)LW, 0);
    k_tfoldx<true><<<dim3(32, 12, 4), 256, 0, stream>>>(
        wkv + (size_t)d*4*768*2048, ln2w + (size_t)d*4*768, ln1w + (size_t)d*4*768,
        wbuf + 1024ull*768, wbuf + 3072ull*768, 768, 2048,
        768LL*2048, 768, (long long)LW, (long long)LW);
    k_tfoldx<false><<<dim3(12, 16, 4), 256, 0, stream>>>(
        wo + (size_t)d*4*1024*768, nullptr, nullptr,
        wbuf + 3932160ull, nullptr, 1024, 768, 1024LL*768, 0, (long long)LW, 0);
  };
  auto attnW = [&](int di, const bf16*& qkvlT_p, const bf16*& kvxT_p, const bf16*& woT_p) {
    if (fullw) {
      qkvlT_p = wqkvlT + (size_t)di * 3072 * 768;
      kvxT_p  = wkvxT  + (size_t)di * 2048 * 768;
      woT_p   = woT    + (size_t)di * 768 * 1024;
    } else {
      bf16* base = wbuf + (size_t)(di & 3) * LW;
      qkvlT_p = base;
      kvxT_p  = base + 2359296ull;
      woT_p   = base + 3932160ull;
    }
  };
  auto ffW = [&](int d, const bf16*& w1p, const bf16*& w2p) {
    if (fullw) {
      w1p = w1T + (size_t)d * 3072 * 768;
      w2p = w2T + (size_t)d * 768 * 3072;
    } else {
      bf16* d1 = wbuf;
      bf16* d2 = wbuf + 3072ull * 768;
      k_tfoldx<false><<<dim3(48, 12, 1), 256, 0, stream>>>(
          ffw1 + (size_t)d*768*3072, fflnw + 768ull*d, nullptr, d1, nullptr,
          768, 3072, 0, 0, 0, 0);
      k_tfoldx<false><<<dim3(12, 48, 1), 256, 0, stream>>>(
          ffw2 + (size_t)d*3072*768, nullptr, nullptr, d2, nullptr,
          3072, 768, 0, 0, 0, 0);
      w1p = d1; w2p = d2;
    }
  };

  // ---- feature projection -> row stats only ----
  for (int i = 0; i < 4; ++i) {
    int n1 = N1S[i], frd = FRDS[i];
    size_t cnt = (size_t)16 * n1 * frd;
    k_cvt<<<(int)(cnt / 1024), 256, 0, stream>>>(f_in[i], fbf[i], (int)(cnt / 4));
    for (int b0 = 0; b0 < 16; b0 += bc) {
      int rows = bc * n1;
      gemm(pick(rows, 768), fbf[i] + (size_t)b0 * n1 * frd, pT[i], featf32,
           pb_in[i], nullptr, rows, 768, frd, false, false);
      k_stats<<<rows, 256, 0, stream>>>(featf32, rstats + ROFF[i] + (size_t)b0 * n1);
    }
  }

  hipMemcpyAsync(lat, id_emb, 1024ull * 768 * 4, hipMemcpyDeviceToDevice, stream);

  // ---- depth loop ----
  for (int d = 0; d < 6; ++d) {
    if (!fullw) foldDepthAttn(d);
    for (int i = 0; i < 4; ++i) {
      int di = d * 4 + i, n1 = N1S[i], nseg = NSEG[i], frd = FRDS[i];
      const bf16 *qkvlT_p, *kvxT_p, *woT_p;
      attnW(di, qkvlT_p, kvxT_p, woT_p);
      const bf16* PTp;
      if (fullw) {
        PTp = PTall + PTO[i] + (size_t)d * 2048 * frd;
      } else {
        gemm(64, kvxT_p, pbf[i], PTbuf, nullptr, nullptr, 2048, frd, 768, true, false);
        PTp = PTbuf;
      }
      k_std<<<1024, 256, 0, stream>>>(lat, zlat);
      gemm(64, zlat, qkvlT_p, qkvl_act, qkvl_bias + 3072ull * di, nullptr,
           1024, 3072, 768, true, false);
      for (int b0 = 0; b0 < 16; b0 += bc) {
        int rows = bc * n1;
        if (i == 3) {
          k_attn<true><<<bc * 16 * nseg, 256, 0, stream>>>(
              qkvl_act, kvxbuf, attnout, opart, mlpart, n1, b0, nseg, bc,
              fbf[3], PTp, rstats + ROFF[3],
              bwv + 2048ull * di, svv + 2048ull * di, kvx_bias + 2048ull * di);
        } else {
          gemmkv(fbf[i] + (size_t)b0 * n1 * frd, PTp, kvxbuf,
                 kvx_bias + 2048ull * di, rstats + ROFF[i] + (size_t)b0 * n1,
                 bwv + 2048ull * di, svv + 2048ull * di, rows, 2048, frd);
          k_attn<false><<<bc * 16 * nseg, 256, 0, stream>>>(
              qkvl_act, kvxbuf, attnout, opart, mlpart, n1, b0, nseg, bc,
              nullptr, nullptr, nullptr, nullptr, nullptr, nullptr);
        }
        if (nseg > 1)
          k_amerge<<<bc * 16, 256, 0, stream>>>(opart, mlpart, attnout, b0, nseg, bc);
      }
      gemm(32, attnout, woT_p, lat, nullptr, lat, 1024, 768, 1024, false, false);
    }
    const bf16 *w1p, *w2p;
    ffW(d, w1p, w2p);
    k_std<<<1024, 256, 0, stream>>>(lat, zlat);
    gemm(64, zlat, w1p, ffh, ff_bias + 3072ull * d, nullptr, 1024, 3072, 768, true, true);
    gemm(32, ffh, w2p, lat, nullptr, lat, 1024, 768, 3072, false, false);
  }

  // ---- head ----
  k_cvt<<<768, 256, 0, stream>>>(lat, latbf, 196608);
  gemm(32, latbf, projT, headtmp, projb, nullptr, 1024, 768, 768, false, false);
  k_lnout<<<1024, 256, 0, stream>>>(headtmp, normw, normb, (float*)d_out);
}